// Round 18
// baseline (230.347 us; speedup 1.0000x reference)
//
#include <hip/hip_runtime.h>
#include <hip/hip_bf16.h>

#define S_LEN 2048
#define D_DIM 1024
#define H_NUM 16
#define HD_DIM 64
#define GH_DIM 64
#define FFN_H 2730
#define FFNP  2816          // FFN_H padded to multiple of 128 (zero-filled)
#define CTX_W 512
#define L2LAM -0.00144341687f   // log2(0.999)
#define QBLK 64
#define KBLK 64
#define ALDK 76             // LDS row stride (152B): write-conflict-free, reads <=2-way
#define QSCALE 0.1803368801111731f  // 0.125 * log2(e): scores come out ready for exp2

typedef unsigned short u16;
typedef __attribute__((ext_vector_type(8))) short bf16x8_t;
typedef __attribute__((ext_vector_type(4))) float f32x4_t;

__device__ inline float wave_sum(float v) {
    for (int off = 32; off; off >>= 1) v += __shfl_xor(v, off);
    return v;
}
// f32 -> bf16 (RNE) via the HW pack instruction: 1 VALU op.
__device__ inline u16 f2bf(float f) {
    unsigned r;
    asm("v_cvt_pk_bf16_f32 %0, %1, %2" : "=v"(r) : "v"(f), "v"(f));
    return (u16)r;
}
// pack two f32 -> u32 of 2 bf16 (lo, hi): 1 VALU op.
__device__ inline unsigned f2bf2(float lo, float hi) {
    unsigned r;
    asm("v_cvt_pk_bf16_f32 %0, %1, %2" : "=v"(r) : "v"(lo), "v"(hi));
    return r;
}
__device__ inline float bf2f(u16 u) {
    return __uint_as_float(((unsigned int)u) << 16);
}
__device__ inline void gload16(const void* g, void* l) {
    __builtin_amdgcn_global_load_lds(
        (const __attribute__((address_space(1))) void*)g,
        (__attribute__((address_space(3))) void*)l, 16, 0, 0);
}

// ------- RMSNorm (fp32 in -> bf16 out), optionally fused gamma gate ---------
template<bool GAMMA>
__global__ __launch_bounds__(256) void rmsnorm_gamma_kernel(
    const float* __restrict__ in, const float* __restrict__ w,
    u16* __restrict__ out, const float* __restrict__ w1,
    const float* __restrict__ w2, float* __restrict__ gamma)
{
    __shared__ float hl[D_DIM];
    __shared__ float part[4][GH_DIM];
    __shared__ float wsum[4];
    int row = blockIdx.x;
    int tid = threadIdx.x, lane = tid & 63, wv = tid >> 6;
    const float4* ir = reinterpret_cast<const float4*>(in + (size_t)row * D_DIM);
    float4 v = ir[tid];
    float ss = v.x*v.x + v.y*v.y + v.z*v.z + v.w*v.w;
    ss = wave_sum(ss);
    if (lane == 0) wsum[wv] = ss;
    __syncthreads();
    float tot = wsum[0] + wsum[1] + wsum[2] + wsum[3];
    float scale = rsqrtf(tot / (float)D_DIM + 1e-6f);
    const float4* wr = reinterpret_cast<const float4*>(w);
    float4 wv4 = wr[tid];
    float h0 = v.x * scale * wv4.x, h1 = v.y * scale * wv4.y;
    float h2 = v.z * scale * wv4.z, h3 = v.w * scale * wv4.w;
    uint2 o;
    o.x = f2bf2(h0, h1);
    o.y = f2bf2(h2, h3);
    *reinterpret_cast<uint2*>(out + (size_t)row * D_DIM + tid * 4) = o;
    if (GAMMA) {
        hl[tid*4+0] = h0; hl[tid*4+1] = h1; hl[tid*4+2] = h2; hl[tid*4+3] = h3;
        __syncthreads();
        float acc = 0.f;
        #pragma unroll 8
        for (int k = wv * 256; k < wv * 256 + 256; ++k)
            acc += hl[k] * w1[k * GH_DIM + lane];
        part[wv][lane] = acc;
        __syncthreads();
        if (wv == 0) {
            float t = part[0][lane] + part[1][lane] + part[2][lane] + part[3][lane];
            float z = t / (1.f + __expf(-t));
            float y = z * w2[lane];
            float t2 = wave_sum(y);
            if (lane == 0) gamma[row] = 1.f / (1.f + __expf(-t2));
        }
    }
}

// --- prep: weight transposes (64x64 tiles, 128B writes) + rmsnorm1+gamma ----
__global__ __launch_bounds__(256) void prep_kernel(
    const float* __restrict__ w_qkv, const float* __restrict__ w_o,
    const float* __restrict__ w1f, const float* __restrict__ w3f,
    const float* __restrict__ w2f, u16* __restrict__ wqT,
    u16* __restrict__ woT, u16* __restrict__ w13T, u16* __restrict__ w2T,
    const float* __restrict__ x, const float* __restrict__ norm1_w,
    u16* __restrict__ h_bf, const float* __restrict__ gw1,
    const float* __restrict__ gw2, float* __restrict__ gamma)
{
    __shared__ float tile[64][65];
    __shared__ float part[4][GH_DIM];
    __shared__ float wsum[4];
    int b = blockIdx.x;
    int tid = threadIdx.x;
    if (b < 3136) {
        const float* src; u16* dst;
        int srcK, srcN, Kp, rowOff, rowMul, nbx;
        if (b < 768)       {           src = w_qkv; dst = wqT;  srcK = 1024; srcN = 3072; Kp = 1024; rowOff = 0; rowMul = 1; nbx = 48; }
        else if (b < 1024) { b -= 768;  src = w_o;  dst = woT;  srcK = 1024; srcN = 1024; Kp = 1024; rowOff = 0; rowMul = 1; nbx = 16; }
        else if (b < 1728) { b -= 1024; src = w1f;  dst = w13T; srcK = 1024; srcN = 2730; Kp = 1024; rowOff = 0; rowMul = 2; nbx = 44; }
        else if (b < 2432) { b -= 1728; src = w3f;  dst = w13T; srcK = 1024; srcN = 2730; Kp = 1024; rowOff = 1; rowMul = 2; nbx = 44; }
        else               { b -= 2432; src = w2f;  dst = w2T;  srcK = 2730; srcN = 1024; Kp = 2816; rowOff = 0; rowMul = 1; nbx = 16; }
        int n0 = (b % nbx) * 64, k0 = (b / nbx) * 64;
        int tx = tid & 15, ty = tid >> 4;       // read: 16 thr/row x float4
        bool interior = (k0 + 63 < srcK) && (n0 + 63 < srcN);
        #pragma unroll
        for (int p = 0; p < 4; ++p) {
            int kk = p * 16 + ty;
            int r = k0 + kk;
            int cb = n0 + tx * 4;
            float4 v;
            if (interior) {
                v = *(const float4*)(src + (size_t)r * srcN + cb);
            } else {
                v.x = (r < srcK && cb     < srcN) ? src[(size_t)r * srcN + cb]     : 0.f;
                v.y = (r < srcK && cb + 1 < srcN) ? src[(size_t)r * srcN + cb + 1] : 0.f;
                v.z = (r < srcK && cb + 2 < srcN) ? src[(size_t)r * srcN + cb + 2] : 0.f;
                v.w = (r < srcK && cb + 3 < srcN) ? src[(size_t)r * srcN + cb + 3] : 0.f;
            }
            tile[kk][tx*4+0] = v.x; tile[kk][tx*4+1] = v.y;
            tile[kk][tx*4+2] = v.z; tile[kk][tx*4+3] = v.w;
        }
        __syncthreads();
        int wx = tid & 7, wy = tid >> 3;        // write: 8 thr/row x uint4(8 u16)
        #pragma unroll
        for (int p = 0; p < 2; ++p) {
            int nn = p * 32 + wy;
            int ks = wx * 8;
            uint4 o;
            o.x = f2bf2(tile[ks+0][nn], tile[ks+1][nn]);
            o.y = f2bf2(tile[ks+2][nn], tile[ks+3][nn]);
            o.z = f2bf2(tile[ks+4][nn], tile[ks+5][nn]);
            o.w = f2bf2(tile[ks+6][nn], tile[ks+7][nn]);
            *(uint4*)(dst + (size_t)(rowOff + (size_t)(n0 + nn) * rowMul) * Kp + k0 + ks) = o;
        }
    } else {
        int row = b - 3136;
        int lane = tid & 63, wv = tid >> 6;
        float* hl = &tile[0][0];
        const float4* ir = reinterpret_cast<const float4*>(x + (size_t)row * D_DIM);
        float4 v = ir[tid];
        float ss = v.x*v.x + v.y*v.y + v.z*v.z + v.w*v.w;
        ss = wave_sum(ss);
        if (lane == 0) wsum[wv] = ss;
        __syncthreads();
        float tot = wsum[0] + wsum[1] + wsum[2] + wsum[3];
        float scale = rsqrtf(tot / (float)D_DIM + 1e-6f);
        const float4* wr = reinterpret_cast<const float4*>(norm1_w);
        float4 wv4 = wr[tid];
        float h0 = v.x * scale * wv4.x, h1 = v.y * scale * wv4.y;
        float h2 = v.z * scale * wv4.z, h3 = v.w * scale * wv4.w;
        uint2 o;
        o.x = f2bf2(h0, h1);
        o.y = f2bf2(h2, h3);
        *reinterpret_cast<uint2*>(h_bf + (size_t)row * D_DIM + tid * 4) = o;
        hl[tid*4+0] = h0; hl[tid*4+1] = h1; hl[tid*4+2] = h2; hl[tid*4+3] = h3;
        __syncthreads();
        float acc = 0.f;
        #pragma unroll 8
        for (int k = wv * 256; k < wv * 256 + 256; ++k)
            acc += hl[k] * gw1[k * GH_DIM + lane];
        part[wv][lane] = acc;
        __syncthreads();
        if (wv == 0) {
            float t = part[0][lane] + part[1][lane] + part[2][lane] + part[3][lane];
            float z = t / (1.f + __expf(-t));
            float y = z * gw2[lane];
            float t2 = wave_sum(y);
            if (lane == 0) gamma[row] = 1.f / (1.f + __expf(-t2));
        }
    }
}

// ---- fused split qkv + qk rmsnorm + RoPE + KV transpose (one launch) -------
__global__ __launch_bounds__(256) void split_rope_tr_kernel(
    const u16* __restrict__ qkv, const float* __restrict__ qw,
    const float* __restrict__ kw, float* __restrict__ qhp,
    u16* __restrict__ khp, u16* __restrict__ khT, u16* __restrict__ vhT)
{
    __shared__ u16 tk[64][ALDK];
    __shared__ u16 tv[64][ALDK];
    int tid = threadIdx.x;
    int w = tid >> 6, d = tid & 63;
    int h = blockIdx.y;
    int s0 = blockIdx.x * 64;
    float qwv = qw[d], kwv = kw[d];
    int j = d & 31;
    float inv = expf(-(float)j * (9.2103403719761836f / 32.0f));
    float sgn = (d < 32) ? -1.f : 1.f;
    for (int i = 0; i < 16; ++i) {
        int sl = w * 16 + i;
        int s = s0 + sl;
        size_t base = (size_t)s * (3 * D_DIM) + h * HD_DIM + d;
        float qv = bf2f(qkv[base]);
        float kv = bf2f(qkv[base + D_DIM]);
        u16  vv = qkv[base + 2 * D_DIM];
        float sq = wave_sum(qv * qv);
        float qn = qv * rsqrtf(sq / (float)HD_DIM + 1e-6f) * qwv;
        float sk = wave_sum(kv * kv);
        float kn = kv * rsqrtf(sk / (float)HD_DIM + 1e-6f) * kwv;
        float ang = (float)s * inv;
        float cs = cosf(ang), sn = sinf(ang);
        float qp = __shfl_xor(qn, 32);
        float kp = __shfl_xor(kn, 32);
        float qo = qn * cs + sgn * qp * sn;
        float ko = kn * cs + sgn * kp * sn;
        size_t ob = ((size_t)h * S_LEN + s) * HD_DIM + d;
        u16 kb = f2bf(ko);
        qhp[ob] = qo;
        khp[ob] = kb;
        tk[sl][d] = kb;
        tv[sl][d] = vv;
    }
    __syncthreads();
    int r = tid >> 2, cc = (tid & 3) * 16;
    union { u16 u[16]; bf16x8_t v[2]; } ok, ov;
    #pragma unroll
    for (int e = 0; e < 16; ++e) {
        int ksrc = (e & 3) * 16 + (tid & 3) * 4 + (e >> 2);   // pi^-1 permute
        ok.u[e] = tk[ksrc][r]; ov.u[e] = tv[ksrc][r];
    }
    u16* kd = khT + ((size_t)h * HD_DIM + r) * S_LEN + s0 + cc;
    u16* vd = vhT + ((size_t)h * HD_DIM + r) * S_LEN + s0 + cc;
    *(bf16x8_t*)kd       = ok.v[0];
    *(bf16x8_t*)(kd + 8) = ok.v[1];
    *(bf16x8_t*)vd       = ov.v[0];
    *(bf16x8_t*)(vd + 8) = ov.v[1];
}

// ---------------- bf16 MFMA GEMM, 128-col tiles ------------------------------
// MODE 1: bf16 out.  MODE 2: paired silu-mul, bf16 out width N/2.
template<int BM, int MODE>
__global__ __launch_bounds__(256) void gemm_bb_kernel(
    const u16* __restrict__ A, const u16* __restrict__ B,
    u16* __restrict__ Cb, int M, int N, int K)
{
    constexpr int MREP = BM / 32;
    constexpr int ACH  = BM / 32;
    __shared__ u16 As[BM * 64];
    __shared__ u16 Bs[128 * 64];
    int tid = threadIdx.x, lane = tid & 63, wid = tid >> 6;
    int wr = wid >> 1, wc = wid & 1;
    int row0 = blockIdx.y * BM, col0 = blockIdx.x * 128;
    int l8 = lane >> 3, l7 = lane & 7;
    f32x4_t acc[MREP][4];
    #pragma unroll
    for (int i = 0; i < MREP; ++i)
        #pragma unroll
        for (int j = 0; j < 4; ++j) acc[i][j] = (f32x4_t)0.f;

    int fr = lane & 15, fo = (lane >> 4) * 8;
    for (int k0 = 0; k0 < K; k0 += 64) {
        #pragma unroll
        for (int i = 0; i < ACH; ++i) {
            int ch = wid * ACH + i;
            const u16* ga = A + (size_t)(row0 + ch * 8 + l8) * K + k0 + l7 * 8;
            gload16(ga, &As[ch * 512]);
        }
        #pragma unroll
        for (int i = 0; i < 4; ++i) {
            int ch = wid * 4 + i;
            const u16* gb = B + (size_t)(col0 + ch * 8 + l8) * K + k0 + l7 * 8;
            gload16(gb, &Bs[ch * 512]);
        }
        __syncthreads();
        __builtin_amdgcn_s_setprio(1);
        #pragma unroll
        for (int khf = 0; khf < 2; ++khf) {
            bf16x8_t bfrag[4];
            #pragma unroll
            for (int ni = 0; ni < 4; ++ni)
                bfrag[ni] = *(const bf16x8_t*)&Bs[(wc * 64 + ni * 16 + fr) * 64 + khf * 32 + fo];
            #pragma unroll
            for (int mi = 0; mi < MREP; ++mi) {
                bf16x8_t af = *(const bf16x8_t*)&As[(wr * (BM / 2) + mi * 16 + fr) * 64 + khf * 32 + fo];
                #pragma unroll
                for (int ni = 0; ni < 4; ++ni)
                    acc[mi][ni] = __builtin_amdgcn_mfma_f32_16x16x32_bf16(
                        af, bfrag[ni], acc[mi][ni], 0, 0, 0);
            }
        }
        __builtin_amdgcn_s_setprio(0);
        __syncthreads();
    }
    int dr = (lane >> 4) * 4, dc = lane & 15;
    #pragma unroll
    for (int mi = 0; mi < MREP; ++mi) {
        int gr = row0 + wr * (BM / 2) + mi * 16 + dr;
        #pragma unroll
        for (int ni = 0; ni < 4; ++ni) {
            int gc = col0 + wc * 64 + ni * 16 + dc;
            #pragma unroll
            for (int j = 0; j < 4; ++j) {
                float v = acc[mi][ni][j];
                if (MODE == 1) {
                    Cb[(size_t)(gr + j) * N + gc] = f2bf(v);
                } else {
                    float partner = __shfl_xor(v, 1);
                    float a1 = (dc & 1) ? partner : v;
                    float a3 = (dc & 1) ? v : partner;
                    float rr = a1 / (1.f + __expf(-a1)) * a3;
                    if (!(dc & 1))
                        Cb[(size_t)(gr + j) * (N >> 1) + (gc >> 1)] = f2bf(rr);
                }
            }
        }
    }
}

// ------- bf16 MFMA GEMM, 64x64 tiles, BK=128, fp32 out + residual -----------
// 16 MFMAs per barrier round (4 K=32 sub-steps); halves barrier count for
// the K-deep skinny GEMMs (w_o, ffn2).
__global__ __launch_bounds__(256) void gemm64_kernel(
    const u16* __restrict__ A, const u16* __restrict__ B,
    const float* __restrict__ res, float* __restrict__ Cf,
    int M, int N, int K)
{
    __shared__ u16 As[64 * 128];
    __shared__ u16 Bs[64 * 128];
    int tid = threadIdx.x, lane = tid & 63, wid = tid >> 6;
    int wr = wid >> 1, wc = wid & 1;
    int row0 = blockIdx.y * 64, col0 = blockIdx.x * 64;
    int l4 = lane >> 4;           // row within 4-row chunk
    int l15 = (lane & 15) * 8;    // col chunk (8 u16 = 16B)
    f32x4_t acc[2][2];
    #pragma unroll
    for (int i = 0; i < 2; ++i)
        #pragma unroll
        for (int j = 0; j < 2; ++j) acc[i][j] = (f32x4_t)0.f;
    int fr = lane & 15, fo = (lane >> 4) * 8;
    for (int k0 = 0; k0 < K; k0 += 128) {
        #pragma unroll
        for (int i = 0; i < 4; ++i) {
            int ch = wid * 4 + i;          // 16 chunks of 4 rows x 128 cols
            const u16* ga = A + (size_t)(row0 + ch * 4 + l4) * K + k0 + l15;
            gload16(ga, &As[ch * 512]);
            const u16* gb = B + (size_t)(col0 + ch * 4 + l4) * K + k0 + l15;
            gload16(gb, &Bs[ch * 512]);
        }
        __syncthreads();
        __builtin_amdgcn_s_setprio(1);
        #pragma unroll
        for (int khf = 0; khf < 4; ++khf) {
            bf16x8_t bfrag[2];
            #pragma unroll
            for (int ni = 0; ni < 2; ++ni)
                bfrag[ni] = *(const bf16x8_t*)&Bs[(wc * 32 + ni * 16 + fr) * 128 + khf * 32 + fo];
            #pragma unroll
            for (int mi = 0; mi < 2; ++mi) {
                bf16x8_t af = *(const bf16x8_t*)&As[(wr * 32 + mi * 16 + fr) * 128 + khf * 32 + fo];
                #pragma unroll
                for (int ni = 0; ni < 2; ++ni)
                    acc[mi][ni] = __builtin_amdgcn_mfma_f32_16x16x32_bf16(
                        af, bfrag[ni], acc[mi][ni], 0, 0, 0);
            }
        }
        __builtin_amdgcn_s_setprio(0);
        __syncthreads();
    }
    int dr = (lane >> 4) * 4, dc = lane & 15;
    #pragma unroll
    for (int mi = 0; mi < 2; ++mi) {
        int gr = row0 + wr * 32 + mi * 16 + dr;
        #pragma unroll
        for (int ni = 0; ni < 2; ++ni) {
            int gc = col0 + wc * 32 + ni * 16 + dc;
            #pragma unroll
            for (int j = 0; j < 4; ++j) {
                size_t off = (size_t)(gr + j) * N + gc;
                Cf[off] = acc[mi][ni][j] + res[off];
            }
        }
    }
}

// ============ FUSED omega-rule + flash attention ============================
__global__ __launch_bounds__(256) void fused_omega_attn_kernel(
    const float* __restrict__ qhp, const u16* __restrict__ khp,
    const u16* __restrict__ khT, const u16* __restrict__ vhT,
    const float* __restrict__ gammab, const float* __restrict__ mp,
    const float* __restrict__ mg, u16* __restrict__ ao)
{
    __shared__ u16 Ks[2][KBLK][ALDK];
    __shared__ u16 Xt[2][KBLK][ALDK];
    __shared__ u16 Ps[QBLK][ALDK];
    __shared__ float colfL[CTX_W + KBLK];
    const int tid = threadIdx.x, lane = tid & 63, wq = tid >> 6;
    const int b = blockIdx.x;
    const int hi = (b >> 8) & 1;
    const int h = ((b & 7) << 1) + hi;
    const int s5 = (b >> 3) & 31;
    const int qt = hi ? (31 - s5) : s5;
    const int q0 = qt * QBLK;
    const int fr = lane & 15, g4 = lane >> 4;
    const int fko = g4 * 8;
    const int c = fr, rg = g4;
    const int si = tid >> 2, sdb = (tid & 3) * 16;
    const size_t hS = (size_t)h * S_LEN;
    const size_t hD = (size_t)h * HD_DIM;

    int rowt[4]; float rowf[4];
    #pragma unroll
    for (int j = 0; j < 4; ++j) {
        rowt[j] = q0 + wq * 16 + rg * 4 + j;
        rowf[j] = exp2f((float)(wq * 16 + rg * 4 + j) * L2LAM);
    }
    bf16x8_t qf[2];
    {
        const float* qrow = qhp + (hS + q0 + wq * 16 + fr) * HD_DIM;
        #pragma unroll
        for (int u = 0; u < 2; ++u) {
            float4 a = *(const float4*)(qrow + u * 32 + fko);
            float4 bq = *(const float4*)(qrow + u * 32 + fko + 4);
            bf16x8_t f;
            f[0]=f2bf(a.x); f[1]=f2bf(a.y); f[2]=f2bf(a.z); f[3]=f2bf(a.w);
            f[4]=f2bf(bq.x); f[5]=f2bf(bq.y); f[6]=f2bf(bq.z); f[7]=f2bf(bq.w);
            qf[u] = f;
        }
    }
    // preload q_old in C-layout (hides latency under the omega loop)
    float qold[4][4];
    #pragma unroll
    for (int n = 0; n < 4; ++n)
        #pragma unroll
        for (int j = 0; j < 4; ++j)
            qold[n][j] = qhp[(hS + rowt[j]) * HD_DIM + n * 16 + c];

    // ---------------- omega phase (double-buffered) ----------------
    f32x4_t accc[4];
    #pragma unroll
    for (int n = 0; n < 4; ++n) accc[n] = (f32x4_t)0.f;
    float wsum[4] = {0.f, 0.f, 0.f, 0.f};
    const int kt0 = (q0 > (CTX_W - 1)) ? (q0 - (CTX_W - 1)) / KBLK : 0;
    const int i0 = kt0 * KBLK;
    const int nwin = (qt + 1) * KBLK - i0;
    for (int idx = tid; idx < nwin; idx += 256) {
        int icol = i0 + idx;
        colfL[idx] = exp2f((float)(q0 - icol) * L2LAM) * gammab[icol];
    }
    {
        const u16* gk = khp + (hS + kt0 * KBLK + si) * HD_DIM + sdb;
        const u16* gx = khT + (hD + si) * S_LEN + kt0 * KBLK + sdb;
        *(bf16x8_t*)&Ks[0][si][sdb]     = *(const bf16x8_t*)gk;
        *(bf16x8_t*)&Ks[0][si][sdb + 8] = *(const bf16x8_t*)(gk + 8);
        *(bf16x8_t*)&Xt[0][si][sdb]     = *(const bf16x8_t*)gx;
        *(bf16x8_t*)&Xt[0][si][sdb + 8] = *(const bf16x8_t*)(gx + 8);
    }
    __syncthreads();
    int cur = 0;
    for (int kt = kt0; kt <= qt; ++kt) {
        const int k0 = kt * KBLK;
        const bool hn = (kt < qt);
        bf16x8_t nk0, nk1, nx0, nx1;
        if (hn) {
            const u16* gk = khp + (hS + k0 + KBLK + si) * HD_DIM + sdb;
            const u16* gx = khT + (hD + si) * S_LEN + k0 + KBLK + sdb;
            nk0 = *(const bf16x8_t*)gk; nk1 = *(const bf16x8_t*)(gk + 8);
            nx0 = *(const bf16x8_t*)gx; nx1 = *(const bf16x8_t*)(gx + 8);
        }
        f32x4_t s[4];
        #pragma unroll
        for (int n = 0; n < 4; ++n) s[n] = (f32x4_t)0.f;
        __builtin_amdgcn_s_setprio(1);
        #pragma unroll
        for (int u = 0; u < 2; ++u)
            #pragma unroll
            for (int n = 0; n < 4; ++n) {
                bf16x8_t kb = *(const bf16x8_t*)&Ks[cur][n * 16 + fr][u * 32 + fko];
                s[n] = __builtin_amdgcn_mfma_f32_16x16x32_bf16(qf[u], kb, s[n], 0, 0, 0);
            }
        __builtin_amdgcn_s_setprio(0);
        const bool boundary = (kt == kt0) || (kt == qt);
        float colf[4];
        #pragma unroll
        for (int n = 0; n < 4; ++n)
            colf[n] = colfL[k0 - i0 + n * 16 + c];
        #pragma unroll
        for (int j = 0; j < 4; ++j) {
            float pv[4];
            #pragma unroll
            for (int n = 0; n < 4; ++n) {
                float w;
                if (boundary) {
                    int delta = rowt[j] - (k0 + n * 16 + c);
                    w = (delta >= 0 && delta < CTX_W) ? rowf[j] * colf[n] : 0.f;
                } else {
                    w = rowf[j] * colf[n];
                }
                wsum[j] += w;
                pv[n] = w * s[n][j];
            }
            uint2 pk;
            pk.x = f2bf2(pv[0], pv[1]);
            pk.y = f2bf2(pv[2], pv[3]);
            *(uint2*)&Ps[wq * 16 + rg * 4 + j][c * 4] = pk;   // ds_write_b64
        }
        __builtin_amdgcn_s_setprio(1);
        #pragma unroll
        for (int u = 0; u < 2; ++u) {
            bf16x8_t pa = *(const bf16x8_t*)&Ps[wq * 16 + fr][u * 32 + fko];
            #pragma unroll
            for (int n = 0; n < 4; ++n) {
                bf16x8_t kb = *(const bf16x8_t*)&Xt[cur][n * 16 + fr][u * 32 + fko];
                accc[n] = __builtin_amdgcn_mfma_f32_16x16x32_bf16(pa, kb, accc[n], 0, 0, 0);
            }
        }
        __builtin_amdgcn_s_setprio(0);
        if (hn) {
            int nxt = cur ^ 1;
            *(bf16x8_t*)&Ks[nxt][si][sdb]     = nk0;
            *(bf16x8_t*)&Ks[nxt][si][sdb + 8] = nk1;
            *(bf16x8_t*)&Xt[nxt][si][sdb]     = nx0;
            *(bf16x8_t*)&Xt[nxt][si][sdb + 8] = nx1;
        }
        __syncthreads();
        cur ^= 1;
    }
    // persist = Q @ M_p^T
    f32x4_t pacc[4];
    #pragma unroll
    for (int n = 0; n < 4; ++n) pacc[n] = (f32x4_t)0.f;
    const float* mph = mp + hD * HD_DIM;
    #pragma unroll
    for (int u = 0; u < 2; ++u)
        #pragma unroll
        for (int n = 0; n < 4; ++n) {
            const float* br = mph + (size_t)(n * 16 + fr) * HD_DIM + u * 32 + fko;
            float4 a = *(const float4*)br;
            float4 bq = *(const float4*)(br + 4);
            bf16x8_t f;
            f[0]=f2bf(a.x); f[1]=f2bf(a.y); f[2]=f2bf(a.z); f[3]=f2bf(a.w);
            f[4]=f2bf(bq.x); f[5]=f2bf(bq.y); f[6]=f2bf(bq.z); f[7]=f2bf(bq.w);
            pacc[n] = __builtin_amdgcn_mfma_f32_16x16x32_bf16(qf[u], f, pacc[n], 0, 0, 0);
        }
    #pragma unroll
    for (int j = 0; j < 4; ++j) {
        wsum[j] += __shfl_xor(wsum[j], 1);
        wsum[j] += __shfl_xor(wsum[j], 2);
        wsum[j] += __shfl_xor(wsum[j], 4);
        wsum[j] += __shfl_xor(wsum[j], 8);
    }
    float gate = 1.f / (1.f + __expf(-mg[0]));
    float keep = 1.f - gate;
    #pragma unroll
    for (int n = 0; n < 4; ++n) {
        #pragma unroll
        for (int j = 0; j < 4; ++j) {
            float qn = keep * qold[n][j] + gate * (pacc[n][j] + accc[n][j]) / (1.f + wsum[j]);
            Ps[wq * 16 + rg * 4 + j][n * 16 + c] = f2bf(qn * QSCALE);
        }
    }
    bf16x8_t qf2[2];
    #pragma unroll
    for (int u = 0; u < 2; ++u)
        qf2[u] = *(const bf16x8_t*)&Ps[wq * 16 + fr][u * 32 + fko];

    // ---------------- attention phase (double-buffered, no-max softmax) -----
    f32x4_t acco[4];
    #pragma unroll
    for (int n = 0; n < 4; ++n) acco[n] = (f32x4_t)0.f;
    float l_run[4] = {0.f, 0.f, 0.f, 0.f};
    {
        const u16* gk = khp + (hS + si) * HD_DIM + sdb;
        const u16* gv = vhT + (hD + si) * S_LEN + sdb;
        *(bf16x8_t*)&Ks[0][si][sdb]     = *(const bf16x8_t*)gk;
        *(bf16x8_t*)&Ks[0][si][sdb + 8] = *(const bf16x8_t*)(gk + 8);
        *(bf16x8_t*)&Xt[0][si][sdb]     = *(const bf16x8_t*)gv;
        *(bf16x8_t*)&Xt[0][si][sdb + 8] = *(const bf16x8_t*)(gv + 8);
    }
    __syncthreads();
    cur = 0;
    for (int kt = 0; kt <= qt; ++kt) {
        const int k0 = kt * KBLK;
        const bool hn = (kt < qt);
        bf16x8_t nk0, nk1, nv0, nv1;
        if (hn) {
            const u16* gk = khp + (hS + k0 + KBLK + si) * HD_DIM + sdb;
            const u16* gv = vhT + (hD + si) * S_LEN + k0 + KBLK + sdb;
            nk0 = *(const bf16x8_t*)gk; nk1 = *(const bf16x8_t*)(gk + 8);
            nv0 = *(const bf16x8_t*)gv; nv1 = *(const bf16x8_t*)(gv + 8);
        }
        f32x4_t s[4];
        #pragma unroll
        for (int n = 0; n < 4; ++n) s[n] = (f32x4_t)0.f;
        __builtin_amdgcn_s_setprio(1);
        #pragma unroll
        for (int u = 0; u < 2; ++u)
            #pragma unroll
            for (int n = 0; n < 4; ++n) {
                bf16x8_t kb = *(const bf16x8_t*)&Ks[cur][n * 16 + fr][u * 32 + fko];
                s[n] = __builtin_amdgcn_mfma_f32_16x16x32_bf16(qf2[u], kb, s[n], 0, 0, 0);
            }
        __builtin_amdgcn_s_setprio(0);
        if (kt == qt) {
            #pragma unroll
            for (int n = 0; n < 4; ++n) {
                int icol = k0 + n * 16 + c;
                #pragma unroll
                for (int j = 0; j < 4; ++j)
                    if (icol > rowt[j]) s[n][j] = -1e30f;
            }
        }
        #pragma unroll
        for (int j = 0; j < 4; ++j) {
            float p0 = exp2f(s[0][j]);
            float p1 = exp2f(s[1][j]);
            float p2 = exp2f(s[2][j]);
            float p3 = exp2f(s[3][j]);
            l_run[j] += (p0 + p1) + (p2 + p3);
            uint2 pk;
            pk.x = f2bf2(p0, p1);
            pk.y = f2bf2(p2, p3);
            *(uint2*)&Ps[wq * 16 + rg * 4 + j][c * 4] = pk;   // ds_write_b64
        }
        __builtin_amdgcn_s_setprio(1);
        #pragma unroll
        for (int u = 0; u < 2; ++u) {
            bf16x8_t pa = *(const bf16x8_t*)&Ps[wq * 16 + fr][u * 32 + fko];
            #pragma unroll
            for (int n = 0; n < 4; ++n) {
                bf16x8_t vb = *(const bf16x8_t*)&Xt[cur][n * 16 + fr][u * 32 + fko];
                acco[n] = __builtin_amdgcn_mfma_f32_16x16x32_bf16(pa, vb, acco[n], 0, 0, 0);
            }
        }
        __builtin_amdgcn_s_setprio(0);
        if (hn) {
            int nxt = cur ^ 1;
            *(bf16x8_t*)&Ks[nxt][si][sdb]     = nk0;
            *(bf16x8_t*)&Ks[nxt][si][sdb + 8] = nk1;
            *(bf16x8_t*)&Xt[nxt][si][sdb]     = nv0;
            *(bf16x8_t*)&Xt[nxt][si][sdb + 8] = nv1;
        }
        __syncthreads();
        cur ^= 1;
    }
    #pragma unroll
    for (int j = 0; j < 4; ++j) {
        l_run[j] += __shfl_xor(l_run[j], 1);
        l_run[j] += __shfl_xor(l_run[j], 2);
        l_run[j] += __shfl_xor(l_run[j], 4);
        l_run[j] += __shfl_xor(l_run[j], 8);
    }
    #pragma unroll
    for (int n = 0; n < 4; ++n) {
        #pragma unroll
        for (int j = 0; j < 4; ++j) {
            float o = acco[n][j] / l_run[j];
            ao[(size_t)rowt[j] * D_DIM + h * HD_DIM + n * 16 + c] = f2bf(o);
        }
    }
}

extern "C" void kernel_launch(void* const* d_in, const int* in_sizes, int n_in,
                              void* d_out, int out_size, void* d_ws, size_t ws_size,
                              hipStream_t stream) {
    const float* x         = (const float*)d_in[0];
    const float* norm1_w   = (const float*)d_in[1];
    const float* norm2_w   = (const float*)d_in[2];
    const float* w_qkv     = (const float*)d_in[3];
    const float* q_norm_w  = (const float*)d_in[4];
    const float* k_norm_w  = (const float*)d_in[5];
    const float* gamma_w1  = (const float*)d_in[6];
    const float* gamma_w2  = (const float*)d_in[7];
    const float* m_persist = (const float*)d_in[8];
    const float* mem_gate  = (const float*)d_in[9];
    const float* w_o       = (const float*)d_in[10];
    const float* ffn_w1    = (const float*)d_in[11];
    const float* ffn_w3    = (const float*)d_in[12];
    const float* ffn_w2    = (const float*)d_in[13];
    float* out = (float*)d_out;
    char* ws = (char*)d_ws;

    const size_t MB = 1024 * 1024;
    u16*   h_bf   = (u16*)(ws);                 // [0,4MB) h / h2
    u16*   wqT    = (u16*)(ws + 4 * MB);        // [4,10)
    u16*   woT    = (u16*)(ws + 10 * MB);       // [10,12)
    u16*   w13T   = (u16*)(ws + 12 * MB);       // [12,23) interleaved w1/w3
    u16*   w2T    = (u16*)(ws + 23 * MB);       // [23,28.5)
    u16*   qkv_bf = (u16*)(ws + 29884416);      // [28.5,40.5) dead after split
    u16*   ao_bf  = (u16*)(ws + 38273024);      // [36.5,40.5) (after qkv dead)
    float* qh     = (float*)(ws + 42467328);    // [40.5,48.5) fp32 q
    u16*   kh     = (u16*)(ws + 50855936);      // [48.5,52.5)
    u16*   khT_s  = (u16*)(ws + 50855936 + 4 * MB);   // [52.5,56.5)
    float* gammab = (float*)(ws + 59244544);    // [56.5,+8KB)
    u16*   vhT_s  = (u16*)(ws + 59244544 + 64 * 1024); // [56.5+64KB,+4MB)
    u16*   mid_bf = (u16*)(ws + 29884416);      // [28.5,40) post-attention

    // --- prep: weight transposes + rmsnorm1 + gamma, ONE launch --------------
    hipLaunchKernelGGL(prep_kernel, dim3(3136 + S_LEN), dim3(256), 0, stream,
                       w_qkv, w_o, ffn_w1, ffn_w3, ffn_w2, wqT, woT, w13T, w2T,
                       x, norm1_w, h_bf, gamma_w1, gamma_w2, gammab);

    // --- forward pass ---------------------------------------------------------
    hipLaunchKernelGGL((gemm_bb_kernel<64, 1>), dim3(24, 32), dim3(256), 0, stream,
                       h_bf, wqT, qkv_bf, S_LEN, 3 * D_DIM, D_DIM);
    hipLaunchKernelGGL(split_rope_tr_kernel, dim3(S_LEN / 64, H_NUM), dim3(256), 0, stream,
                       qkv_bf, q_norm_w, k_norm_w, qh, kh, khT_s, vhT_s);
    hipLaunchKernelGGL(fused_omega_attn_kernel, dim3(512), dim3(256), 0, stream,
                       qh, kh, khT_s, vhT_s, gammab, m_persist, mem_gate, ao_bf);
    hipLaunchKernelGGL(gemm64_kernel, dim3(16, 32), dim3(256), 0, stream,
                       ao_bf, woT, x, out, S_LEN, D_DIM, D_DIM);
    hipLaunchKernelGGL((rmsnorm_gamma_kernel<false>), dim3(S_LEN), dim3(256), 0, stream,
                       out, norm2_w, h_bf, (const float*)nullptr,
                       (const float*)nullptr, (float*)nullptr);
    // ffn13 GEMM (BM=128) with fused SwiGLU epilogue -> mid
    hipLaunchKernelGGL((gemm_bb_kernel<128, 2>), dim3(44, 16), dim3(256), 0, stream,
                       h_bf, w13T, mid_bf, S_LEN, 2 * FFNP, D_DIM);
    hipLaunchKernelGGL(gemm64_kernel, dim3(16, 32), dim3(256), 0, stream,
                       mid_bf, w2T, out, out, S_LEN, D_DIM, FFNP);
}

// Round 19
// 222.610 us; speedup vs baseline: 1.0348x; 1.0348x over previous
//
#include <hip/hip_runtime.h>
#include <hip/hip_bf16.h>

#define S_LEN 2048
#define D_DIM 1024
#define H_NUM 16
#define HD_DIM 64
#define GH_DIM 64
#define FFN_H 2730
#define FFNP  2816          // FFN_H padded to multiple of 128 (zero-filled)
#define CTX_W 512
#define L2LAM -0.00144341687f   // log2(0.999)
#define QBLK 64
#define KBLK 64
#define ALDK 76             // LDS row stride (152B): write-conflict-free, reads <=2-way
#define QSCALE 0.1803368801111731f  // 0.125 * log2(e): scores come out ready for exp2

typedef unsigned short u16;
typedef __attribute__((ext_vector_type(8))) short bf16x8_t;
typedef __attribute__((ext_vector_type(4))) float f32x4_t;

__device__ inline float wave_sum(float v) {
    for (int off = 32; off; off >>= 1) v += __shfl_xor(v, off);
    return v;
}
// f32 -> bf16 (RNE) via the HW pack instruction: 1 VALU op.
__device__ inline u16 f2bf(float f) {
    unsigned r;
    asm("v_cvt_pk_bf16_f32 %0, %1, %2" : "=v"(r) : "v"(f), "v"(f));
    return (u16)r;
}
// pack two f32 -> u32 of 2 bf16 (lo, hi): 1 VALU op.
__device__ inline unsigned f2bf2(float lo, float hi) {
    unsigned r;
    asm("v_cvt_pk_bf16_f32 %0, %1, %2" : "=v"(r) : "v"(lo), "v"(hi));
    return r;
}
__device__ inline float bf2f(u16 u) {
    return __uint_as_float(((unsigned int)u) << 16);
}
__device__ inline void gload16(const void* g, void* l) {
    __builtin_amdgcn_global_load_lds(
        (const __attribute__((address_space(1))) void*)g,
        (__attribute__((address_space(3))) void*)l, 16, 0, 0);
}

// ------- RMSNorm (fp32 in -> bf16 out), optionally fused gamma gate ---------
template<bool GAMMA>
__global__ __launch_bounds__(256) void rmsnorm_gamma_kernel(
    const float* __restrict__ in, const float* __restrict__ w,
    u16* __restrict__ out, const float* __restrict__ w1,
    const float* __restrict__ w2, float* __restrict__ gamma)
{
    __shared__ float hl[D_DIM];
    __shared__ float part[4][GH_DIM];
    __shared__ float wsum[4];
    int row = blockIdx.x;
    int tid = threadIdx.x, lane = tid & 63, wv = tid >> 6;
    const float4* ir = reinterpret_cast<const float4*>(in + (size_t)row * D_DIM);
    float4 v = ir[tid];
    float ss = v.x*v.x + v.y*v.y + v.z*v.z + v.w*v.w;
    ss = wave_sum(ss);
    if (lane == 0) wsum[wv] = ss;
    __syncthreads();
    float tot = wsum[0] + wsum[1] + wsum[2] + wsum[3];
    float scale = rsqrtf(tot / (float)D_DIM + 1e-6f);
    const float4* wr = reinterpret_cast<const float4*>(w);
    float4 wv4 = wr[tid];
    float h0 = v.x * scale * wv4.x, h1 = v.y * scale * wv4.y;
    float h2 = v.z * scale * wv4.z, h3 = v.w * scale * wv4.w;
    uint2 o;
    o.x = f2bf2(h0, h1);
    o.y = f2bf2(h2, h3);
    *reinterpret_cast<uint2*>(out + (size_t)row * D_DIM + tid * 4) = o;
    if (GAMMA) {
        hl[tid*4+0] = h0; hl[tid*4+1] = h1; hl[tid*4+2] = h2; hl[tid*4+3] = h3;
        __syncthreads();
        float acc = 0.f;
        #pragma unroll 8
        for (int k = wv * 256; k < wv * 256 + 256; ++k)
            acc += hl[k] * w1[k * GH_DIM + lane];
        part[wv][lane] = acc;
        __syncthreads();
        if (wv == 0) {
            float t = part[0][lane] + part[1][lane] + part[2][lane] + part[3][lane];
            float z = t / (1.f + __expf(-t));
            float y = z * w2[lane];
            float t2 = wave_sum(y);
            if (lane == 0) gamma[row] = 1.f / (1.f + __expf(-t2));
        }
    }
}

// --- prep: weight transposes (64x64 tiles, 128B writes) + rmsnorm1+gamma ----
__global__ __launch_bounds__(256) void prep_kernel(
    const float* __restrict__ w_qkv, const float* __restrict__ w_o,
    const float* __restrict__ w1f, const float* __restrict__ w3f,
    const float* __restrict__ w2f, u16* __restrict__ wqT,
    u16* __restrict__ woT, u16* __restrict__ w13T, u16* __restrict__ w2T,
    const float* __restrict__ x, const float* __restrict__ norm1_w,
    u16* __restrict__ h_bf, const float* __restrict__ gw1,
    const float* __restrict__ gw2, float* __restrict__ gamma)
{
    __shared__ float tile[64][65];
    __shared__ float part[4][GH_DIM];
    __shared__ float wsum[4];
    int b = blockIdx.x;
    int tid = threadIdx.x;
    if (b < 3136) {
        const float* src; u16* dst;
        int srcK, srcN, Kp, rowOff, rowMul, nbx;
        if (b < 768)       {           src = w_qkv; dst = wqT;  srcK = 1024; srcN = 3072; Kp = 1024; rowOff = 0; rowMul = 1; nbx = 48; }
        else if (b < 1024) { b -= 768;  src = w_o;  dst = woT;  srcK = 1024; srcN = 1024; Kp = 1024; rowOff = 0; rowMul = 1; nbx = 16; }
        else if (b < 1728) { b -= 1024; src = w1f;  dst = w13T; srcK = 1024; srcN = 2730; Kp = 1024; rowOff = 0; rowMul = 2; nbx = 44; }
        else if (b < 2432) { b -= 1728; src = w3f;  dst = w13T; srcK = 1024; srcN = 2730; Kp = 1024; rowOff = 1; rowMul = 2; nbx = 44; }
        else               { b -= 2432; src = w2f;  dst = w2T;  srcK = 2730; srcN = 1024; Kp = 2816; rowOff = 0; rowMul = 1; nbx = 16; }
        int n0 = (b % nbx) * 64, k0 = (b / nbx) * 64;
        int tx = tid & 15, ty = tid >> 4;       // read: 16 thr/row x float4
        bool interior = (k0 + 63 < srcK) && (n0 + 63 < srcN);
        #pragma unroll
        for (int p = 0; p < 4; ++p) {
            int kk = p * 16 + ty;
            int r = k0 + kk;
            int cb = n0 + tx * 4;
            float4 v;
            if (interior) {
                v = *(const float4*)(src + (size_t)r * srcN + cb);
            } else {
                v.x = (r < srcK && cb     < srcN) ? src[(size_t)r * srcN + cb]     : 0.f;
                v.y = (r < srcK && cb + 1 < srcN) ? src[(size_t)r * srcN + cb + 1] : 0.f;
                v.z = (r < srcK && cb + 2 < srcN) ? src[(size_t)r * srcN + cb + 2] : 0.f;
                v.w = (r < srcK && cb + 3 < srcN) ? src[(size_t)r * srcN + cb + 3] : 0.f;
            }
            tile[kk][tx*4+0] = v.x; tile[kk][tx*4+1] = v.y;
            tile[kk][tx*4+2] = v.z; tile[kk][tx*4+3] = v.w;
        }
        __syncthreads();
        int wx = tid & 7, wy = tid >> 3;        // write: 8 thr/row x uint4(8 u16)
        #pragma unroll
        for (int p = 0; p < 2; ++p) {
            int nn = p * 32 + wy;
            int ks = wx * 8;
            uint4 o;
            o.x = f2bf2(tile[ks+0][nn], tile[ks+1][nn]);
            o.y = f2bf2(tile[ks+2][nn], tile[ks+3][nn]);
            o.z = f2bf2(tile[ks+4][nn], tile[ks+5][nn]);
            o.w = f2bf2(tile[ks+6][nn], tile[ks+7][nn]);
            *(uint4*)(dst + (size_t)(rowOff + (size_t)(n0 + nn) * rowMul) * Kp + k0 + ks) = o;
        }
    } else {
        int row = b - 3136;
        int lane = tid & 63, wv = tid >> 6;
        float* hl = &tile[0][0];
        const float4* ir = reinterpret_cast<const float4*>(x + (size_t)row * D_DIM);
        float4 v = ir[tid];
        float ss = v.x*v.x + v.y*v.y + v.z*v.z + v.w*v.w;
        ss = wave_sum(ss);
        if (lane == 0) wsum[wv] = ss;
        __syncthreads();
        float tot = wsum[0] + wsum[1] + wsum[2] + wsum[3];
        float scale = rsqrtf(tot / (float)D_DIM + 1e-6f);
        const float4* wr = reinterpret_cast<const float4*>(norm1_w);
        float4 wv4 = wr[tid];
        float h0 = v.x * scale * wv4.x, h1 = v.y * scale * wv4.y;
        float h2 = v.z * scale * wv4.z, h3 = v.w * scale * wv4.w;
        uint2 o;
        o.x = f2bf2(h0, h1);
        o.y = f2bf2(h2, h3);
        *reinterpret_cast<uint2*>(h_bf + (size_t)row * D_DIM + tid * 4) = o;
        hl[tid*4+0] = h0; hl[tid*4+1] = h1; hl[tid*4+2] = h2; hl[tid*4+3] = h3;
        __syncthreads();
        float acc = 0.f;
        #pragma unroll 8
        for (int k = wv * 256; k < wv * 256 + 256; ++k)
            acc += hl[k] * gw1[k * GH_DIM + lane];
        part[wv][lane] = acc;
        __syncthreads();
        if (wv == 0) {
            float t = part[0][lane] + part[1][lane] + part[2][lane] + part[3][lane];
            float z = t / (1.f + __expf(-t));
            float y = z * gw2[lane];
            float t2 = wave_sum(y);
            if (lane == 0) gamma[row] = 1.f / (1.f + __expf(-t2));
        }
    }
}

// ---- fused split qkv + qk rmsnorm + RoPE + KV transpose (one launch) -------
__global__ __launch_bounds__(256) void split_rope_tr_kernel(
    const u16* __restrict__ qkv, const float* __restrict__ qw,
    const float* __restrict__ kw, float* __restrict__ qhp,
    u16* __restrict__ khp, u16* __restrict__ khT, u16* __restrict__ vhT)
{
    __shared__ u16 tk[64][ALDK];
    __shared__ u16 tv[64][ALDK];
    int tid = threadIdx.x;
    int w = tid >> 6, d = tid & 63;
    int h = blockIdx.y;
    int s0 = blockIdx.x * 64;
    float qwv = qw[d], kwv = kw[d];
    int j = d & 31;
    float inv = expf(-(float)j * (9.2103403719761836f / 32.0f));
    float sgn = (d < 32) ? -1.f : 1.f;
    for (int i = 0; i < 16; ++i) {
        int sl = w * 16 + i;
        int s = s0 + sl;
        size_t base = (size_t)s * (3 * D_DIM) + h * HD_DIM + d;
        float qv = bf2f(qkv[base]);
        float kv = bf2f(qkv[base + D_DIM]);
        u16  vv = qkv[base + 2 * D_DIM];
        float sq = wave_sum(qv * qv);
        float qn = qv * rsqrtf(sq / (float)HD_DIM + 1e-6f) * qwv;
        float sk = wave_sum(kv * kv);
        float kn = kv * rsqrtf(sk / (float)HD_DIM + 1e-6f) * kwv;
        float ang = (float)s * inv;
        float cs = cosf(ang), sn = sinf(ang);
        float qp = __shfl_xor(qn, 32);
        float kp = __shfl_xor(kn, 32);
        float qo = qn * cs + sgn * qp * sn;
        float ko = kn * cs + sgn * kp * sn;
        size_t ob = ((size_t)h * S_LEN + s) * HD_DIM + d;
        u16 kb = f2bf(ko);
        qhp[ob] = qo;
        khp[ob] = kb;
        tk[sl][d] = kb;
        tv[sl][d] = vv;
    }
    __syncthreads();
    int r = tid >> 2, cc = (tid & 3) * 16;
    union { u16 u[16]; bf16x8_t v[2]; } ok, ov;
    #pragma unroll
    for (int e = 0; e < 16; ++e) {
        int ksrc = (e & 3) * 16 + (tid & 3) * 4 + (e >> 2);   // pi^-1 permute
        ok.u[e] = tk[ksrc][r]; ov.u[e] = tv[ksrc][r];
    }
    u16* kd = khT + ((size_t)h * HD_DIM + r) * S_LEN + s0 + cc;
    u16* vd = vhT + ((size_t)h * HD_DIM + r) * S_LEN + s0 + cc;
    *(bf16x8_t*)kd       = ok.v[0];
    *(bf16x8_t*)(kd + 8) = ok.v[1];
    *(bf16x8_t*)vd       = ov.v[0];
    *(bf16x8_t*)(vd + 8) = ov.v[1];
}

// ---------------- bf16 MFMA GEMM, 128-col tiles ------------------------------
// MODE 1: bf16 out.  MODE 2: paired silu-mul, bf16 out width N/2.
template<int BM, int MODE>
__global__ __launch_bounds__(256) void gemm_bb_kernel(
    const u16* __restrict__ A, const u16* __restrict__ B,
    u16* __restrict__ Cb, int M, int N, int K)
{
    constexpr int MREP = BM / 32;
    constexpr int ACH  = BM / 32;
    __shared__ u16 As[BM * 64];
    __shared__ u16 Bs[128 * 64];
    int tid = threadIdx.x, lane = tid & 63, wid = tid >> 6;
    int wr = wid >> 1, wc = wid & 1;
    int row0 = blockIdx.y * BM, col0 = blockIdx.x * 128;
    int l8 = lane >> 3, l7 = lane & 7;
    f32x4_t acc[MREP][4];
    #pragma unroll
    for (int i = 0; i < MREP; ++i)
        #pragma unroll
        for (int j = 0; j < 4; ++j) acc[i][j] = (f32x4_t)0.f;

    int fr = lane & 15, fo = (lane >> 4) * 8;
    for (int k0 = 0; k0 < K; k0 += 64) {
        #pragma unroll
        for (int i = 0; i < ACH; ++i) {
            int ch = wid * ACH + i;
            const u16* ga = A + (size_t)(row0 + ch * 8 + l8) * K + k0 + l7 * 8;
            gload16(ga, &As[ch * 512]);
        }
        #pragma unroll
        for (int i = 0; i < 4; ++i) {
            int ch = wid * 4 + i;
            const u16* gb = B + (size_t)(col0 + ch * 8 + l8) * K + k0 + l7 * 8;
            gload16(gb, &Bs[ch * 512]);
        }
        __syncthreads();
        __builtin_amdgcn_s_setprio(1);
        #pragma unroll
        for (int khf = 0; khf < 2; ++khf) {
            bf16x8_t bfrag[4];
            #pragma unroll
            for (int ni = 0; ni < 4; ++ni)
                bfrag[ni] = *(const bf16x8_t*)&Bs[(wc * 64 + ni * 16 + fr) * 64 + khf * 32 + fo];
            #pragma unroll
            for (int mi = 0; mi < MREP; ++mi) {
                bf16x8_t af = *(const bf16x8_t*)&As[(wr * (BM / 2) + mi * 16 + fr) * 64 + khf * 32 + fo];
                #pragma unroll
                for (int ni = 0; ni < 4; ++ni)
                    acc[mi][ni] = __builtin_amdgcn_mfma_f32_16x16x32_bf16(
                        af, bfrag[ni], acc[mi][ni], 0, 0, 0);
            }
        }
        __builtin_amdgcn_s_setprio(0);
        __syncthreads();
    }
    int dr = (lane >> 4) * 4, dc = lane & 15;
    #pragma unroll
    for (int mi = 0; mi < MREP; ++mi) {
        int gr = row0 + wr * (BM / 2) + mi * 16 + dr;
        #pragma unroll
        for (int ni = 0; ni < 4; ++ni) {
            int gc = col0 + wc * 64 + ni * 16 + dc;
            #pragma unroll
            for (int j = 0; j < 4; ++j) {
                float v = acc[mi][ni][j];
                if (MODE == 1) {
                    Cb[(size_t)(gr + j) * N + gc] = f2bf(v);
                } else {
                    float partner = __shfl_xor(v, 1);
                    float a1 = (dc & 1) ? partner : v;
                    float a3 = (dc & 1) ? v : partner;
                    float rr = a1 / (1.f + __expf(-a1)) * a3;
                    if (!(dc & 1))
                        Cb[(size_t)(gr + j) * (N >> 1) + (gc >> 1)] = f2bf(rr);
                }
            }
        }
    }
}

// ---------------- bf16 MFMA GEMM, 64x64 tiles, fp32 out + residual ----------
// (BK=64: the R18 BK=128 variant regressed -- 256B LDS row stride serialized
// the b128 fragment reads; this layout measures 0 bank conflicts.)
__global__ __launch_bounds__(256) void gemm64_kernel(
    const u16* __restrict__ A, const u16* __restrict__ B,
    const float* __restrict__ res, float* __restrict__ Cf,
    int M, int N, int K)
{
    __shared__ u16 As[64 * 64];
    __shared__ u16 Bs[64 * 64];
    int tid = threadIdx.x, lane = tid & 63, wid = tid >> 6;
    int wr = wid >> 1, wc = wid & 1;
    int row0 = blockIdx.y * 64, col0 = blockIdx.x * 64;
    int l8 = lane >> 3, l7 = lane & 7;
    f32x4_t acc[2][2];
    #pragma unroll
    for (int i = 0; i < 2; ++i)
        #pragma unroll
        for (int j = 0; j < 2; ++j) acc[i][j] = (f32x4_t)0.f;
    int fr = lane & 15, fo = (lane >> 4) * 8;
    for (int k0 = 0; k0 < K; k0 += 64) {
        #pragma unroll
        for (int i = 0; i < 2; ++i) {
            int ch = wid * 2 + i;
            const u16* ga = A + (size_t)(row0 + ch * 8 + l8) * K + k0 + l7 * 8;
            gload16(ga, &As[ch * 512]);
            const u16* gb = B + (size_t)(col0 + ch * 8 + l8) * K + k0 + l7 * 8;
            gload16(gb, &Bs[ch * 512]);
        }
        __syncthreads();
        __builtin_amdgcn_s_setprio(1);
        #pragma unroll
        for (int khf = 0; khf < 2; ++khf) {
            bf16x8_t bfrag[2];
            #pragma unroll
            for (int ni = 0; ni < 2; ++ni)
                bfrag[ni] = *(const bf16x8_t*)&Bs[(wc * 32 + ni * 16 + fr) * 64 + khf * 32 + fo];
            #pragma unroll
            for (int mi = 0; mi < 2; ++mi) {
                bf16x8_t af = *(const bf16x8_t*)&As[(wr * 32 + mi * 16 + fr) * 64 + khf * 32 + fo];
                #pragma unroll
                for (int ni = 0; ni < 2; ++ni)
                    acc[mi][ni] = __builtin_amdgcn_mfma_f32_16x16x32_bf16(
                        af, bfrag[ni], acc[mi][ni], 0, 0, 0);
            }
        }
        __builtin_amdgcn_s_setprio(0);
        __syncthreads();
    }
    int dr = (lane >> 4) * 4, dc = lane & 15;
    #pragma unroll
    for (int mi = 0; mi < 2; ++mi) {
        int gr = row0 + wr * 32 + mi * 16 + dr;
        #pragma unroll
        for (int ni = 0; ni < 2; ++ni) {
            int gc = col0 + wc * 32 + ni * 16 + dc;
            #pragma unroll
            for (int j = 0; j < 4; ++j) {
                size_t off = (size_t)(gr + j) * N + gc;
                Cf[off] = acc[mi][ni][j] + res[off];
            }
        }
    }
}

// ============ FUSED omega-rule + flash attention ============================
__global__ __launch_bounds__(256) void fused_omega_attn_kernel(
    const float* __restrict__ qhp, const u16* __restrict__ khp,
    const u16* __restrict__ khT, const u16* __restrict__ vhT,
    const float* __restrict__ gammab, const float* __restrict__ mp,
    const float* __restrict__ mg, u16* __restrict__ ao)
{
    __shared__ u16 Ks[2][KBLK][ALDK];
    __shared__ u16 Xt[2][KBLK][ALDK];
    __shared__ u16 Ps[QBLK][ALDK];
    __shared__ float colfL[CTX_W + KBLK];
    const int tid = threadIdx.x, lane = tid & 63, wq = tid >> 6;
    const int b = blockIdx.x;
    const int hi = (b >> 8) & 1;
    const int h = ((b & 7) << 1) + hi;
    const int s5 = (b >> 3) & 31;
    const int qt = hi ? (31 - s5) : s5;
    const int q0 = qt * QBLK;
    const int fr = lane & 15, g4 = lane >> 4;
    const int fko = g4 * 8;
    const int c = fr, rg = g4;
    const int si = tid >> 2, sdb = (tid & 3) * 16;
    const size_t hS = (size_t)h * S_LEN;
    const size_t hD = (size_t)h * HD_DIM;

    int rowt[4]; float rowf[4];
    #pragma unroll
    for (int j = 0; j < 4; ++j) {
        rowt[j] = q0 + wq * 16 + rg * 4 + j;
        rowf[j] = exp2f((float)(wq * 16 + rg * 4 + j) * L2LAM);
    }
    bf16x8_t qf[2];
    {
        const float* qrow = qhp + (hS + q0 + wq * 16 + fr) * HD_DIM;
        #pragma unroll
        for (int u = 0; u < 2; ++u) {
            float4 a = *(const float4*)(qrow + u * 32 + fko);
            float4 bq = *(const float4*)(qrow + u * 32 + fko + 4);
            bf16x8_t f;
            f[0]=f2bf(a.x); f[1]=f2bf(a.y); f[2]=f2bf(a.z); f[3]=f2bf(a.w);
            f[4]=f2bf(bq.x); f[5]=f2bf(bq.y); f[6]=f2bf(bq.z); f[7]=f2bf(bq.w);
            qf[u] = f;
        }
    }
    // preload q_old in C-layout (hides latency under the omega loop)
    float qold[4][4];
    #pragma unroll
    for (int n = 0; n < 4; ++n)
        #pragma unroll
        for (int j = 0; j < 4; ++j)
            qold[n][j] = qhp[(hS + rowt[j]) * HD_DIM + n * 16 + c];

    // ---------------- omega phase (double-buffered) ----------------
    f32x4_t accc[4];
    #pragma unroll
    for (int n = 0; n < 4; ++n) accc[n] = (f32x4_t)0.f;
    float wsum[4] = {0.f, 0.f, 0.f, 0.f};
    const int kt0 = (q0 > (CTX_W - 1)) ? (q0 - (CTX_W - 1)) / KBLK : 0;
    const int i0 = kt0 * KBLK;
    const int nwin = (qt + 1) * KBLK - i0;
    for (int idx = tid; idx < nwin; idx += 256) {
        int icol = i0 + idx;
        colfL[idx] = exp2f((float)(q0 - icol) * L2LAM) * gammab[icol];
    }
    {
        const u16* gk = khp + (hS + kt0 * KBLK + si) * HD_DIM + sdb;
        const u16* gx = khT + (hD + si) * S_LEN + kt0 * KBLK + sdb;
        *(bf16x8_t*)&Ks[0][si][sdb]     = *(const bf16x8_t*)gk;
        *(bf16x8_t*)&Ks[0][si][sdb + 8] = *(const bf16x8_t*)(gk + 8);
        *(bf16x8_t*)&Xt[0][si][sdb]     = *(const bf16x8_t*)gx;
        *(bf16x8_t*)&Xt[0][si][sdb + 8] = *(const bf16x8_t*)(gx + 8);
    }
    __syncthreads();
    int cur = 0;
    for (int kt = kt0; kt <= qt; ++kt) {
        const int k0 = kt * KBLK;
        const bool hn = (kt < qt);
        bf16x8_t nk0, nk1, nx0, nx1;
        if (hn) {
            const u16* gk = khp + (hS + k0 + KBLK + si) * HD_DIM + sdb;
            const u16* gx = khT + (hD + si) * S_LEN + k0 + KBLK + sdb;
            nk0 = *(const bf16x8_t*)gk; nk1 = *(const bf16x8_t*)(gk + 8);
            nx0 = *(const bf16x8_t*)gx; nx1 = *(const bf16x8_t*)(gx + 8);
        }
        f32x4_t s[4];
        #pragma unroll
        for (int n = 0; n < 4; ++n) s[n] = (f32x4_t)0.f;
        __builtin_amdgcn_s_setprio(1);
        #pragma unroll
        for (int u = 0; u < 2; ++u)
            #pragma unroll
            for (int n = 0; n < 4; ++n) {
                bf16x8_t kb = *(const bf16x8_t*)&Ks[cur][n * 16 + fr][u * 32 + fko];
                s[n] = __builtin_amdgcn_mfma_f32_16x16x32_bf16(qf[u], kb, s[n], 0, 0, 0);
            }
        __builtin_amdgcn_s_setprio(0);
        const bool boundary = (kt == kt0) || (kt == qt);
        float colf[4];
        #pragma unroll
        for (int n = 0; n < 4; ++n)
            colf[n] = colfL[k0 - i0 + n * 16 + c];
        #pragma unroll
        for (int j = 0; j < 4; ++j) {
            float pv[4];
            #pragma unroll
            for (int n = 0; n < 4; ++n) {
                float w;
                if (boundary) {
                    int delta = rowt[j] - (k0 + n * 16 + c);
                    w = (delta >= 0 && delta < CTX_W) ? rowf[j] * colf[n] : 0.f;
                } else {
                    w = rowf[j] * colf[n];
                }
                wsum[j] += w;
                pv[n] = w * s[n][j];
            }
            uint2 pk;
            pk.x = f2bf2(pv[0], pv[1]);
            pk.y = f2bf2(pv[2], pv[3]);
            *(uint2*)&Ps[wq * 16 + rg * 4 + j][c * 4] = pk;   // ds_write_b64
        }
        __builtin_amdgcn_s_setprio(1);
        #pragma unroll
        for (int u = 0; u < 2; ++u) {
            bf16x8_t pa = *(const bf16x8_t*)&Ps[wq * 16 + fr][u * 32 + fko];
            #pragma unroll
            for (int n = 0; n < 4; ++n) {
                bf16x8_t kb = *(const bf16x8_t*)&Xt[cur][n * 16 + fr][u * 32 + fko];
                accc[n] = __builtin_amdgcn_mfma_f32_16x16x32_bf16(pa, kb, accc[n], 0, 0, 0);
            }
        }
        __builtin_amdgcn_s_setprio(0);
        if (hn) {
            int nxt = cur ^ 1;
            *(bf16x8_t*)&Ks[nxt][si][sdb]     = nk0;
            *(bf16x8_t*)&Ks[nxt][si][sdb + 8] = nk1;
            *(bf16x8_t*)&Xt[nxt][si][sdb]     = nx0;
            *(bf16x8_t*)&Xt[nxt][si][sdb + 8] = nx1;
        }
        __syncthreads();
        cur ^= 1;
    }
    // persist = Q @ M_p^T
    f32x4_t pacc[4];
    #pragma unroll
    for (int n = 0; n < 4; ++n) pacc[n] = (f32x4_t)0.f;
    const float* mph = mp + hD * HD_DIM;
    #pragma unroll
    for (int u = 0; u < 2; ++u)
        #pragma unroll
        for (int n = 0; n < 4; ++n) {
            const float* br = mph + (size_t)(n * 16 + fr) * HD_DIM + u * 32 + fko;
            float4 a = *(const float4*)br;
            float4 bq = *(const float4*)(br + 4);
            bf16x8_t f;
            f[0]=f2bf(a.x); f[1]=f2bf(a.y); f[2]=f2bf(a.z); f[3]=f2bf(a.w);
            f[4]=f2bf(bq.x); f[5]=f2bf(bq.y); f[6]=f2bf(bq.z); f[7]=f2bf(bq.w);
            pacc[n] = __builtin_amdgcn_mfma_f32_16x16x32_bf16(qf[u], f, pacc[n], 0, 0, 0);
        }
    #pragma unroll
    for (int j = 0; j < 4; ++j) {
        wsum[j] += __shfl_xor(wsum[j], 1);
        wsum[j] += __shfl_xor(wsum[j], 2);
        wsum[j] += __shfl_xor(wsum[j], 4);
        wsum[j] += __shfl_xor(wsum[j], 8);
    }
    float gate = 1.f / (1.f + __expf(-mg[0]));
    float keep = 1.f - gate;
    #pragma unroll
    for (int n = 0; n < 4; ++n) {
        #pragma unroll
        for (int j = 0; j < 4; ++j) {
            float qn = keep * qold[n][j] + gate * (pacc[n][j] + accc[n][j]) / (1.f + wsum[j]);
            Ps[wq * 16 + rg * 4 + j][n * 16 + c] = f2bf(qn * QSCALE);
        }
    }
    bf16x8_t qf2[2];
    #pragma unroll
    for (int u = 0; u < 2; ++u)
        qf2[u] = *(const bf16x8_t*)&Ps[wq * 16 + fr][u * 32 + fko];

    // ---------------- attention phase (double-buffered, no-max softmax) -----
    f32x4_t acco[4];
    #pragma unroll
    for (int n = 0; n < 4; ++n) acco[n] = (f32x4_t)0.f;
    float l_run[4] = {0.f, 0.f, 0.f, 0.f};
    {
        const u16* gk = khp + (hS + si) * HD_DIM + sdb;
        const u16* gv = vhT + (hD + si) * S_LEN + sdb;
        *(bf16x8_t*)&Ks[0][si][sdb]     = *(const bf16x8_t*)gk;
        *(bf16x8_t*)&Ks[0][si][sdb + 8] = *(const bf16x8_t*)(gk + 8);
        *(bf16x8_t*)&Xt[0][si][sdb]     = *(const bf16x8_t*)gv;
        *(bf16x8_t*)&Xt[0][si][sdb + 8] = *(const bf16x8_t*)(gv + 8);
    }
    __syncthreads();
    cur = 0;
    for (int kt = 0; kt <= qt; ++kt) {
        const int k0 = kt * KBLK;
        const bool hn = (kt < qt);
        bf16x8_t nk0, nk1, nv0, nv1;
        if (hn) {
            const u16* gk = khp + (hS + k0 + KBLK + si) * HD_DIM + sdb;
            const u16* gv = vhT + (hD + si) * S_LEN + k0 + KBLK + sdb;
            nk0 = *(const bf16x8_t*)gk; nk1 = *(const bf16x8_t*)(gk + 8);
            nv0 = *(const bf16x8_t*)gv; nv1 = *(const bf16x8_t*)(gv + 8);
        }
        f32x4_t s[4];
        #pragma unroll
        for (int n = 0; n < 4; ++n) s[n] = (f32x4_t)0.f;
        __builtin_amdgcn_s_setprio(1);
        #pragma unroll
        for (int u = 0; u < 2; ++u)
            #pragma unroll
            for (int n = 0; n < 4; ++n) {
                bf16x8_t kb = *(const bf16x8_t*)&Ks[cur][n * 16 + fr][u * 32 + fko];
                s[n] = __builtin_amdgcn_mfma_f32_16x16x32_bf16(qf2[u], kb, s[n], 0, 0, 0);
            }
        __builtin_amdgcn_s_setprio(0);
        if (kt == qt) {
            #pragma unroll
            for (int n = 0; n < 4; ++n) {
                int icol = k0 + n * 16 + c;
                #pragma unroll
                for (int j = 0; j < 4; ++j)
                    if (icol > rowt[j]) s[n][j] = -1e30f;
            }
        }
        #pragma unroll
        for (int j = 0; j < 4; ++j) {
            float p0 = exp2f(s[0][j]);
            float p1 = exp2f(s[1][j]);
            float p2 = exp2f(s[2][j]);
            float p3 = exp2f(s[3][j]);
            l_run[j] += (p0 + p1) + (p2 + p3);
            uint2 pk;
            pk.x = f2bf2(p0, p1);
            pk.y = f2bf2(p2, p3);
            *(uint2*)&Ps[wq * 16 + rg * 4 + j][c * 4] = pk;   // ds_write_b64
        }
        __builtin_amdgcn_s_setprio(1);
        #pragma unroll
        for (int u = 0; u < 2; ++u) {
            bf16x8_t pa = *(const bf16x8_t*)&Ps[wq * 16 + fr][u * 32 + fko];
            #pragma unroll
            for (int n = 0; n < 4; ++n) {
                bf16x8_t vb = *(const bf16x8_t*)&Xt[cur][n * 16 + fr][u * 32 + fko];
                acco[n] = __builtin_amdgcn_mfma_f32_16x16x32_bf16(pa, vb, acco[n], 0, 0, 0);
            }
        }
        __builtin_amdgcn_s_setprio(0);
        if (hn) {
            int nxt = cur ^ 1;
            *(bf16x8_t*)&Ks[nxt][si][sdb]     = nk0;
            *(bf16x8_t*)&Ks[nxt][si][sdb + 8] = nk1;
            *(bf16x8_t*)&Xt[nxt][si][sdb]     = nv0;
            *(bf16x8_t*)&Xt[nxt][si][sdb + 8] = nv1;
        }
        __syncthreads();
        cur ^= 1;
    }
    #pragma unroll
    for (int j = 0; j < 4; ++j) {
        l_run[j] += __shfl_xor(l_run[j], 1);
        l_run[j] += __shfl_xor(l_run[j], 2);
        l_run[j] += __shfl_xor(l_run[j], 4);
        l_run[j] += __shfl_xor(l_run[j], 8);
    }
    #pragma unroll
    for (int n = 0; n < 4; ++n) {
        #pragma unroll
        for (int j = 0; j < 4; ++j) {
            float o = acco[n][j] / l_run[j];
            ao[(size_t)rowt[j] * D_DIM + h * HD_DIM + n * 16 + c] = f2bf(o);
        }
    }
}

extern "C" void kernel_launch(void* const* d_in, const int* in_sizes, int n_in,
                              void* d_out, int out_size, void* d_ws, size_t ws_size,
                              hipStream_t stream) {
    const float* x         = (const float*)d_in[0];
    const float* norm1_w   = (const float*)d_in[1];
    const float* norm2_w   = (const float*)d_in[2];
    const float* w_qkv     = (const float*)d_in[3];
    const float* q_norm_w  = (const float*)d_in[4];
    const float* k_norm_w  = (const float*)d_in[5];
    const float* gamma_w1  = (const float*)d_in[6];
    const float* gamma_w2  = (const float*)d_in[7];
    const float* m_persist = (const float*)d_in[8];
    const float* mem_gate  = (const float*)d_in[9];
    const float* w_o       = (const float*)d_in[10];
    const float* ffn_w1    = (const float*)d_in[11];
    const float* ffn_w3    = (const float*)d_in[12];
    const float* ffn_w2    = (const float*)d_in[13];
    float* out = (float*)d_out;
    char* ws = (char*)d_ws;

    const size_t MB = 1024 * 1024;
    u16*   h_bf   = (u16*)(ws);                 // [0,4MB) h / h2
    u16*   wqT    = (u16*)(ws + 4 * MB);        // [4,10)
    u16*   woT    = (u16*)(ws + 10 * MB);       // [10,12)
    u16*   w13T   = (u16*)(ws + 12 * MB);       // [12,23) interleaved w1/w3
    u16*   w2T    = (u16*)(ws + 23 * MB);       // [23,28.5)
    u16*   qkv_bf = (u16*)(ws + 29884416);      // [28.5,40.5) dead after split
    u16*   ao_bf  = (u16*)(ws + 38273024);      // [36.5,40.5) (after qkv dead)
    float* qh     = (float*)(ws + 42467328);    // [40.5,48.5) fp32 q
    u16*   kh     = (u16*)(ws + 50855936);      // [48.5,52.5)
    u16*   khT_s  = (u16*)(ws + 50855936 + 4 * MB);   // [52.5,56.5)
    float* gammab = (float*)(ws + 59244544);    // [56.5,+8KB)
    u16*   vhT_s  = (u16*)(ws + 59244544 + 64 * 1024); // [56.5+64KB,+4MB)
    u16*   mid_bf = (u16*)(ws + 29884416);      // [28.5,40) post-attention

    // --- prep: weight transposes + rmsnorm1 + gamma, ONE launch --------------
    hipLaunchKernelGGL(prep_kernel, dim3(3136 + S_LEN), dim3(256), 0, stream,
                       w_qkv, w_o, ffn_w1, ffn_w3, ffn_w2, wqT, woT, w13T, w2T,
                       x, norm1_w, h_bf, gamma_w1, gamma_w2, gammab);

    // --- forward pass ---------------------------------------------------------
    hipLaunchKernelGGL((gemm_bb_kernel<64, 1>), dim3(24, 32), dim3(256), 0, stream,
                       h_bf, wqT, qkv_bf, S_LEN, 3 * D_DIM, D_DIM);
    hipLaunchKernelGGL(split_rope_tr_kernel, dim3(S_LEN / 64, H_NUM), dim3(256), 0, stream,
                       qkv_bf, q_norm_w, k_norm_w, qh, kh, khT_s, vhT_s);
    hipLaunchKernelGGL(fused_omega_attn_kernel, dim3(512), dim3(256), 0, stream,
                       qh, kh, khT_s, vhT_s, gammab, m_persist, mem_gate, ao_bf);
    hipLaunchKernelGGL(gemm64_kernel, dim3(16, 32), dim3(256), 0, stream,
                       ao_bf, woT, x, out, S_LEN, D_DIM, D_DIM);
    hipLaunchKernelGGL((rmsnorm_gamma_kernel<false>), dim3(S_LEN), dim3(256), 0, stream,
                       out, norm2_w, h_bf, (const float*)nullptr,
                       (const float*)nullptr, (float*)nullptr);
    // ffn13 GEMM (BM=128) with fused SwiGLU epilogue -> mid
    hipLaunchKernelGGL((gemm_bb_kernel<128, 2>), dim3(44, 16), dim3(256), 0, stream,
                       h_bf, w13T, mid_bf, S_LEN, 2 * FFNP, D_DIM);
    hipLaunchKernelGGL(gemm64_kernel, dim3(16, 32), dim3(256), 0, stream,
                       mid_bf, w2T, out, out, S_LEN, D_DIM, FFNP);
}

// Round 20
// 222.599 us; speedup vs baseline: 1.0348x; 1.0001x over previous
//
#include <hip/hip_runtime.h>
#include <hip/hip_bf16.h>

#define S_LEN 2048
#define D_DIM 1024
#define H_NUM 16
#define HD_DIM 64
#define GH_DIM 64
#define FFN_H 2730
#define FFNP  2816          // FFN_H padded to multiple of 128 (zero-filled)
#define CTX_W 512
#define L2LAM -0.00144341687f   // log2(0.999)
#define QBLK 64
#define KBLK 64
#define ALDK 76             // LDS row stride (152B): write-conflict-free, reads <=2-way
#define QSCALE 0.1803368801111731f  // 0.125 * log2(e): scores come out ready for exp2

typedef unsigned short u16;
typedef __attribute__((ext_vector_type(8))) short bf16x8_t;
typedef __attribute__((ext_vector_type(4))) float f32x4_t;

__device__ inline float wave_sum(float v) {
    for (int off = 32; off; off >>= 1) v += __shfl_xor(v, off);
    return v;
}
// f32 -> bf16 (RNE) via the HW pack instruction: 1 VALU op.
__device__ inline u16 f2bf(float f) {
    unsigned r;
    asm("v_cvt_pk_bf16_f32 %0, %1, %2" : "=v"(r) : "v"(f), "v"(f));
    return (u16)r;
}
// pack two f32 -> u32 of 2 bf16 (lo, hi): 1 VALU op.
__device__ inline unsigned f2bf2(float lo, float hi) {
    unsigned r;
    asm("v_cvt_pk_bf16_f32 %0, %1, %2" : "=v"(r) : "v"(lo), "v"(hi));
    return r;
}
__device__ inline float bf2f(u16 u) {
    return __uint_as_float(((unsigned int)u) << 16);
}
__device__ inline void gload16(const void* g, void* l) {
    __builtin_amdgcn_global_load_lds(
        (const __attribute__((address_space(1))) void*)g,
        (__attribute__((address_space(3))) void*)l, 16, 0, 0);
}

// ------- RMSNorm (fp32 in -> bf16 out), optionally fused gamma gate ---------
template<bool GAMMA>
__global__ __launch_bounds__(256) void rmsnorm_gamma_kernel(
    const float* __restrict__ in, const float* __restrict__ w,
    u16* __restrict__ out, const float* __restrict__ w1,
    const float* __restrict__ w2, float* __restrict__ gamma)
{
    __shared__ float hl[D_DIM];
    __shared__ float part[4][GH_DIM];
    __shared__ float wsum[4];
    int row = blockIdx.x;
    int tid = threadIdx.x, lane = tid & 63, wv = tid >> 6;
    const float4* ir = reinterpret_cast<const float4*>(in + (size_t)row * D_DIM);
    float4 v = ir[tid];
    float ss = v.x*v.x + v.y*v.y + v.z*v.z + v.w*v.w;
    ss = wave_sum(ss);
    if (lane == 0) wsum[wv] = ss;
    __syncthreads();
    float tot = wsum[0] + wsum[1] + wsum[2] + wsum[3];
    float scale = rsqrtf(tot / (float)D_DIM + 1e-6f);
    const float4* wr = reinterpret_cast<const float4*>(w);
    float4 wv4 = wr[tid];
    float h0 = v.x * scale * wv4.x, h1 = v.y * scale * wv4.y;
    float h2 = v.z * scale * wv4.z, h3 = v.w * scale * wv4.w;
    uint2 o;
    o.x = f2bf2(h0, h1);
    o.y = f2bf2(h2, h3);
    *reinterpret_cast<uint2*>(out + (size_t)row * D_DIM + tid * 4) = o;
    if (GAMMA) {
        hl[tid*4+0] = h0; hl[tid*4+1] = h1; hl[tid*4+2] = h2; hl[tid*4+3] = h3;
        __syncthreads();
        float acc = 0.f;
        #pragma unroll 8
        for (int k = wv * 256; k < wv * 256 + 256; ++k)
            acc += hl[k] * w1[k * GH_DIM + lane];
        part[wv][lane] = acc;
        __syncthreads();
        if (wv == 0) {
            float t = part[0][lane] + part[1][lane] + part[2][lane] + part[3][lane];
            float z = t / (1.f + __expf(-t));
            float y = z * w2[lane];
            float t2 = wave_sum(y);
            if (lane == 0) gamma[row] = 1.f / (1.f + __expf(-t2));
        }
    }
}

// --- prep: weight transposes (64x64 tiles, 128B writes) + rmsnorm1+gamma ----
__global__ __launch_bounds__(256) void prep_kernel(
    const float* __restrict__ w_qkv, const float* __restrict__ w_o,
    const float* __restrict__ w1f, const float* __restrict__ w3f,
    const float* __restrict__ w2f, u16* __restrict__ wqT,
    u16* __restrict__ woT, u16* __restrict__ w13T, u16* __restrict__ w2T,
    const float* __restrict__ x, const float* __restrict__ norm1_w,
    u16* __restrict__ h_bf, const float* __restrict__ gw1,
    const float* __restrict__ gw2, float* __restrict__ gamma)
{
    __shared__ float tile[64][65];
    __shared__ float part[4][GH_DIM];
    __shared__ float wsum[4];
    int b = blockIdx.x;
    int tid = threadIdx.x;
    if (b < 3136) {
        const float* src; u16* dst;
        int srcK, srcN, Kp, rowOff, rowMul, nbx;
        if (b < 768)       {           src = w_qkv; dst = wqT;  srcK = 1024; srcN = 3072; Kp = 1024; rowOff = 0; rowMul = 1; nbx = 48; }
        else if (b < 1024) { b -= 768;  src = w_o;  dst = woT;  srcK = 1024; srcN = 1024; Kp = 1024; rowOff = 0; rowMul = 1; nbx = 16; }
        else if (b < 1728) { b -= 1024; src = w1f;  dst = w13T; srcK = 1024; srcN = 2730; Kp = 1024; rowOff = 0; rowMul = 2; nbx = 44; }
        else if (b < 2432) { b -= 1728; src = w3f;  dst = w13T; srcK = 1024; srcN = 2730; Kp = 1024; rowOff = 1; rowMul = 2; nbx = 44; }
        else               { b -= 2432; src = w2f;  dst = w2T;  srcK = 2730; srcN = 1024; Kp = 2816; rowOff = 0; rowMul = 1; nbx = 16; }
        int n0 = (b % nbx) * 64, k0 = (b / nbx) * 64;
        int tx = tid & 15, ty = tid >> 4;       // read: 16 thr/row x float4
        bool interior = (k0 + 63 < srcK) && (n0 + 63 < srcN);
        #pragma unroll
        for (int p = 0; p < 4; ++p) {
            int kk = p * 16 + ty;
            int r = k0 + kk;
            int cb = n0 + tx * 4;
            float4 v;
            if (interior) {
                v = *(const float4*)(src + (size_t)r * srcN + cb);
            } else {
                v.x = (r < srcK && cb     < srcN) ? src[(size_t)r * srcN + cb]     : 0.f;
                v.y = (r < srcK && cb + 1 < srcN) ? src[(size_t)r * srcN + cb + 1] : 0.f;
                v.z = (r < srcK && cb + 2 < srcN) ? src[(size_t)r * srcN + cb + 2] : 0.f;
                v.w = (r < srcK && cb + 3 < srcN) ? src[(size_t)r * srcN + cb + 3] : 0.f;
            }
            tile[kk][tx*4+0] = v.x; tile[kk][tx*4+1] = v.y;
            tile[kk][tx*4+2] = v.z; tile[kk][tx*4+3] = v.w;
        }
        __syncthreads();
        int wx = tid & 7, wy = tid >> 3;        // write: 8 thr/row x uint4(8 u16)
        #pragma unroll
        for (int p = 0; p < 2; ++p) {
            int nn = p * 32 + wy;
            int ks = wx * 8;
            uint4 o;
            o.x = f2bf2(tile[ks+0][nn], tile[ks+1][nn]);
            o.y = f2bf2(tile[ks+2][nn], tile[ks+3][nn]);
            o.z = f2bf2(tile[ks+4][nn], tile[ks+5][nn]);
            o.w = f2bf2(tile[ks+6][nn], tile[ks+7][nn]);
            *(uint4*)(dst + (size_t)(rowOff + (size_t)(n0 + nn) * rowMul) * Kp + k0 + ks) = o;
        }
    } else {
        int row = b - 3136;
        int lane = tid & 63, wv = tid >> 6;
        float* hl = &tile[0][0];
        const float4* ir = reinterpret_cast<const float4*>(x + (size_t)row * D_DIM);
        float4 v = ir[tid];
        float ss = v.x*v.x + v.y*v.y + v.z*v.z + v.w*v.w;
        ss = wave_sum(ss);
        if (lane == 0) wsum[wv] = ss;
        __syncthreads();
        float tot = wsum[0] + wsum[1] + wsum[2] + wsum[3];
        float scale = rsqrtf(tot / (float)D_DIM + 1e-6f);
        const float4* wr = reinterpret_cast<const float4*>(norm1_w);
        float4 wv4 = wr[tid];
        float h0 = v.x * scale * wv4.x, h1 = v.y * scale * wv4.y;
        float h2 = v.z * scale * wv4.z, h3 = v.w * scale * wv4.w;
        uint2 o;
        o.x = f2bf2(h0, h1);
        o.y = f2bf2(h2, h3);
        *reinterpret_cast<uint2*>(h_bf + (size_t)row * D_DIM + tid * 4) = o;
        hl[tid*4+0] = h0; hl[tid*4+1] = h1; hl[tid*4+2] = h2; hl[tid*4+3] = h3;
        __syncthreads();
        float acc = 0.f;
        #pragma unroll 8
        for (int k = wv * 256; k < wv * 256 + 256; ++k)
            acc += hl[k] * gw1[k * GH_DIM + lane];
        part[wv][lane] = acc;
        __syncthreads();
        if (wv == 0) {
            float t = part[0][lane] + part[1][lane] + part[2][lane] + part[3][lane];
            float z = t / (1.f + __expf(-t));
            float y = z * gw2[lane];
            float t2 = wave_sum(y);
            if (lane == 0) gamma[row] = 1.f / (1.f + __expf(-t2));
        }
    }
}

// ---- fused split qkv + qk rmsnorm + RoPE + KV transpose (one launch) -------
__global__ __launch_bounds__(256) void split_rope_tr_kernel(
    const u16* __restrict__ qkv, const float* __restrict__ qw,
    const float* __restrict__ kw, float* __restrict__ qhp,
    u16* __restrict__ khp, u16* __restrict__ khT, u16* __restrict__ vhT)
{
    __shared__ u16 tk[64][ALDK];
    __shared__ u16 tv[64][ALDK];
    int tid = threadIdx.x;
    int w = tid >> 6, d = tid & 63;
    int h = blockIdx.y;
    int s0 = blockIdx.x * 64;
    float qwv = qw[d], kwv = kw[d];
    int j = d & 31;
    float inv = expf(-(float)j * (9.2103403719761836f / 32.0f));
    float sgn = (d < 32) ? -1.f : 1.f;
    for (int i = 0; i < 16; ++i) {
        int sl = w * 16 + i;
        int s = s0 + sl;
        size_t base = (size_t)s * (3 * D_DIM) + h * HD_DIM + d;
        float qv = bf2f(qkv[base]);
        float kv = bf2f(qkv[base + D_DIM]);
        u16  vv = qkv[base + 2 * D_DIM];
        float sq = wave_sum(qv * qv);
        float qn = qv * rsqrtf(sq / (float)HD_DIM + 1e-6f) * qwv;
        float sk = wave_sum(kv * kv);
        float kn = kv * rsqrtf(sk / (float)HD_DIM + 1e-6f) * kwv;
        float ang = (float)s * inv;
        float cs = cosf(ang), sn = sinf(ang);
        float qp = __shfl_xor(qn, 32);
        float kp = __shfl_xor(kn, 32);
        float qo = qn * cs + sgn * qp * sn;
        float ko = kn * cs + sgn * kp * sn;
        size_t ob = ((size_t)h * S_LEN + s) * HD_DIM + d;
        u16 kb = f2bf(ko);
        qhp[ob] = qo;
        khp[ob] = kb;
        tk[sl][d] = kb;
        tv[sl][d] = vv;
    }
    __syncthreads();
    int r = tid >> 2, cc = (tid & 3) * 16;
    union { u16 u[16]; bf16x8_t v[2]; } ok, ov;
    #pragma unroll
    for (int e = 0; e < 16; ++e) {
        int ksrc = (e & 3) * 16 + (tid & 3) * 4 + (e >> 2);   // pi^-1 permute
        ok.u[e] = tk[ksrc][r]; ov.u[e] = tv[ksrc][r];
    }
    u16* kd = khT + ((size_t)h * HD_DIM + r) * S_LEN + s0 + cc;
    u16* vd = vhT + ((size_t)h * HD_DIM + r) * S_LEN + s0 + cc;
    *(bf16x8_t*)kd       = ok.v[0];
    *(bf16x8_t*)(kd + 8) = ok.v[1];
    *(bf16x8_t*)vd       = ov.v[0];
    *(bf16x8_t*)(vd + 8) = ov.v[1];
}

// ---------------- bf16 MFMA GEMM, 128-col tiles ------------------------------
// MODE 1: bf16 out.  MODE 2: paired silu-mul, bf16 out width N/2.
template<int BM, int MODE>
__global__ __launch_bounds__(256) void gemm_bb_kernel(
    const u16* __restrict__ A, const u16* __restrict__ B,
    u16* __restrict__ Cb, int M, int N, int K)
{
    constexpr int MREP = BM / 32;
    constexpr int ACH  = BM / 32;
    __shared__ u16 As[BM * 64];
    __shared__ u16 Bs[128 * 64];
    int tid = threadIdx.x, lane = tid & 63, wid = tid >> 6;
    int wr = wid >> 1, wc = wid & 1;
    int row0 = blockIdx.y * BM, col0 = blockIdx.x * 128;
    int l8 = lane >> 3, l7 = lane & 7;
    f32x4_t acc[MREP][4];
    #pragma unroll
    for (int i = 0; i < MREP; ++i)
        #pragma unroll
        for (int j = 0; j < 4; ++j) acc[i][j] = (f32x4_t)0.f;

    int fr = lane & 15, fo = (lane >> 4) * 8;
    for (int k0 = 0; k0 < K; k0 += 64) {
        #pragma unroll
        for (int i = 0; i < ACH; ++i) {
            int ch = wid * ACH + i;
            const u16* ga = A + (size_t)(row0 + ch * 8 + l8) * K + k0 + l7 * 8;
            gload16(ga, &As[ch * 512]);
        }
        #pragma unroll
        for (int i = 0; i < 4; ++i) {
            int ch = wid * 4 + i;
            const u16* gb = B + (size_t)(col0 + ch * 8 + l8) * K + k0 + l7 * 8;
            gload16(gb, &Bs[ch * 512]);
        }
        __syncthreads();
        __builtin_amdgcn_s_setprio(1);
        #pragma unroll
        for (int khf = 0; khf < 2; ++khf) {
            bf16x8_t bfrag[4];
            #pragma unroll
            for (int ni = 0; ni < 4; ++ni)
                bfrag[ni] = *(const bf16x8_t*)&Bs[(wc * 64 + ni * 16 + fr) * 64 + khf * 32 + fo];
            #pragma unroll
            for (int mi = 0; mi < MREP; ++mi) {
                bf16x8_t af = *(const bf16x8_t*)&As[(wr * (BM / 2) + mi * 16 + fr) * 64 + khf * 32 + fo];
                #pragma unroll
                for (int ni = 0; ni < 4; ++ni)
                    acc[mi][ni] = __builtin_amdgcn_mfma_f32_16x16x32_bf16(
                        af, bfrag[ni], acc[mi][ni], 0, 0, 0);
            }
        }
        __builtin_amdgcn_s_setprio(0);
        __syncthreads();
    }
    int dr = (lane >> 4) * 4, dc = lane & 15;
    #pragma unroll
    for (int mi = 0; mi < MREP; ++mi) {
        int gr = row0 + wr * (BM / 2) + mi * 16 + dr;
        #pragma unroll
        for (int ni = 0; ni < 4; ++ni) {
            int gc = col0 + wc * 64 + ni * 16 + dc;
            #pragma unroll
            for (int j = 0; j < 4; ++j) {
                float v = acc[mi][ni][j];
                if (MODE == 1) {
                    Cb[(size_t)(gr + j) * N + gc] = f2bf(v);
                } else {
                    float partner = __shfl_xor(v, 1);
                    float a1 = (dc & 1) ? partner : v;
                    float a3 = (dc & 1) ? v : partner;
                    float rr = a1 / (1.f + __expf(-a1)) * a3;
                    if (!(dc & 1))
                        Cb[(size_t)(gr + j) * (N >> 1) + (gc >> 1)] = f2bf(rr);
                }
            }
        }
    }
}

// ---------------- bf16 MFMA GEMM, 64x64 tiles, fp32 out + residual ----------
// (BK=64: the R18 BK=128 variant regressed -- 256B LDS row stride serialized
// the b128 fragment reads; this layout measures 0 bank conflicts.)
__global__ __launch_bounds__(256) void gemm64_kernel(
    const u16* __restrict__ A, const u16* __restrict__ B,
    const float* __restrict__ res, float* __restrict__ Cf,
    int M, int N, int K)
{
    __shared__ u16 As[64 * 64];
    __shared__ u16 Bs[64 * 64];
    int tid = threadIdx.x, lane = tid & 63, wid = tid >> 6;
    int wr = wid >> 1, wc = wid & 1;
    int row0 = blockIdx.y * 64, col0 = blockIdx.x * 64;
    int l8 = lane >> 3, l7 = lane & 7;
    f32x4_t acc[2][2];
    #pragma unroll
    for (int i = 0; i < 2; ++i)
        #pragma unroll
        for (int j = 0; j < 2; ++j) acc[i][j] = (f32x4_t)0.f;
    int fr = lane & 15, fo = (lane >> 4) * 8;
    for (int k0 = 0; k0 < K; k0 += 64) {
        #pragma unroll
        for (int i = 0; i < 2; ++i) {
            int ch = wid * 2 + i;
            const u16* ga = A + (size_t)(row0 + ch * 8 + l8) * K + k0 + l7 * 8;
            gload16(ga, &As[ch * 512]);
            const u16* gb = B + (size_t)(col0 + ch * 8 + l8) * K + k0 + l7 * 8;
            gload16(gb, &Bs[ch * 512]);
        }
        __syncthreads();
        __builtin_amdgcn_s_setprio(1);
        #pragma unroll
        for (int khf = 0; khf < 2; ++khf) {
            bf16x8_t bfrag[2];
            #pragma unroll
            for (int ni = 0; ni < 2; ++ni)
                bfrag[ni] = *(const bf16x8_t*)&Bs[(wc * 32 + ni * 16 + fr) * 64 + khf * 32 + fo];
            #pragma unroll
            for (int mi = 0; mi < 2; ++mi) {
                bf16x8_t af = *(const bf16x8_t*)&As[(wr * 32 + mi * 16 + fr) * 64 + khf * 32 + fo];
                #pragma unroll
                for (int ni = 0; ni < 2; ++ni)
                    acc[mi][ni] = __builtin_amdgcn_mfma_f32_16x16x32_bf16(
                        af, bfrag[ni], acc[mi][ni], 0, 0, 0);
            }
        }
        __builtin_amdgcn_s_setprio(0);
        __syncthreads();
    }
    int dr = (lane >> 4) * 4, dc = lane & 15;
    #pragma unroll
    for (int mi = 0; mi < 2; ++mi) {
        int gr = row0 + wr * 32 + mi * 16 + dr;
        #pragma unroll
        for (int ni = 0; ni < 2; ++ni) {
            int gc = col0 + wc * 32 + ni * 16 + dc;
            #pragma unroll
            for (int j = 0; j < 4; ++j) {
                size_t off = (size_t)(gr + j) * N + gc;
                Cf[off] = acc[mi][ni][j] + res[off];
            }
        }
    }
}

// ============ FUSED omega-rule + flash attention ============================
// Attention phase uses DEPTH-2 register prefetch (pA/pB named sets, loop
// unrolled by 2): loads for tile kt+3 are issued at iteration kt, so the
// staging ds_write waits on loads issued a full iteration earlier.
__global__ __launch_bounds__(256) void fused_omega_attn_kernel(
    const float* __restrict__ qhp, const u16* __restrict__ khp,
    const u16* __restrict__ khT, const u16* __restrict__ vhT,
    const float* __restrict__ gammab, const float* __restrict__ mp,
    const float* __restrict__ mg, u16* __restrict__ ao)
{
    __shared__ u16 Ks[2][KBLK][ALDK];
    __shared__ u16 Xt[2][KBLK][ALDK];
    __shared__ u16 Ps[QBLK][ALDK];
    __shared__ float colfL[CTX_W + KBLK];
    const int tid = threadIdx.x, lane = tid & 63, wq = tid >> 6;
    const int b = blockIdx.x;
    const int hi = (b >> 8) & 1;
    const int h = ((b & 7) << 1) + hi;
    const int s5 = (b >> 3) & 31;
    const int qt = hi ? (31 - s5) : s5;
    const int q0 = qt * QBLK;
    const int fr = lane & 15, g4 = lane >> 4;
    const int fko = g4 * 8;
    const int c = fr, rg = g4;
    const int si = tid >> 2, sdb = (tid & 3) * 16;
    const size_t hS = (size_t)h * S_LEN;
    const size_t hD = (size_t)h * HD_DIM;

    int rowt[4]; float rowf[4];
    #pragma unroll
    for (int j = 0; j < 4; ++j) {
        rowt[j] = q0 + wq * 16 + rg * 4 + j;
        rowf[j] = exp2f((float)(wq * 16 + rg * 4 + j) * L2LAM);
    }
    bf16x8_t qf[2];
    {
        const float* qrow = qhp + (hS + q0 + wq * 16 + fr) * HD_DIM;
        #pragma unroll
        for (int u = 0; u < 2; ++u) {
            float4 a = *(const float4*)(qrow + u * 32 + fko);
            float4 bq = *(const float4*)(qrow + u * 32 + fko + 4);
            bf16x8_t f;
            f[0]=f2bf(a.x); f[1]=f2bf(a.y); f[2]=f2bf(a.z); f[3]=f2bf(a.w);
            f[4]=f2bf(bq.x); f[5]=f2bf(bq.y); f[6]=f2bf(bq.z); f[7]=f2bf(bq.w);
            qf[u] = f;
        }
    }
    // preload q_old in C-layout (hides latency under the omega loop)
    float qold[4][4];
    #pragma unroll
    for (int n = 0; n < 4; ++n)
        #pragma unroll
        for (int j = 0; j < 4; ++j)
            qold[n][j] = qhp[(hS + rowt[j]) * HD_DIM + n * 16 + c];

    // ---------------- omega phase (double-buffered) ----------------
    f32x4_t accc[4];
    #pragma unroll
    for (int n = 0; n < 4; ++n) accc[n] = (f32x4_t)0.f;
    float wsum[4] = {0.f, 0.f, 0.f, 0.f};
    const int kt0 = (q0 > (CTX_W - 1)) ? (q0 - (CTX_W - 1)) / KBLK : 0;
    const int i0 = kt0 * KBLK;
    const int nwin = (qt + 1) * KBLK - i0;
    for (int idx = tid; idx < nwin; idx += 256) {
        int icol = i0 + idx;
        colfL[idx] = exp2f((float)(q0 - icol) * L2LAM) * gammab[icol];
    }
    {
        const u16* gk = khp + (hS + kt0 * KBLK + si) * HD_DIM + sdb;
        const u16* gx = khT + (hD + si) * S_LEN + kt0 * KBLK + sdb;
        *(bf16x8_t*)&Ks[0][si][sdb]     = *(const bf16x8_t*)gk;
        *(bf16x8_t*)&Ks[0][si][sdb + 8] = *(const bf16x8_t*)(gk + 8);
        *(bf16x8_t*)&Xt[0][si][sdb]     = *(const bf16x8_t*)gx;
        *(bf16x8_t*)&Xt[0][si][sdb + 8] = *(const bf16x8_t*)(gx + 8);
    }
    __syncthreads();
    int cur = 0;
    for (int kt = kt0; kt <= qt; ++kt) {
        const int k0 = kt * KBLK;
        const bool hn = (kt < qt);
        bf16x8_t nk0, nk1, nx0, nx1;
        if (hn) {
            const u16* gk = khp + (hS + k0 + KBLK + si) * HD_DIM + sdb;
            const u16* gx = khT + (hD + si) * S_LEN + k0 + KBLK + sdb;
            nk0 = *(const bf16x8_t*)gk; nk1 = *(const bf16x8_t*)(gk + 8);
            nx0 = *(const bf16x8_t*)gx; nx1 = *(const bf16x8_t*)(gx + 8);
        }
        f32x4_t s[4];
        #pragma unroll
        for (int n = 0; n < 4; ++n) s[n] = (f32x4_t)0.f;
        __builtin_amdgcn_s_setprio(1);
        #pragma unroll
        for (int u = 0; u < 2; ++u)
            #pragma unroll
            for (int n = 0; n < 4; ++n) {
                bf16x8_t kb = *(const bf16x8_t*)&Ks[cur][n * 16 + fr][u * 32 + fko];
                s[n] = __builtin_amdgcn_mfma_f32_16x16x32_bf16(qf[u], kb, s[n], 0, 0, 0);
            }
        __builtin_amdgcn_s_setprio(0);
        const bool boundary = (kt == kt0) || (kt == qt);
        float colf[4];
        #pragma unroll
        for (int n = 0; n < 4; ++n)
            colf[n] = colfL[k0 - i0 + n * 16 + c];
        #pragma unroll
        for (int j = 0; j < 4; ++j) {
            float pv[4];
            #pragma unroll
            for (int n = 0; n < 4; ++n) {
                float w;
                if (boundary) {
                    int delta = rowt[j] - (k0 + n * 16 + c);
                    w = (delta >= 0 && delta < CTX_W) ? rowf[j] * colf[n] : 0.f;
                } else {
                    w = rowf[j] * colf[n];
                }
                wsum[j] += w;
                pv[n] = w * s[n][j];
            }
            uint2 pk;
            pk.x = f2bf2(pv[0], pv[1]);
            pk.y = f2bf2(pv[2], pv[3]);
            *(uint2*)&Ps[wq * 16 + rg * 4 + j][c * 4] = pk;   // ds_write_b64
        }
        __builtin_amdgcn_s_setprio(1);
        #pragma unroll
        for (int u = 0; u < 2; ++u) {
            bf16x8_t pa = *(const bf16x8_t*)&Ps[wq * 16 + fr][u * 32 + fko];
            #pragma unroll
            for (int n = 0; n < 4; ++n) {
                bf16x8_t kb = *(const bf16x8_t*)&Xt[cur][n * 16 + fr][u * 32 + fko];
                accc[n] = __builtin_amdgcn_mfma_f32_16x16x32_bf16(pa, kb, accc[n], 0, 0, 0);
            }
        }
        __builtin_amdgcn_s_setprio(0);
        if (hn) {
            int nxt = cur ^ 1;
            *(bf16x8_t*)&Ks[nxt][si][sdb]     = nk0;
            *(bf16x8_t*)&Ks[nxt][si][sdb + 8] = nk1;
            *(bf16x8_t*)&Xt[nxt][si][sdb]     = nx0;
            *(bf16x8_t*)&Xt[nxt][si][sdb + 8] = nx1;
        }
        __syncthreads();
        cur ^= 1;
    }
    // persist = Q @ M_p^T
    f32x4_t pacc[4];
    #pragma unroll
    for (int n = 0; n < 4; ++n) pacc[n] = (f32x4_t)0.f;
    const float* mph = mp + hD * HD_DIM;
    #pragma unroll
    for (int u = 0; u < 2; ++u)
        #pragma unroll
        for (int n = 0; n < 4; ++n) {
            const float* br = mph + (size_t)(n * 16 + fr) * HD_DIM + u * 32 + fko;
            float4 a = *(const float4*)br;
            float4 bq = *(const float4*)(br + 4);
            bf16x8_t f;
            f[0]=f2bf(a.x); f[1]=f2bf(a.y); f[2]=f2bf(a.z); f[3]=f2bf(a.w);
            f[4]=f2bf(bq.x); f[5]=f2bf(bq.y); f[6]=f2bf(bq.z); f[7]=f2bf(bq.w);
            pacc[n] = __builtin_amdgcn_mfma_f32_16x16x32_bf16(qf[u], f, pacc[n], 0, 0, 0);
        }
    #pragma unroll
    for (int j = 0; j < 4; ++j) {
        wsum[j] += __shfl_xor(wsum[j], 1);
        wsum[j] += __shfl_xor(wsum[j], 2);
        wsum[j] += __shfl_xor(wsum[j], 4);
        wsum[j] += __shfl_xor(wsum[j], 8);
    }
    float gate = 1.f / (1.f + __expf(-mg[0]));
    float keep = 1.f - gate;
    #pragma unroll
    for (int n = 0; n < 4; ++n) {
        #pragma unroll
        for (int j = 0; j < 4; ++j) {
            float qn = keep * qold[n][j] + gate * (pacc[n][j] + accc[n][j]) / (1.f + wsum[j]);
            Ps[wq * 16 + rg * 4 + j][n * 16 + c] = f2bf(qn * QSCALE);
        }
    }
    bf16x8_t qf2[2];
    #pragma unroll
    for (int u = 0; u < 2; ++u)
        qf2[u] = *(const bf16x8_t*)&Ps[wq * 16 + fr][u * 32 + fko];

    // ------- attention phase: depth-2 prefetch, no-max softmax --------------
    f32x4_t acco[4];
    #pragma unroll
    for (int n = 0; n < 4; ++n) acco[n] = (f32x4_t)0.f;
    float l_run[4] = {0.f, 0.f, 0.f, 0.f};

    auto att_tile = [&](int kt, int curb) {
        const int k0 = kt * KBLK;
        f32x4_t s[4];
        #pragma unroll
        for (int n = 0; n < 4; ++n) s[n] = (f32x4_t)0.f;
        __builtin_amdgcn_s_setprio(1);
        #pragma unroll
        for (int u = 0; u < 2; ++u)
            #pragma unroll
            for (int n = 0; n < 4; ++n) {
                bf16x8_t kb = *(const bf16x8_t*)&Ks[curb][n * 16 + fr][u * 32 + fko];
                s[n] = __builtin_amdgcn_mfma_f32_16x16x32_bf16(qf2[u], kb, s[n], 0, 0, 0);
            }
        __builtin_amdgcn_s_setprio(0);
        if (kt == qt) {   // causal mask only on diagonal tile
            #pragma unroll
            for (int n = 0; n < 4; ++n) {
                int icol = k0 + n * 16 + c;
                #pragma unroll
                for (int j = 0; j < 4; ++j)
                    if (icol > rowt[j]) s[n][j] = -1e30f;
            }
        }
        #pragma unroll
        for (int j = 0; j < 4; ++j) {
            float p0 = exp2f(s[0][j]);
            float p1 = exp2f(s[1][j]);
            float p2 = exp2f(s[2][j]);
            float p3 = exp2f(s[3][j]);
            l_run[j] += (p0 + p1) + (p2 + p3);
            uint2 pk;
            pk.x = f2bf2(p0, p1);
            pk.y = f2bf2(p2, p3);
            *(uint2*)&Ps[wq * 16 + rg * 4 + j][c * 4] = pk;   // ds_write_b64
        }
        __builtin_amdgcn_s_setprio(1);
        #pragma unroll
        for (int u = 0; u < 2; ++u) {
            bf16x8_t pa = *(const bf16x8_t*)&Ps[wq * 16 + fr][u * 32 + fko];
            #pragma unroll
            for (int n = 0; n < 4; ++n) {
                bf16x8_t vb = *(const bf16x8_t*)&Xt[curb][n * 16 + fr][u * 32 + fko];
                acco[n] = __builtin_amdgcn_mfma_f32_16x16x32_bf16(pa, vb, acco[n], 0, 0, 0);
            }
        }
        __builtin_amdgcn_s_setprio(0);
    };

    bf16x8_t aK0, aK1, aV0, aV1;     // tile kt+1 (ready)
    bf16x8_t bK0, bK1, bV0, bV1;     // tile kt+2 (in flight)
    {   // prologue: stage tile 0; preload tiles 1 and 2 into regs
        const u16* gk = khp + (hS + si) * HD_DIM + sdb;
        const u16* gv = vhT + (hD + si) * S_LEN + sdb;
        *(bf16x8_t*)&Ks[0][si][sdb]     = *(const bf16x8_t*)gk;
        *(bf16x8_t*)&Ks[0][si][sdb + 8] = *(const bf16x8_t*)(gk + 8);
        *(bf16x8_t*)&Xt[0][si][sdb]     = *(const bf16x8_t*)gv;
        *(bf16x8_t*)&Xt[0][si][sdb + 8] = *(const bf16x8_t*)(gv + 8);
        if (qt >= 1) {
            const u16* gk1 = khp + (hS + KBLK + si) * HD_DIM + sdb;
            const u16* gv1 = vhT + (hD + si) * S_LEN + KBLK + sdb;
            aK0 = *(const bf16x8_t*)gk1; aK1 = *(const bf16x8_t*)(gk1 + 8);
            aV0 = *(const bf16x8_t*)gv1; aV1 = *(const bf16x8_t*)(gv1 + 8);
        }
        if (qt >= 2) {
            const u16* gk2 = khp + (hS + 2 * KBLK + si) * HD_DIM + sdb;
            const u16* gv2 = vhT + (hD + si) * S_LEN + 2 * KBLK + sdb;
            bK0 = *(const bf16x8_t*)gk2; bK1 = *(const bf16x8_t*)(gk2 + 8);
            bV0 = *(const bf16x8_t*)gv2; bV1 = *(const bf16x8_t*)(gv2 + 8);
        }
    }
    __syncthreads();
    cur = 0;
    int kt = 0;
    while (kt <= qt) {
        // ---- body A: set pA holds tile kt+1 ----
        att_tile(kt, cur);
        if (kt + 1 <= qt) {
            int nxt = cur ^ 1;
            *(bf16x8_t*)&Ks[nxt][si][sdb]     = aK0;
            *(bf16x8_t*)&Ks[nxt][si][sdb + 8] = aK1;
            *(bf16x8_t*)&Xt[nxt][si][sdb]     = aV0;
            *(bf16x8_t*)&Xt[nxt][si][sdb + 8] = aV1;
        }
        if (kt + 3 <= qt) {
            const u16* gk = khp + (hS + (kt + 3) * KBLK + si) * HD_DIM + sdb;
            const u16* gv = vhT + (hD + si) * S_LEN + (kt + 3) * KBLK + sdb;
            aK0 = *(const bf16x8_t*)gk; aK1 = *(const bf16x8_t*)(gk + 8);
            aV0 = *(const bf16x8_t*)gv; aV1 = *(const bf16x8_t*)(gv + 8);
        }
        __syncthreads();
        cur ^= 1;
        ++kt;
        if (kt > qt) break;
        // ---- body B: set pB holds tile kt+1 ----
        att_tile(kt, cur);
        if (kt + 1 <= qt) {
            int nxt = cur ^ 1;
            *(bf16x8_t*)&Ks[nxt][si][sdb]     = bK0;
            *(bf16x8_t*)&Ks[nxt][si][sdb + 8] = bK1;
            *(bf16x8_t*)&Xt[nxt][si][sdb]     = bV0;
            *(bf16x8_t*)&Xt[nxt][si][sdb + 8] = bV1;
        }
        if (kt + 3 <= qt) {
            const u16* gk = khp + (hS + (kt + 3) * KBLK + si) * HD_DIM + sdb;
            const u16* gv = vhT + (hD + si) * S_LEN + (kt + 3) * KBLK + sdb;
            bK0 = *(const bf16x8_t*)gk; bK1 = *(const bf16x8_t*)(gk + 8);
            bV0 = *(const bf16x8_t*)gv; bV1 = *(const bf16x8_t*)(gv + 8);
        }
        __syncthreads();
        cur ^= 1;
        ++kt;
    }
    #pragma unroll
    for (int j = 0; j < 4; ++j) {
        l_run[j] += __shfl_xor(l_run[j], 1);
        l_run[j] += __shfl_xor(l_run[j], 2);
        l_run[j] += __shfl_xor(l_run[j], 4);
        l_run[j] += __shfl_xor(l_run[j], 8);
    }
    #pragma unroll
    for (int n = 0; n < 4; ++n) {
        #pragma unroll
        for (int j = 0; j < 4; ++j) {
            float o = acco[n][j] / l_run[j];
            ao[(size_t)rowt[j] * D_DIM + h * HD_DIM + n * 16 + c] = f2bf(o);
        }
    }
}

extern "C" void kernel_launch(void* const* d_in, const int* in_sizes, int n_in,
                              void* d_out, int out_size, void* d_ws, size_t ws_size,
                              hipStream_t stream) {
    const float* x         = (const float*)d_in[0];
    const float* norm1_w   = (const float*)d_in[1];
    const float* norm2_w   = (const float*)d_in[2];
    const float* w_qkv     = (const float*)d_in[3];
    const float* q_norm_w  = (const float*)d_in[4];
    const float* k_norm_w  = (const float*)d_in[5];
    const float* gamma_w1  = (const float*)d_in[6];
    const float* gamma_w2  = (const float*)d_in[7];
    const float* m_persist = (const float*)d_in[8];
    const float* mem_gate  = (const float*)d_in[9];
    const float* w_o       = (const float*)d_in[10];
    const float* ffn_w1    = (const float*)d_in[11];
    const float* ffn_w3    = (const float*)d_in[12];
    const float* ffn_w2    = (const float*)d_in[13];
    float* out = (float*)d_out;
    char* ws = (char*)d_ws;

    const size_t MB = 1024 * 1024;
    u16*   h_bf   = (u16*)(ws);                 // [0,4MB) h / h2
    u16*   wqT    = (u16*)(ws + 4 * MB);        // [4,10)
    u16*   woT    = (u16*)(ws + 10 * MB);       // [10,12)
    u16*   w13T   = (u16*)(ws + 12 * MB);       // [12,23) interleaved w1/w3
    u16*   w2T    = (u16*)(ws + 23 * MB);       // [23,28.5)
    u16*   qkv_bf = (u16*)(ws + 29884416);      // [28.5,40.5) dead after split
    u16*   ao_bf  = (u16*)(ws + 38273024);      // [36.5,40.5) (after qkv dead)
    float* qh     = (float*)(ws + 42467328);    // [40.5,48.5) fp32 q
    u16*   kh     = (u16*)(ws + 50855936);      // [48.5,52.5)
    u16*   khT_s  = (u16*)(ws + 50855936 + 4 * MB);   // [52.5,56.5)
    float* gammab = (float*)(ws + 59244544);    // [56.5,+8KB)
    u16*   vhT_s  = (u16*)(ws + 59244544 + 64 * 1024); // [56.5+64KB,+4MB)
    u16*   mid_bf = (u16*)(ws + 29884416);      // [28.5,40) post-attention

    // --- prep: weight transposes + rmsnorm1 + gamma, ONE launch --------------
    hipLaunchKernelGGL(prep_kernel, dim3(3136 + S_LEN), dim3(256), 0, stream,
                       w_qkv, w_o, ffn_w1, ffn_w3, ffn_w2, wqT, woT, w13T, w2T,
                       x, norm1_w, h_bf, gamma_w1, gamma_w2, gammab);

    // --- forward pass ---------------------------------------------------------
    hipLaunchKernelGGL((gemm_bb_kernel<64, 1>), dim3(24, 32), dim3(256), 0, stream,
                       h_bf, wqT, qkv_bf, S_LEN, 3 * D_DIM, D_DIM);
    hipLaunchKernelGGL(split_rope_tr_kernel, dim3(S_LEN / 64, H_NUM), dim3(256), 0, stream,
                       qkv_bf, q_norm_w, k_norm_w, qh, kh, khT_s, vhT_s);
    hipLaunchKernelGGL(fused_omega_attn_kernel, dim3(512), dim3(256), 0, stream,
                       qh, kh, khT_s, vhT_s, gammab, m_persist, mem_gate, ao_bf);
    hipLaunchKernelGGL(gemm64_kernel, dim3(16, 32), dim3(256), 0, stream,
                       ao_bf, woT, x, out, S_LEN, D_DIM, D_DIM);
    hipLaunchKernelGGL((rmsnorm_gamma_kernel<false>), dim3(S_LEN), dim3(256), 0, stream,
                       out, norm2_w, h_bf, (const float*)nullptr,
                       (const float*)nullptr, (float*)nullptr);
    // ffn13 GEMM (BM=128) with fused SwiGLU epilogue -> mid
    hipLaunchKernelGGL((gemm_bb_kernel<128, 2>), dim3(44, 16), dim3(256), 0, stream,
                       h_bf, w13T, mid_bf, S_LEN, 2 * FFNP, D_DIM);
    hipLaunchKernelGGL(gemm64_kernel, dim3(16, 32), dim3(256), 0, stream,
                       mid_bf, w2T, out, out, S_LEN, D_DIM, FFNP);
}

// Round 21
// 222.217 us; speedup vs baseline: 1.0366x; 1.0017x over previous
//
#include <hip/hip_runtime.h>
#include <hip/hip_bf16.h>

#define S_LEN 2048
#define D_DIM 1024
#define H_NUM 16
#define HD_DIM 64
#define GH_DIM 64
#define FFN_H 2730
#define FFNP  2816          // FFN_H padded to multiple of 128 (zero-filled)
#define CTX_W 512
#define L2LAM -0.00144341687f   // log2(0.999)
#define QBLK 64
#define KBLK 64
#define ALDK 76             // LDS row stride (152B): write-conflict-free, reads <=2-way
#define QSCALE 0.1803368801111731f  // 0.125 * log2(e): scores come out ready for exp2

typedef unsigned short u16;
typedef __attribute__((ext_vector_type(8))) short bf16x8_t;
typedef __attribute__((ext_vector_type(4))) float f32x4_t;

__device__ inline float wave_sum(float v) {
    for (int off = 32; off; off >>= 1) v += __shfl_xor(v, off);
    return v;
}
// f32 -> bf16 (RNE) via the HW pack instruction: 1 VALU op.
__device__ inline u16 f2bf(float f) {
    unsigned r;
    asm("v_cvt_pk_bf16_f32 %0, %1, %2" : "=v"(r) : "v"(f), "v"(f));
    return (u16)r;
}
// pack two f32 -> u32 of 2 bf16 (lo, hi): 1 VALU op.
__device__ inline unsigned f2bf2(float lo, float hi) {
    unsigned r;
    asm("v_cvt_pk_bf16_f32 %0, %1, %2" : "=v"(r) : "v"(lo), "v"(hi));
    return r;
}
__device__ inline float bf2f(u16 u) {
    return __uint_as_float(((unsigned int)u) << 16);
}
__device__ inline void gload16(const void* g, void* l) {
    __builtin_amdgcn_global_load_lds(
        (const __attribute__((address_space(1))) void*)g,
        (__attribute__((address_space(3))) void*)l, 16, 0, 0);
}

// ------- RMSNorm (fp32 in -> bf16 out), optionally fused gamma gate ---------
template<bool GAMMA>
__global__ __launch_bounds__(256) void rmsnorm_gamma_kernel(
    const float* __restrict__ in, const float* __restrict__ w,
    u16* __restrict__ out, const float* __restrict__ w1,
    const float* __restrict__ w2, float* __restrict__ gamma)
{
    __shared__ float hl[D_DIM];
    __shared__ float part[4][GH_DIM];
    __shared__ float wsum[4];
    int row = blockIdx.x;
    int tid = threadIdx.x, lane = tid & 63, wv = tid >> 6;
    const float4* ir = reinterpret_cast<const float4*>(in + (size_t)row * D_DIM);
    float4 v = ir[tid];
    float ss = v.x*v.x + v.y*v.y + v.z*v.z + v.w*v.w;
    ss = wave_sum(ss);
    if (lane == 0) wsum[wv] = ss;
    __syncthreads();
    float tot = wsum[0] + wsum[1] + wsum[2] + wsum[3];
    float scale = rsqrtf(tot / (float)D_DIM + 1e-6f);
    const float4* wr = reinterpret_cast<const float4*>(w);
    float4 wv4 = wr[tid];
    float h0 = v.x * scale * wv4.x, h1 = v.y * scale * wv4.y;
    float h2 = v.z * scale * wv4.z, h3 = v.w * scale * wv4.w;
    uint2 o;
    o.x = f2bf2(h0, h1);
    o.y = f2bf2(h2, h3);
    *reinterpret_cast<uint2*>(out + (size_t)row * D_DIM + tid * 4) = o;
    if (GAMMA) {
        hl[tid*4+0] = h0; hl[tid*4+1] = h1; hl[tid*4+2] = h2; hl[tid*4+3] = h3;
        __syncthreads();
        float acc = 0.f;
        #pragma unroll 8
        for (int k = wv * 256; k < wv * 256 + 256; ++k)
            acc += hl[k] * w1[k * GH_DIM + lane];
        part[wv][lane] = acc;
        __syncthreads();
        if (wv == 0) {
            float t = part[0][lane] + part[1][lane] + part[2][lane] + part[3][lane];
            float z = t / (1.f + __expf(-t));
            float y = z * w2[lane];
            float t2 = wave_sum(y);
            if (lane == 0) gamma[row] = 1.f / (1.f + __expf(-t2));
        }
    }
}

// --- prep: weight transposes (64x64 tiles, 128B writes) + rmsnorm1+gamma ----
__global__ __launch_bounds__(256) void prep_kernel(
    const float* __restrict__ w_qkv, const float* __restrict__ w_o,
    const float* __restrict__ w1f, const float* __restrict__ w3f,
    const float* __restrict__ w2f, u16* __restrict__ wqT,
    u16* __restrict__ woT, u16* __restrict__ w13T, u16* __restrict__ w2T,
    const float* __restrict__ x, const float* __restrict__ norm1_w,
    u16* __restrict__ h_bf, const float* __restrict__ gw1,
    const float* __restrict__ gw2, float* __restrict__ gamma)
{
    __shared__ float tile[64][65];
    __shared__ float part[4][GH_DIM];
    __shared__ float wsum[4];
    int b = blockIdx.x;
    int tid = threadIdx.x;
    if (b < 3136) {
        const float* src; u16* dst;
        int srcK, srcN, Kp, rowOff, rowMul, nbx;
        if (b < 768)       {           src = w_qkv; dst = wqT;  srcK = 1024; srcN = 3072; Kp = 1024; rowOff = 0; rowMul = 1; nbx = 48; }
        else if (b < 1024) { b -= 768;  src = w_o;  dst = woT;  srcK = 1024; srcN = 1024; Kp = 1024; rowOff = 0; rowMul = 1; nbx = 16; }
        else if (b < 1728) { b -= 1024; src = w1f;  dst = w13T; srcK = 1024; srcN = 2730; Kp = 1024; rowOff = 0; rowMul = 2; nbx = 44; }
        else if (b < 2432) { b -= 1728; src = w3f;  dst = w13T; srcK = 1024; srcN = 2730; Kp = 1024; rowOff = 1; rowMul = 2; nbx = 44; }
        else               { b -= 2432; src = w2f;  dst = w2T;  srcK = 2730; srcN = 1024; Kp = 2816; rowOff = 0; rowMul = 1; nbx = 16; }
        int n0 = (b % nbx) * 64, k0 = (b / nbx) * 64;
        int tx = tid & 15, ty = tid >> 4;       // read: 16 thr/row x float4
        bool interior = (k0 + 63 < srcK) && (n0 + 63 < srcN);
        #pragma unroll
        for (int p = 0; p < 4; ++p) {
            int kk = p * 16 + ty;
            int r = k0 + kk;
            int cb = n0 + tx * 4;
            float4 v;
            if (interior) {
                v = *(const float4*)(src + (size_t)r * srcN + cb);
            } else {
                v.x = (r < srcK && cb     < srcN) ? src[(size_t)r * srcN + cb]     : 0.f;
                v.y = (r < srcK && cb + 1 < srcN) ? src[(size_t)r * srcN + cb + 1] : 0.f;
                v.z = (r < srcK && cb + 2 < srcN) ? src[(size_t)r * srcN + cb + 2] : 0.f;
                v.w = (r < srcK && cb + 3 < srcN) ? src[(size_t)r * srcN + cb + 3] : 0.f;
            }
            tile[kk][tx*4+0] = v.x; tile[kk][tx*4+1] = v.y;
            tile[kk][tx*4+2] = v.z; tile[kk][tx*4+3] = v.w;
        }
        __syncthreads();
        int wx = tid & 7, wy = tid >> 3;        // write: 8 thr/row x uint4(8 u16)
        #pragma unroll
        for (int p = 0; p < 2; ++p) {
            int nn = p * 32 + wy;
            int ks = wx * 8;
            uint4 o;
            o.x = f2bf2(tile[ks+0][nn], tile[ks+1][nn]);
            o.y = f2bf2(tile[ks+2][nn], tile[ks+3][nn]);
            o.z = f2bf2(tile[ks+4][nn], tile[ks+5][nn]);
            o.w = f2bf2(tile[ks+6][nn], tile[ks+7][nn]);
            *(uint4*)(dst + (size_t)(rowOff + (size_t)(n0 + nn) * rowMul) * Kp + k0 + ks) = o;
        }
    } else {
        int row = b - 3136;
        int lane = tid & 63, wv = tid >> 6;
        float* hl = &tile[0][0];
        const float4* ir = reinterpret_cast<const float4*>(x + (size_t)row * D_DIM);
        float4 v = ir[tid];
        float ss = v.x*v.x + v.y*v.y + v.z*v.z + v.w*v.w;
        ss = wave_sum(ss);
        if (lane == 0) wsum[wv] = ss;
        __syncthreads();
        float tot = wsum[0] + wsum[1] + wsum[2] + wsum[3];
        float scale = rsqrtf(tot / (float)D_DIM + 1e-6f);
        const float4* wr = reinterpret_cast<const float4*>(norm1_w);
        float4 wv4 = wr[tid];
        float h0 = v.x * scale * wv4.x, h1 = v.y * scale * wv4.y;
        float h2 = v.z * scale * wv4.z, h3 = v.w * scale * wv4.w;
        uint2 o;
        o.x = f2bf2(h0, h1);
        o.y = f2bf2(h2, h3);
        *reinterpret_cast<uint2*>(h_bf + (size_t)row * D_DIM + tid * 4) = o;
        hl[tid*4+0] = h0; hl[tid*4+1] = h1; hl[tid*4+2] = h2; hl[tid*4+3] = h3;
        __syncthreads();
        float acc = 0.f;
        #pragma unroll 8
        for (int k = wv * 256; k < wv * 256 + 256; ++k)
            acc += hl[k] * gw1[k * GH_DIM + lane];
        part[wv][lane] = acc;
        __syncthreads();
        if (wv == 0) {
            float t = part[0][lane] + part[1][lane] + part[2][lane] + part[3][lane];
            float z = t / (1.f + __expf(-t));
            float y = z * gw2[lane];
            float t2 = wave_sum(y);
            if (lane == 0) gamma[row] = 1.f / (1.f + __expf(-t2));
        }
    }
}

// ---- fused split qkv + qk rmsnorm + RoPE + KV transpose (one launch) -------
__global__ __launch_bounds__(256) void split_rope_tr_kernel(
    const u16* __restrict__ qkv, const float* __restrict__ qw,
    const float* __restrict__ kw, float* __restrict__ qhp,
    u16* __restrict__ khp, u16* __restrict__ khT, u16* __restrict__ vhT)
{
    __shared__ u16 tk[64][ALDK];
    __shared__ u16 tv[64][ALDK];
    int tid = threadIdx.x;
    int w = tid >> 6, d = tid & 63;
    int h = blockIdx.y;
    int s0 = blockIdx.x * 64;
    float qwv = qw[d], kwv = kw[d];
    int j = d & 31;
    float inv = expf(-(float)j * (9.2103403719761836f / 32.0f));
    float sgn = (d < 32) ? -1.f : 1.f;
    for (int i = 0; i < 16; ++i) {
        int sl = w * 16 + i;
        int s = s0 + sl;
        size_t base = (size_t)s * (3 * D_DIM) + h * HD_DIM + d;
        float qv = bf2f(qkv[base]);
        float kv = bf2f(qkv[base + D_DIM]);
        u16  vv = qkv[base + 2 * D_DIM];
        float sq = wave_sum(qv * qv);
        float qn = qv * rsqrtf(sq / (float)HD_DIM + 1e-6f) * qwv;
        float sk = wave_sum(kv * kv);
        float kn = kv * rsqrtf(sk / (float)HD_DIM + 1e-6f) * kwv;
        float ang = (float)s * inv;
        float cs = cosf(ang), sn = sinf(ang);
        float qp = __shfl_xor(qn, 32);
        float kp = __shfl_xor(kn, 32);
        float qo = qn * cs + sgn * qp * sn;
        float ko = kn * cs + sgn * kp * sn;
        size_t ob = ((size_t)h * S_LEN + s) * HD_DIM + d;
        u16 kb = f2bf(ko);
        qhp[ob] = qo;
        khp[ob] = kb;
        tk[sl][d] = kb;
        tv[sl][d] = vv;
    }
    __syncthreads();
    int r = tid >> 2, cc = (tid & 3) * 16;
    union { u16 u[16]; bf16x8_t v[2]; } ok, ov;
    #pragma unroll
    for (int e = 0; e < 16; ++e) {
        int ksrc = (e & 3) * 16 + (tid & 3) * 4 + (e >> 2);   // pi^-1 permute
        ok.u[e] = tk[ksrc][r]; ov.u[e] = tv[ksrc][r];
    }
    u16* kd = khT + ((size_t)h * HD_DIM + r) * S_LEN + s0 + cc;
    u16* vd = vhT + ((size_t)h * HD_DIM + r) * S_LEN + s0 + cc;
    *(bf16x8_t*)kd       = ok.v[0];
    *(bf16x8_t*)(kd + 8) = ok.v[1];
    *(bf16x8_t*)vd       = ov.v[0];
    *(bf16x8_t*)(vd + 8) = ov.v[1];
}

// ---------------- bf16 MFMA GEMM, 128-col tiles ------------------------------
// MODE 1: bf16 out.  MODE 2: paired silu-mul, bf16 out width N/2.
template<int BM, int MODE>
__global__ __launch_bounds__(256) void gemm_bb_kernel(
    const u16* __restrict__ A, const u16* __restrict__ B,
    u16* __restrict__ Cb, int M, int N, int K)
{
    constexpr int MREP = BM / 32;
    constexpr int ACH  = BM / 32;
    __shared__ u16 As[BM * 64];
    __shared__ u16 Bs[128 * 64];
    int tid = threadIdx.x, lane = tid & 63, wid = tid >> 6;
    int wr = wid >> 1, wc = wid & 1;
    int row0 = blockIdx.y * BM, col0 = blockIdx.x * 128;
    int l8 = lane >> 3, l7 = lane & 7;
    f32x4_t acc[MREP][4];
    #pragma unroll
    for (int i = 0; i < MREP; ++i)
        #pragma unroll
        for (int j = 0; j < 4; ++j) acc[i][j] = (f32x4_t)0.f;

    int fr = lane & 15, fo = (lane >> 4) * 8;
    for (int k0 = 0; k0 < K; k0 += 64) {
        #pragma unroll
        for (int i = 0; i < ACH; ++i) {
            int ch = wid * ACH + i;
            const u16* ga = A + (size_t)(row0 + ch * 8 + l8) * K + k0 + l7 * 8;
            gload16(ga, &As[ch * 512]);
        }
        #pragma unroll
        for (int i = 0; i < 4; ++i) {
            int ch = wid * 4 + i;
            const u16* gb = B + (size_t)(col0 + ch * 8 + l8) * K + k0 + l7 * 8;
            gload16(gb, &Bs[ch * 512]);
        }
        __syncthreads();
        __builtin_amdgcn_s_setprio(1);
        #pragma unroll
        for (int khf = 0; khf < 2; ++khf) {
            bf16x8_t bfrag[4];
            #pragma unroll
            for (int ni = 0; ni < 4; ++ni)
                bfrag[ni] = *(const bf16x8_t*)&Bs[(wc * 64 + ni * 16 + fr) * 64 + khf * 32 + fo];
            #pragma unroll
            for (int mi = 0; mi < MREP; ++mi) {
                bf16x8_t af = *(const bf16x8_t*)&As[(wr * (BM / 2) + mi * 16 + fr) * 64 + khf * 32 + fo];
                #pragma unroll
                for (int ni = 0; ni < 4; ++ni)
                    acc[mi][ni] = __builtin_amdgcn_mfma_f32_16x16x32_bf16(
                        af, bfrag[ni], acc[mi][ni], 0, 0, 0);
            }
        }
        __builtin_amdgcn_s_setprio(0);
        __syncthreads();
    }
    int dr = (lane >> 4) * 4, dc = lane & 15;
    #pragma unroll
    for (int mi = 0; mi < MREP; ++mi) {
        int gr = row0 + wr * (BM / 2) + mi * 16 + dr;
        #pragma unroll
        for (int ni = 0; ni < 4; ++ni) {
            int gc = col0 + wc * 64 + ni * 16 + dc;
            #pragma unroll
            for (int j = 0; j < 4; ++j) {
                float v = acc[mi][ni][j];
                if (MODE == 1) {
                    Cb[(size_t)(gr + j) * N + gc] = f2bf(v);
                } else {
                    float partner = __shfl_xor(v, 1);
                    float a1 = (dc & 1) ? partner : v;
                    float a3 = (dc & 1) ? v : partner;
                    float rr = a1 / (1.f + __expf(-a1)) * a3;
                    if (!(dc & 1))
                        Cb[(size_t)(gr + j) * (N >> 1) + (gc >> 1)] = f2bf(rr);
                }
            }
        }
    }
}

// ---------------- bf16 MFMA GEMM, 64x64 tiles, fp32 out + residual ----------
// (BK=64: the R18 BK=128 variant regressed -- 256B LDS row stride serialized
// the b128 fragment reads; this layout measures 0 bank conflicts.)
__global__ __launch_bounds__(256) void gemm64_kernel(
    const u16* __restrict__ A, const u16* __restrict__ B,
    const float* __restrict__ res, float* __restrict__ Cf,
    int M, int N, int K)
{
    __shared__ u16 As[64 * 64];
    __shared__ u16 Bs[64 * 64];
    int tid = threadIdx.x, lane = tid & 63, wid = tid >> 6;
    int wr = wid >> 1, wc = wid & 1;
    int row0 = blockIdx.y * 64, col0 = blockIdx.x * 64;
    int l8 = lane >> 3, l7 = lane & 7;
    f32x4_t acc[2][2];
    #pragma unroll
    for (int i = 0; i < 2; ++i)
        #pragma unroll
        for (int j = 0; j < 2; ++j) acc[i][j] = (f32x4_t)0.f;
    int fr = lane & 15, fo = (lane >> 4) * 8;
    for (int k0 = 0; k0 < K; k0 += 64) {
        #pragma unroll
        for (int i = 0; i < 2; ++i) {
            int ch = wid * 2 + i;
            const u16* ga = A + (size_t)(row0 + ch * 8 + l8) * K + k0 + l7 * 8;
            gload16(ga, &As[ch * 512]);
            const u16* gb = B + (size_t)(col0 + ch * 8 + l8) * K + k0 + l7 * 8;
            gload16(gb, &Bs[ch * 512]);
        }
        __syncthreads();
        __builtin_amdgcn_s_setprio(1);
        #pragma unroll
        for (int khf = 0; khf < 2; ++khf) {
            bf16x8_t bfrag[2];
            #pragma unroll
            for (int ni = 0; ni < 2; ++ni)
                bfrag[ni] = *(const bf16x8_t*)&Bs[(wc * 32 + ni * 16 + fr) * 64 + khf * 32 + fo];
            #pragma unroll
            for (int mi = 0; mi < 2; ++mi) {
                bf16x8_t af = *(const bf16x8_t*)&As[(wr * 32 + mi * 16 + fr) * 64 + khf * 32 + fo];
                #pragma unroll
                for (int ni = 0; ni < 2; ++ni)
                    acc[mi][ni] = __builtin_amdgcn_mfma_f32_16x16x32_bf16(
                        af, bfrag[ni], acc[mi][ni], 0, 0, 0);
            }
        }
        __builtin_amdgcn_s_setprio(0);
        __syncthreads();
    }
    int dr = (lane >> 4) * 4, dc = lane & 15;
    #pragma unroll
    for (int mi = 0; mi < 2; ++mi) {
        int gr = row0 + wr * 32 + mi * 16 + dr;
        #pragma unroll
        for (int ni = 0; ni < 2; ++ni) {
            int gc = col0 + wc * 32 + ni * 16 + dc;
            #pragma unroll
            for (int j = 0; j < 4; ++j) {
                size_t off = (size_t)(gr + j) * N + gc;
                Cf[off] = acc[mi][ni][j] + res[off];
            }
        }
    }
}

// ============ FUSED omega-rule + flash attention ============================
__global__ __launch_bounds__(256) void fused_omega_attn_kernel(
    const float* __restrict__ qhp, const u16* __restrict__ khp,
    const u16* __restrict__ khT, const u16* __restrict__ vhT,
    const float* __restrict__ gammab, const float* __restrict__ mp,
    const float* __restrict__ mg, u16* __restrict__ ao)
{
    __shared__ u16 Ks[2][KBLK][ALDK];
    __shared__ u16 Xt[2][KBLK][ALDK];
    __shared__ u16 Ps[QBLK][ALDK];
    __shared__ float colfL[CTX_W + KBLK];
    const int tid = threadIdx.x, lane = tid & 63, wq = tid >> 6;
    const int b = blockIdx.x;
    const int hi = (b >> 8) & 1;
    const int h = ((b & 7) << 1) + hi;
    const int s5 = (b >> 3) & 31;
    const int qt = hi ? (31 - s5) : s5;
    const int q0 = qt * QBLK;
    const int fr = lane & 15, g4 = lane >> 4;
    const int fko = g4 * 8;
    const int c = fr, rg = g4;
    const int si = tid >> 2, sdb = (tid & 3) * 16;
    const size_t hS = (size_t)h * S_LEN;
    const size_t hD = (size_t)h * HD_DIM;

    int rowt[4]; float rowf[4];
    #pragma unroll
    for (int j = 0; j < 4; ++j) {
        rowt[j] = q0 + wq * 16 + rg * 4 + j;
        rowf[j] = exp2f((float)(wq * 16 + rg * 4 + j) * L2LAM);
    }
    bf16x8_t qf[2];
    {
        const float* qrow = qhp + (hS + q0 + wq * 16 + fr) * HD_DIM;
        #pragma unroll
        for (int u = 0; u < 2; ++u) {
            float4 a = *(const float4*)(qrow + u * 32 + fko);
            float4 bq = *(const float4*)(qrow + u * 32 + fko + 4);
            bf16x8_t f;
            f[0]=f2bf(a.x); f[1]=f2bf(a.y); f[2]=f2bf(a.z); f[3]=f2bf(a.w);
            f[4]=f2bf(bq.x); f[5]=f2bf(bq.y); f[6]=f2bf(bq.z); f[7]=f2bf(bq.w);
            qf[u] = f;
        }
    }
    // preload q_old in C-layout (hides latency under the omega loop)
    float qold[4][4];
    #pragma unroll
    for (int n = 0; n < 4; ++n)
        #pragma unroll
        for (int j = 0; j < 4; ++j)
            qold[n][j] = qhp[(hS + rowt[j]) * HD_DIM + n * 16 + c];

    // ---------------- omega phase (double-buffered) ----------------
    f32x4_t accc[4];
    #pragma unroll
    for (int n = 0; n < 4; ++n) accc[n] = (f32x4_t)0.f;
    float wsum[4] = {0.f, 0.f, 0.f, 0.f};
    const int kt0 = (q0 > (CTX_W - 1)) ? (q0 - (CTX_W - 1)) / KBLK : 0;
    const int i0 = kt0 * KBLK;
    const int nwin = (qt + 1) * KBLK - i0;
    for (int idx = tid; idx < nwin; idx += 256) {
        int icol = i0 + idx;
        colfL[idx] = exp2f((float)(q0 - icol) * L2LAM) * gammab[icol];
    }
    {
        const u16* gk = khp + (hS + kt0 * KBLK + si) * HD_DIM + sdb;
        const u16* gx = khT + (hD + si) * S_LEN + kt0 * KBLK + sdb;
        *(bf16x8_t*)&Ks[0][si][sdb]     = *(const bf16x8_t*)gk;
        *(bf16x8_t*)&Ks[0][si][sdb + 8] = *(const bf16x8_t*)(gk + 8);
        *(bf16x8_t*)&Xt[0][si][sdb]     = *(const bf16x8_t*)gx;
        *(bf16x8_t*)&Xt[0][si][sdb + 8] = *(const bf16x8_t*)(gx + 8);
    }
    __syncthreads();
    int cur = 0;
    for (int kt = kt0; kt <= qt; ++kt) {
        const int k0 = kt * KBLK;
        const bool hn = (kt < qt);
        bf16x8_t nk0, nk1, nx0, nx1;
        if (hn) {
            const u16* gk = khp + (hS + k0 + KBLK + si) * HD_DIM + sdb;
            const u16* gx = khT + (hD + si) * S_LEN + k0 + KBLK + sdb;
            nk0 = *(const bf16x8_t*)gk; nk1 = *(const bf16x8_t*)(gk + 8);
            nx0 = *(const bf16x8_t*)gx; nx1 = *(const bf16x8_t*)(gx + 8);
        }
        f32x4_t s[4];
        #pragma unroll
        for (int n = 0; n < 4; ++n) s[n] = (f32x4_t)0.f;
        __builtin_amdgcn_s_setprio(1);
        #pragma unroll
        for (int u = 0; u < 2; ++u)
            #pragma unroll
            for (int n = 0; n < 4; ++n) {
                bf16x8_t kb = *(const bf16x8_t*)&Ks[cur][n * 16 + fr][u * 32 + fko];
                s[n] = __builtin_amdgcn_mfma_f32_16x16x32_bf16(qf[u], kb, s[n], 0, 0, 0);
            }
        __builtin_amdgcn_s_setprio(0);
        const bool boundary = (kt == kt0) || (kt == qt);
        float colf[4];
        #pragma unroll
        for (int n = 0; n < 4; ++n)
            colf[n] = colfL[k0 - i0 + n * 16 + c];
        #pragma unroll
        for (int j = 0; j < 4; ++j) {
            float pv[4];
            #pragma unroll
            for (int n = 0; n < 4; ++n) {
                float w;
                if (boundary) {
                    int delta = rowt[j] - (k0 + n * 16 + c);
                    w = (delta >= 0 && delta < CTX_W) ? rowf[j] * colf[n] : 0.f;
                } else {
                    w = rowf[j] * colf[n];
                }
                wsum[j] += w;
                pv[n] = w * s[n][j];
            }
            uint2 pk;
            pk.x = f2bf2(pv[0], pv[1]);
            pk.y = f2bf2(pv[2], pv[3]);
            *(uint2*)&Ps[wq * 16 + rg * 4 + j][c * 4] = pk;   // ds_write_b64
        }
        __builtin_amdgcn_s_setprio(1);
        #pragma unroll
        for (int u = 0; u < 2; ++u) {
            bf16x8_t pa = *(const bf16x8_t*)&Ps[wq * 16 + fr][u * 32 + fko];
            #pragma unroll
            for (int n = 0; n < 4; ++n) {
                bf16x8_t kb = *(const bf16x8_t*)&Xt[cur][n * 16 + fr][u * 32 + fko];
                accc[n] = __builtin_amdgcn_mfma_f32_16x16x32_bf16(pa, kb, accc[n], 0, 0, 0);
            }
        }
        __builtin_amdgcn_s_setprio(0);
        if (hn) {
            int nxt = cur ^ 1;
            *(bf16x8_t*)&Ks[nxt][si][sdb]     = nk0;
            *(bf16x8_t*)&Ks[nxt][si][sdb + 8] = nk1;
            *(bf16x8_t*)&Xt[nxt][si][sdb]     = nx0;
            *(bf16x8_t*)&Xt[nxt][si][sdb + 8] = nx1;
        }
        __syncthreads();
        cur ^= 1;
    }
    // persist = Q @ M_p^T
    f32x4_t pacc[4];
    #pragma unroll
    for (int n = 0; n < 4; ++n) pacc[n] = (f32x4_t)0.f;
    const float* mph = mp + hD * HD_DIM;
    #pragma unroll
    for (int u = 0; u < 2; ++u)
        #pragma unroll
        for (int n = 0; n < 4; ++n) {
            const float* br = mph + (size_t)(n * 16 + fr) * HD_DIM + u * 32 + fko;
            float4 a = *(const float4*)br;
            float4 bq = *(const float4*)(br + 4);
            bf16x8_t f;
            f[0]=f2bf(a.x); f[1]=f2bf(a.y); f[2]=f2bf(a.z); f[3]=f2bf(a.w);
            f[4]=f2bf(bq.x); f[5]=f2bf(bq.y); f[6]=f2bf(bq.z); f[7]=f2bf(bq.w);
            pacc[n] = __builtin_amdgcn_mfma_f32_16x16x32_bf16(qf[u], f, pacc[n], 0, 0, 0);
        }
    #pragma unroll
    for (int j = 0; j < 4; ++j) {
        wsum[j] += __shfl_xor(wsum[j], 1);
        wsum[j] += __shfl_xor(wsum[j], 2);
        wsum[j] += __shfl_xor(wsum[j], 4);
        wsum[j] += __shfl_xor(wsum[j], 8);
    }
    float gate = 1.f / (1.f + __expf(-mg[0]));
    float keep = 1.f - gate;
    #pragma unroll
    for (int n = 0; n < 4; ++n) {
        #pragma unroll
        for (int j = 0; j < 4; ++j) {
            float qn = keep * qold[n][j] + gate * (pacc[n][j] + accc[n][j]) / (1.f + wsum[j]);
            Ps[wq * 16 + rg * 4 + j][n * 16 + c] = f2bf(qn * QSCALE);
        }
    }
    bf16x8_t qf2[2];
    #pragma unroll
    for (int u = 0; u < 2; ++u)
        qf2[u] = *(const bf16x8_t*)&Ps[wq * 16 + fr][u * 32 + fko];

    // ---------------- attention phase (double-buffered, no-max softmax) -----
    f32x4_t acco[4];
    #pragma unroll
    for (int n = 0; n < 4; ++n) acco[n] = (f32x4_t)0.f;
    float l_run[4] = {0.f, 0.f, 0.f, 0.f};
    {
        const u16* gk = khp + (hS + si) * HD_DIM + sdb;
        const u16* gv = vhT + (hD + si) * S_LEN + sdb;
        *(bf16x8_t*)&Ks[0][si][sdb]     = *(const bf16x8_t*)gk;
        *(bf16x8_t*)&Ks[0][si][sdb + 8] = *(const bf16x8_t*)(gk + 8);
        *(bf16x8_t*)&Xt[0][si][sdb]     = *(const bf16x8_t*)gv;
        *(bf16x8_t*)&Xt[0][si][sdb + 8] = *(const bf16x8_t*)(gv + 8);
    }
    __syncthreads();
    cur = 0;
    for (int kt = 0; kt <= qt; ++kt) {
        const int k0 = kt * KBLK;
        const bool hn = (kt < qt);
        bf16x8_t nk0, nk1, nv0, nv1;
        if (hn) {
            const u16* gk = khp + (hS + k0 + KBLK + si) * HD_DIM + sdb;
            const u16* gv = vhT + (hD + si) * S_LEN + k0 + KBLK + sdb;
            nk0 = *(const bf16x8_t*)gk; nk1 = *(const bf16x8_t*)(gk + 8);
            nv0 = *(const bf16x8_t*)gv; nv1 = *(const bf16x8_t*)(gv + 8);
        }
        f32x4_t s[4];
        #pragma unroll
        for (int n = 0; n < 4; ++n) s[n] = (f32x4_t)0.f;
        __builtin_amdgcn_s_setprio(1);
        #pragma unroll
        for (int u = 0; u < 2; ++u)
            #pragma unroll
            for (int n = 0; n < 4; ++n) {
                bf16x8_t kb = *(const bf16x8_t*)&Ks[cur][n * 16 + fr][u * 32 + fko];
                s[n] = __builtin_amdgcn_mfma_f32_16x16x32_bf16(qf2[u], kb, s[n], 0, 0, 0);
            }
        __builtin_amdgcn_s_setprio(0);
        if (kt == qt) {
            #pragma unroll
            for (int n = 0; n < 4; ++n) {
                int icol = k0 + n * 16 + c;
                #pragma unroll
                for (int j = 0; j < 4; ++j)
                    if (icol > rowt[j]) s[n][j] = -1e30f;
            }
        }
        #pragma unroll
        for (int j = 0; j < 4; ++j) {
            float p0 = exp2f(s[0][j]);
            float p1 = exp2f(s[1][j]);
            float p2 = exp2f(s[2][j]);
            float p3 = exp2f(s[3][j]);
            l_run[j] += (p0 + p1) + (p2 + p3);
            uint2 pk;
            pk.x = f2bf2(p0, p1);
            pk.y = f2bf2(p2, p3);
            *(uint2*)&Ps[wq * 16 + rg * 4 + j][c * 4] = pk;   // ds_write_b64
        }
        __builtin_amdgcn_s_setprio(1);
        #pragma unroll
        for (int u = 0; u < 2; ++u) {
            bf16x8_t pa = *(const bf16x8_t*)&Ps[wq * 16 + fr][u * 32 + fko];
            #pragma unroll
            for (int n = 0; n < 4; ++n) {
                bf16x8_t vb = *(const bf16x8_t*)&Xt[cur][n * 16 + fr][u * 32 + fko];
                acco[n] = __builtin_amdgcn_mfma_f32_16x16x32_bf16(pa, vb, acco[n], 0, 0, 0);
            }
        }
        __builtin_amdgcn_s_setprio(0);
        if (hn) {
            int nxt = cur ^ 1;
            *(bf16x8_t*)&Ks[nxt][si][sdb]     = nk0;
            *(bf16x8_t*)&Ks[nxt][si][sdb + 8] = nk1;
            *(bf16x8_t*)&Xt[nxt][si][sdb]     = nv0;
            *(bf16x8_t*)&Xt[nxt][si][sdb + 8] = nv1;
        }
        __syncthreads();
        cur ^= 1;
    }
    #pragma unroll
    for (int j = 0; j < 4; ++j) {
        l_run[j] += __shfl_xor(l_run[j], 1);
        l_run[j] += __shfl_xor(l_run[j], 2);
        l_run[j] += __shfl_xor(l_run[j], 4);
        l_run[j] += __shfl_xor(l_run[j], 8);
    }
    #pragma unroll
    for (int n = 0; n < 4; ++n) {
        #pragma unroll
        for (int j = 0; j < 4; ++j) {
            float o = acco[n][j] / l_run[j];
            ao[(size_t)rowt[j] * D_DIM + h * HD_DIM + n * 16 + c] = f2bf(o);
        }
    }
}

extern "C" void kernel_launch(void* const* d_in, const int* in_sizes, int n_in,
                              void* d_out, int out_size, void* d_ws, size_t ws_size,
                              hipStream_t stream) {
    const float* x         = (const float*)d_in[0];
    const float* norm1_w   = (const float*)d_in[1];
    const float* norm2_w   = (const float*)d_in[2];
    const float* w_qkv     = (const float*)d_in[3];
    const float* q_norm_w  = (const float*)d_in[4];
    const float* k_norm_w  = (const float*)d_in[5];
    const float* gamma_w1  = (const float*)d_in[6];
    const float* gamma_w2  = (const float*)d_in[7];
    const float* m_persist = (const float*)d_in[8];
    const float* mem_gate  = (const float*)d_in[9];
    const float* w_o       = (const float*)d_in[10];
    const float* ffn_w1    = (const float*)d_in[11];
    const float* ffn_w3    = (const float*)d_in[12];
    const float* ffn_w2    = (const float*)d_in[13];
    float* out = (float*)d_out;
    char* ws = (char*)d_ws;

    const size_t MB = 1024 * 1024;
    u16*   h_bf   = (u16*)(ws);                 // [0,4MB) h / h2
    u16*   wqT    = (u16*)(ws + 4 * MB);        // [4,10)
    u16*   woT    = (u16*)(ws + 10 * MB);       // [10,12)
    u16*   w13T   = (u16*)(ws + 12 * MB);       // [12,23) interleaved w1/w3
    u16*   w2T    = (u16*)(ws + 23 * MB);       // [23,28.5)
    u16*   qkv_bf = (u16*)(ws + 29884416);      // [28.5,40.5) dead after split
    u16*   ao_bf  = (u16*)(ws + 38273024);      // [36.5,40.5) (after qkv dead)
    float* qh     = (float*)(ws + 42467328);    // [40.5,48.5) fp32 q
    u16*   kh     = (u16*)(ws + 50855936);      // [48.5,52.5)
    u16*   khT_s  = (u16*)(ws + 50855936 + 4 * MB);   // [52.5,56.5)
    float* gammab = (float*)(ws + 59244544);    // [56.5,+8KB)
    u16*   vhT_s  = (u16*)(ws + 59244544 + 64 * 1024); // [56.5+64KB,+4MB)
    u16*   mid_bf = (u16*)(ws + 29884416);      // [28.5,40) post-attention

    // --- prep: weight transposes + rmsnorm1 + gamma, ONE launch --------------
    hipLaunchKernelGGL(prep_kernel, dim3(3136 + S_LEN), dim3(256), 0, stream,
                       w_qkv, w_o, ffn_w1, ffn_w3, ffn_w2, wqT, woT, w13T, w2T,
                       x, norm1_w, h_bf, gamma_w1, gamma_w2, gammab);

    // --- forward pass ---------------------------------------------------------
    hipLaunchKernelGGL((gemm_bb_kernel<64, 1>), dim3(24, 32), dim3(256), 0, stream,
                       h_bf, wqT, qkv_bf, S_LEN, 3 * D_DIM, D_DIM);
    hipLaunchKernelGGL(split_rope_tr_kernel, dim3(S_LEN / 64, H_NUM), dim3(256), 0, stream,
                       qkv_bf, q_norm_w, k_norm_w, qh, kh, khT_s, vhT_s);
    hipLaunchKernelGGL(fused_omega_attn_kernel, dim3(512), dim3(256), 0, stream,
                       qh, kh, khT_s, vhT_s, gammab, m_persist, mem_gate, ao_bf);
    hipLaunchKernelGGL(gemm64_kernel, dim3(16, 32), dim3(256), 0, stream,
                       ao_bf, woT, x, out, S_LEN, D_DIM, D_DIM);
    hipLaunchKernelGGL((rmsnorm_gamma_kernel<false>), dim3(S_LEN), dim3(256), 0, stream,
                       out, norm2_w, h_bf, (const float*)nullptr,
                       (const float*)nullptr, (float*)nullptr);
    // ffn13 GEMM (BM=128) with fused SwiGLU epilogue -> mid
    hipLaunchKernelGGL((gemm_bb_kernel<128, 2>), dim3(44, 16), dim3(256), 0, stream,
                       h_bf, w13T, mid_bf, S_LEN, 2 * FFNP, D_DIM);
    hipLaunchKernelGGL(gemm64_kernel, dim3(16, 32), dim3(256), 0, stream,
                       mid_bf, w2T, out, out, S_LEN, D_DIM, FFNP);
}

// Round 22
// 217.914 us; speedup vs baseline: 1.0571x; 1.0197x over previous
//
#include <hip/hip_runtime.h>
#include <hip/hip_bf16.h>

#define S_LEN 2048
#define D_DIM 1024
#define H_NUM 16
#define HD_DIM 64
#define GH_DIM 64
#define FFN_H 2730
#define FFNP  2816          // FFN_H padded to multiple of 128 (zero-filled)
#define CTX_W 512
#define L2LAM -0.00144341687f   // log2(0.999)
#define QBLK 64
#define KBLK 64
#define ALDK 76             // LDS row stride (152B): write-conflict-free, reads <=2-way
#define QSCALE 0.1803368801111731f  // 0.125 * log2(e): scores come out ready for exp2

typedef unsigned short u16;
typedef __attribute__((ext_vector_type(8))) short bf16x8_t;
typedef __attribute__((ext_vector_type(4))) float f32x4_t;

__device__ inline float wave_sum(float v) {
    for (int off = 32; off; off >>= 1) v += __shfl_xor(v, off);
    return v;
}
// f32 -> bf16 (RNE) via the HW pack instruction: 1 VALU op.
__device__ inline u16 f2bf(float f) {
    unsigned r;
    asm("v_cvt_pk_bf16_f32 %0, %1, %2" : "=v"(r) : "v"(f), "v"(f));
    return (u16)r;
}
// pack two f32 -> u32 of 2 bf16 (lo, hi): 1 VALU op.
__device__ inline unsigned f2bf2(float lo, float hi) {
    unsigned r;
    asm("v_cvt_pk_bf16_f32 %0, %1, %2" : "=v"(r) : "v"(lo), "v"(hi));
    return r;
}
__device__ inline float bf2f(u16 u) {
    return __uint_as_float(((unsigned int)u) << 16);
}
__device__ inline void gload16(const void* g, void* l) {
    __builtin_amdgcn_global_load_lds(
        (const __attribute__((address_space(1))) void*)g,
        (__attribute__((address_space(3))) void*)l, 16, 0, 0);
}

// ------- RMSNorm (fp32 in -> bf16 out), optionally fused gamma gate ---------
template<bool GAMMA>
__global__ __launch_bounds__(256) void rmsnorm_gamma_kernel(
    const float* __restrict__ in, const float* __restrict__ w,
    u16* __restrict__ out, const float* __restrict__ w1,
    const float* __restrict__ w2, float* __restrict__ gamma)
{
    __shared__ float hl[D_DIM];
    __shared__ float part[4][GH_DIM];
    __shared__ float wsum[4];
    int row = blockIdx.x;
    int tid = threadIdx.x, lane = tid & 63, wv = tid >> 6;
    const float4* ir = reinterpret_cast<const float4*>(in + (size_t)row * D_DIM);
    float4 v = ir[tid];
    float ss = v.x*v.x + v.y*v.y + v.z*v.z + v.w*v.w;
    ss = wave_sum(ss);
    if (lane == 0) wsum[wv] = ss;
    __syncthreads();
    float tot = wsum[0] + wsum[1] + wsum[2] + wsum[3];
    float scale = rsqrtf(tot / (float)D_DIM + 1e-6f);
    const float4* wr = reinterpret_cast<const float4*>(w);
    float4 wv4 = wr[tid];
    float h0 = v.x * scale * wv4.x, h1 = v.y * scale * wv4.y;
    float h2 = v.z * scale * wv4.z, h3 = v.w * scale * wv4.w;
    uint2 o;
    o.x = f2bf2(h0, h1);
    o.y = f2bf2(h2, h3);
    *reinterpret_cast<uint2*>(out + (size_t)row * D_DIM + tid * 4) = o;
    if (GAMMA) {
        hl[tid*4+0] = h0; hl[tid*4+1] = h1; hl[tid*4+2] = h2; hl[tid*4+3] = h3;
        __syncthreads();
        float acc = 0.f;
        #pragma unroll 8
        for (int k = wv * 256; k < wv * 256 + 256; ++k)
            acc += hl[k] * w1[k * GH_DIM + lane];
        part[wv][lane] = acc;
        __syncthreads();
        if (wv == 0) {
            float t = part[0][lane] + part[1][lane] + part[2][lane] + part[3][lane];
            float z = t / (1.f + __expf(-t));
            float y = z * w2[lane];
            float t2 = wave_sum(y);
            if (lane == 0) gamma[row] = 1.f / (1.f + __expf(-t2));
        }
    }
}

// --- prep: weight transposes (64x64 tiles, 128B writes) + rmsnorm1+gamma ----
__global__ __launch_bounds__(256) void prep_kernel(
    const float* __restrict__ w_qkv, const float* __restrict__ w_o,
    const float* __restrict__ w1f, const float* __restrict__ w3f,
    const float* __restrict__ w2f, u16* __restrict__ wqT,
    u16* __restrict__ woT, u16* __restrict__ w13T, u16* __restrict__ w2T,
    const float* __restrict__ x, const float* __restrict__ norm1_w,
    u16* __restrict__ h_bf, const float* __restrict__ gw1,
    const float* __restrict__ gw2, float* __restrict__ gamma)
{
    __shared__ float tile[64][65];
    __shared__ float part[4][GH_DIM];
    __shared__ float wsum[4];
    int b = blockIdx.x;
    int tid = threadIdx.x;
    if (b < 3136) {
        const float* src; u16* dst;
        int srcK, srcN, Kp, rowOff, rowMul, nbx;
        if (b < 768)       {           src = w_qkv; dst = wqT;  srcK = 1024; srcN = 3072; Kp = 1024; rowOff = 0; rowMul = 1; nbx = 48; }
        else if (b < 1024) { b -= 768;  src = w_o;  dst = woT;  srcK = 1024; srcN = 1024; Kp = 1024; rowOff = 0; rowMul = 1; nbx = 16; }
        else if (b < 1728) { b -= 1024; src = w1f;  dst = w13T; srcK = 1024; srcN = 2730; Kp = 1024; rowOff = 0; rowMul = 2; nbx = 44; }
        else if (b < 2432) { b -= 1728; src = w3f;  dst = w13T; srcK = 1024; srcN = 2730; Kp = 1024; rowOff = 1; rowMul = 2; nbx = 44; }
        else               { b -= 2432; src = w2f;  dst = w2T;  srcK = 2730; srcN = 1024; Kp = 2816; rowOff = 0; rowMul = 1; nbx = 16; }
        int n0 = (b % nbx) * 64, k0 = (b / nbx) * 64;
        int tx = tid & 15, ty = tid >> 4;       // read: 16 thr/row x float4
        bool interior = (k0 + 63 < srcK) && (n0 + 63 < srcN);
        #pragma unroll
        for (int p = 0; p < 4; ++p) {
            int kk = p * 16 + ty;
            int r = k0 + kk;
            int cb = n0 + tx * 4;
            float4 v;
            if (interior) {
                v = *(const float4*)(src + (size_t)r * srcN + cb);
            } else {
                v.x = (r < srcK && cb     < srcN) ? src[(size_t)r * srcN + cb]     : 0.f;
                v.y = (r < srcK && cb + 1 < srcN) ? src[(size_t)r * srcN + cb + 1] : 0.f;
                v.z = (r < srcK && cb + 2 < srcN) ? src[(size_t)r * srcN + cb + 2] : 0.f;
                v.w = (r < srcK && cb + 3 < srcN) ? src[(size_t)r * srcN + cb + 3] : 0.f;
            }
            tile[kk][tx*4+0] = v.x; tile[kk][tx*4+1] = v.y;
            tile[kk][tx*4+2] = v.z; tile[kk][tx*4+3] = v.w;
        }
        __syncthreads();
        int wx = tid & 7, wy = tid >> 3;        // write: 8 thr/row x uint4(8 u16)
        #pragma unroll
        for (int p = 0; p < 2; ++p) {
            int nn = p * 32 + wy;
            int ks = wx * 8;
            uint4 o;
            o.x = f2bf2(tile[ks+0][nn], tile[ks+1][nn]);
            o.y = f2bf2(tile[ks+2][nn], tile[ks+3][nn]);
            o.z = f2bf2(tile[ks+4][nn], tile[ks+5][nn]);
            o.w = f2bf2(tile[ks+6][nn], tile[ks+7][nn]);
            *(uint4*)(dst + (size_t)(rowOff + (size_t)(n0 + nn) * rowMul) * Kp + k0 + ks) = o;
        }
    } else {
        int row = b - 3136;
        int lane = tid & 63, wv = tid >> 6;
        float* hl = &tile[0][0];
        const float4* ir = reinterpret_cast<const float4*>(x + (size_t)row * D_DIM);
        float4 v = ir[tid];
        float ss = v.x*v.x + v.y*v.y + v.z*v.z + v.w*v.w;
        ss = wave_sum(ss);
        if (lane == 0) wsum[wv] = ss;
        __syncthreads();
        float tot = wsum[0] + wsum[1] + wsum[2] + wsum[3];
        float scale = rsqrtf(tot / (float)D_DIM + 1e-6f);
        const float4* wr = reinterpret_cast<const float4*>(norm1_w);
        float4 wv4 = wr[tid];
        float h0 = v.x * scale * wv4.x, h1 = v.y * scale * wv4.y;
        float h2 = v.z * scale * wv4.z, h3 = v.w * scale * wv4.w;
        uint2 o;
        o.x = f2bf2(h0, h1);
        o.y = f2bf2(h2, h3);
        *reinterpret_cast<uint2*>(h_bf + (size_t)row * D_DIM + tid * 4) = o;
        hl[tid*4+0] = h0; hl[tid*4+1] = h1; hl[tid*4+2] = h2; hl[tid*4+3] = h3;
        __syncthreads();
        float acc = 0.f;
        #pragma unroll 8
        for (int k = wv * 256; k < wv * 256 + 256; ++k)
            acc += hl[k] * gw1[k * GH_DIM + lane];
        part[wv][lane] = acc;
        __syncthreads();
        if (wv == 0) {
            float t = part[0][lane] + part[1][lane] + part[2][lane] + part[3][lane];
            float z = t / (1.f + __expf(-t));
            float y = z * gw2[lane];
            float t2 = wave_sum(y);
            if (lane == 0) gamma[row] = 1.f / (1.f + __expf(-t2));
        }
    }
}

// ---- fused split qkv + qk rmsnorm + RoPE + KV transpose (one launch) -------
__global__ __launch_bounds__(256) void split_rope_tr_kernel(
    const u16* __restrict__ qkv, const float* __restrict__ qw,
    const float* __restrict__ kw, float* __restrict__ qhp,
    u16* __restrict__ khp, u16* __restrict__ khT, u16* __restrict__ vhT)
{
    __shared__ u16 tk[64][ALDK];
    __shared__ u16 tv[64][ALDK];
    int tid = threadIdx.x;
    int w = tid >> 6, d = tid & 63;
    int h = blockIdx.y;
    int s0 = blockIdx.x * 64;
    float qwv = qw[d], kwv = kw[d];
    int j = d & 31;
    float inv = expf(-(float)j * (9.2103403719761836f / 32.0f));
    float sgn = (d < 32) ? -1.f : 1.f;
    for (int i = 0; i < 16; ++i) {
        int sl = w * 16 + i;
        int s = s0 + sl;
        size_t base = (size_t)s * (3 * D_DIM) + h * HD_DIM + d;
        float qv = bf2f(qkv[base]);
        float kv = bf2f(qkv[base + D_DIM]);
        u16  vv = qkv[base + 2 * D_DIM];
        float sq = wave_sum(qv * qv);
        float qn = qv * rsqrtf(sq / (float)HD_DIM + 1e-6f) * qwv;
        float sk = wave_sum(kv * kv);
        float kn = kv * rsqrtf(sk / (float)HD_DIM + 1e-6f) * kwv;
        float ang = (float)s * inv;
        float cs = cosf(ang), sn = sinf(ang);
        float qp = __shfl_xor(qn, 32);
        float kp = __shfl_xor(kn, 32);
        float qo = qn * cs + sgn * qp * sn;
        float ko = kn * cs + sgn * kp * sn;
        size_t ob = ((size_t)h * S_LEN + s) * HD_DIM + d;
        u16 kb = f2bf(ko);
        qhp[ob] = qo;
        khp[ob] = kb;
        tk[sl][d] = kb;
        tv[sl][d] = vv;
    }
    __syncthreads();
    int r = tid >> 2, cc = (tid & 3) * 16;
    union { u16 u[16]; bf16x8_t v[2]; } ok, ov;
    #pragma unroll
    for (int e = 0; e < 16; ++e) {
        int ksrc = (e & 3) * 16 + (tid & 3) * 4 + (e >> 2);   // pi^-1 permute
        ok.u[e] = tk[ksrc][r]; ov.u[e] = tv[ksrc][r];
    }
    u16* kd = khT + ((size_t)h * HD_DIM + r) * S_LEN + s0 + cc;
    u16* vd = vhT + ((size_t)h * HD_DIM + r) * S_LEN + s0 + cc;
    *(bf16x8_t*)kd       = ok.v[0];
    *(bf16x8_t*)(kd + 8) = ok.v[1];
    *(bf16x8_t*)vd       = ov.v[0];
    *(bf16x8_t*)(vd + 8) = ov.v[1];
}

// ---------------- bf16 MFMA GEMM, 128-col tiles ------------------------------
// MODE 1: bf16 out.  MODE 2: paired silu-mul, bf16 out width N/2.
template<int BM, int MODE>
__global__ __launch_bounds__(256) void gemm_bb_kernel(
    const u16* __restrict__ A, const u16* __restrict__ B,
    u16* __restrict__ Cb, int M, int N, int K)
{
    constexpr int MREP = BM / 32;
    constexpr int ACH  = BM / 32;
    __shared__ u16 As[BM * 64];
    __shared__ u16 Bs[128 * 64];
    int tid = threadIdx.x, lane = tid & 63, wid = tid >> 6;
    int wr = wid >> 1, wc = wid & 1;
    int row0 = blockIdx.y * BM, col0 = blockIdx.x * 128;
    int l8 = lane >> 3, l7 = lane & 7;
    f32x4_t acc[MREP][4];
    #pragma unroll
    for (int i = 0; i < MREP; ++i)
        #pragma unroll
        for (int j = 0; j < 4; ++j) acc[i][j] = (f32x4_t)0.f;

    int fr = lane & 15, fo = (lane >> 4) * 8;
    for (int k0 = 0; k0 < K; k0 += 64) {
        #pragma unroll
        for (int i = 0; i < ACH; ++i) {
            int ch = wid * ACH + i;
            const u16* ga = A + (size_t)(row0 + ch * 8 + l8) * K + k0 + l7 * 8;
            gload16(ga, &As[ch * 512]);
        }
        #pragma unroll
        for (int i = 0; i < 4; ++i) {
            int ch = wid * 4 + i;
            const u16* gb = B + (size_t)(col0 + ch * 8 + l8) * K + k0 + l7 * 8;
            gload16(gb, &Bs[ch * 512]);
        }
        __syncthreads();
        __builtin_amdgcn_s_setprio(1);
        #pragma unroll
        for (int khf = 0; khf < 2; ++khf) {
            bf16x8_t bfrag[4];
            #pragma unroll
            for (int ni = 0; ni < 4; ++ni)
                bfrag[ni] = *(const bf16x8_t*)&Bs[(wc * 64 + ni * 16 + fr) * 64 + khf * 32 + fo];
            #pragma unroll
            for (int mi = 0; mi < MREP; ++mi) {
                bf16x8_t af = *(const bf16x8_t*)&As[(wr * (BM / 2) + mi * 16 + fr) * 64 + khf * 32 + fo];
                #pragma unroll
                for (int ni = 0; ni < 4; ++ni)
                    acc[mi][ni] = __builtin_amdgcn_mfma_f32_16x16x32_bf16(
                        af, bfrag[ni], acc[mi][ni], 0, 0, 0);
            }
        }
        __builtin_amdgcn_s_setprio(0);
        __syncthreads();
    }
    int dr = (lane >> 4) * 4, dc = lane & 15;
    #pragma unroll
    for (int mi = 0; mi < MREP; ++mi) {
        int gr = row0 + wr * (BM / 2) + mi * 16 + dr;
        #pragma unroll
        for (int ni = 0; ni < 4; ++ni) {
            int gc = col0 + wc * 64 + ni * 16 + dc;
            #pragma unroll
            for (int j = 0; j < 4; ++j) {
                float v = acc[mi][ni][j];
                if (MODE == 1) {
                    Cb[(size_t)(gr + j) * N + gc] = f2bf(v);
                } else {
                    float partner = __shfl_xor(v, 1);
                    float a1 = (dc & 1) ? partner : v;
                    float a3 = (dc & 1) ? v : partner;
                    float rr = a1 / (1.f + __expf(-a1)) * a3;
                    if (!(dc & 1))
                        Cb[(size_t)(gr + j) * (N >> 1) + (gc >> 1)] = f2bf(rr);
                }
            }
        }
    }
}

// ---------------- bf16 MFMA GEMM, 64x64 tiles, fp32 out + residual ----------
// (BK=64: the R18 BK=128 variant regressed -- 256B LDS row stride serialized
// the b128 fragment reads; this layout measures 0 bank conflicts.)
__global__ __launch_bounds__(256) void gemm64_kernel(
    const u16* __restrict__ A, const u16* __restrict__ B,
    const float* __restrict__ res, float* __restrict__ Cf,
    int M, int N, int K)
{
    __shared__ u16 As[64 * 64];
    __shared__ u16 Bs[64 * 64];
    int tid = threadIdx.x, lane = tid & 63, wid = tid >> 6;
    int wr = wid >> 1, wc = wid & 1;
    int row0 = blockIdx.y * 64, col0 = blockIdx.x * 64;
    int l8 = lane >> 3, l7 = lane & 7;
    f32x4_t acc[2][2];
    #pragma unroll
    for (int i = 0; i < 2; ++i)
        #pragma unroll
        for (int j = 0; j < 2; ++j) acc[i][j] = (f32x4_t)0.f;
    int fr = lane & 15, fo = (lane >> 4) * 8;
    for (int k0 = 0; k0 < K; k0 += 64) {
        #pragma unroll
        for (int i = 0; i < 2; ++i) {
            int ch = wid * 2 + i;
            const u16* ga = A + (size_t)(row0 + ch * 8 + l8) * K + k0 + l7 * 8;
            gload16(ga, &As[ch * 512]);
            const u16* gb = B + (size_t)(col0 + ch * 8 + l8) * K + k0 + l7 * 8;
            gload16(gb, &Bs[ch * 512]);
        }
        __syncthreads();
        __builtin_amdgcn_s_setprio(1);
        #pragma unroll
        for (int khf = 0; khf < 2; ++khf) {
            bf16x8_t bfrag[2];
            #pragma unroll
            for (int ni = 0; ni < 2; ++ni)
                bfrag[ni] = *(const bf16x8_t*)&Bs[(wc * 32 + ni * 16 + fr) * 64 + khf * 32 + fo];
            #pragma unroll
            for (int mi = 0; mi < 2; ++mi) {
                bf16x8_t af = *(const bf16x8_t*)&As[(wr * 32 + mi * 16 + fr) * 64 + khf * 32 + fo];
                #pragma unroll
                for (int ni = 0; ni < 2; ++ni)
                    acc[mi][ni] = __builtin_amdgcn_mfma_f32_16x16x32_bf16(
                        af, bfrag[ni], acc[mi][ni], 0, 0, 0);
            }
        }
        __builtin_amdgcn_s_setprio(0);
        __syncthreads();
    }
    int dr = (lane >> 4) * 4, dc = lane & 15;
    #pragma unroll
    for (int mi = 0; mi < 2; ++mi) {
        int gr = row0 + wr * 32 + mi * 16 + dr;
        #pragma unroll
        for (int ni = 0; ni < 2; ++ni) {
            int gc = col0 + wc * 32 + ni * 16 + dc;
            #pragma unroll
            for (int j = 0; j < 4; ++j) {
                size_t off = (size_t)(gr + j) * N + gc;
                Cf[off] = acc[mi][ni][j] + res[off];
            }
        }
    }
}

// ============ FUSED omega-rule + flash attention (8-wave col-split) =========
// 512 threads = 8 waves = 4 row-groups x 2 column-halves. Each wave computes
// HALF of each tile's columns (its 2 n-quadrants): half the MFMAs, exp2s and
// P-stores per wave -> 4 waves/SIMD instead of 2 for latency hiding. The
// cross-half combines (softmax l, omega wsum) are additive via a small LDS
// array; output d-columns partition cleanly so acc/pacc/accc need no combine.
// Cost: one extra barrier per tile (P rows shared between the wave pair).
__global__ __launch_bounds__(512) void fused_omega_attn_kernel(
    const float* __restrict__ qhp, const u16* __restrict__ khp,
    const u16* __restrict__ khT, const u16* __restrict__ vhT,
    const float* __restrict__ gammab, const float* __restrict__ mp,
    const float* __restrict__ mg, u16* __restrict__ ao)
{
    __shared__ u16 Ks[2][KBLK][ALDK];
    __shared__ u16 Xt[2][KBLK][ALDK];
    __shared__ u16 Ps[QBLK][ALDK];
    __shared__ float colfL[CTX_W + KBLK];
    __shared__ float redS[2][QBLK];      // cross-half reduction (wsum / l)
    const int tid = threadIdx.x, lane = tid & 63, wid = tid >> 6;
    const int wq = wid & 3;              // row group (16 q-rows)
    const int nh = wid >> 2;             // column half (0/1)
    const int b = blockIdx.x;
    const int hi = (b >> 8) & 1;
    const int h = ((b & 7) << 1) + hi;
    const int s5 = (b >> 3) & 31;
    const int qt = hi ? (31 - s5) : s5;
    const int q0 = qt * QBLK;
    const int fr = lane & 15, g4 = lane >> 4;
    const int fko = g4 * 8;
    const int c = fr, rg = g4;
    const int si = tid >> 3, sdb = (tid & 7) * 8;   // staging: 512 thr x 16B
    const size_t hS = (size_t)h * S_LEN;
    const size_t hD = (size_t)h * HD_DIM;

    int rowt[4]; float rowf[4];
    #pragma unroll
    for (int j = 0; j < 4; ++j) {
        rowt[j] = q0 + wq * 16 + rg * 4 + j;
        rowf[j] = exp2f((float)(wq * 16 + rg * 4 + j) * L2LAM);
    }
    bf16x8_t qf[2];
    {
        const float* qrow = qhp + (hS + q0 + wq * 16 + fr) * HD_DIM;
        #pragma unroll
        for (int u = 0; u < 2; ++u) {
            float4 a = *(const float4*)(qrow + u * 32 + fko);
            float4 bq = *(const float4*)(qrow + u * 32 + fko + 4);
            bf16x8_t f;
            f[0]=f2bf(a.x); f[1]=f2bf(a.y); f[2]=f2bf(a.z); f[3]=f2bf(a.w);
            f[4]=f2bf(bq.x); f[5]=f2bf(bq.y); f[6]=f2bf(bq.z); f[7]=f2bf(bq.w);
            qf[u] = f;
        }
    }
    // preload q_old for this wave's column quadrants (n = 2*nh + nn)
    float qold[2][4];
    #pragma unroll
    for (int nn = 0; nn < 2; ++nn)
        #pragma unroll
        for (int j = 0; j < 4; ++j)
            qold[nn][j] = qhp[(hS + rowt[j]) * HD_DIM + (nh * 2 + nn) * 16 + c];

    // ---------------- omega phase ----------------
    f32x4_t accc[2];
    accc[0] = (f32x4_t)0.f; accc[1] = (f32x4_t)0.f;
    float wsum[4] = {0.f, 0.f, 0.f, 0.f};
    const int kt0 = (q0 > (CTX_W - 1)) ? (q0 - (CTX_W - 1)) / KBLK : 0;
    const int i0 = kt0 * KBLK;
    const int nwin = (qt + 1) * KBLK - i0;
    for (int idx = tid; idx < nwin; idx += 512) {
        int icol = i0 + idx;
        colfL[idx] = exp2f((float)(q0 - icol) * L2LAM) * gammab[icol];
    }
    {
        const u16* gk = khp + (hS + kt0 * KBLK + si) * HD_DIM + sdb;
        const u16* gx = khT + (hD + si) * S_LEN + kt0 * KBLK + sdb;
        *(bf16x8_t*)&Ks[0][si][sdb] = *(const bf16x8_t*)gk;
        *(bf16x8_t*)&Xt[0][si][sdb] = *(const bf16x8_t*)gx;
    }
    __syncthreads();
    int cur = 0;
    for (int kt = kt0; kt <= qt; ++kt) {
        const int k0 = kt * KBLK;
        const bool hn = (kt < qt);
        bf16x8_t nk0, nx0;
        if (hn) {
            const u16* gk = khp + (hS + k0 + KBLK + si) * HD_DIM + sdb;
            const u16* gx = khT + (hD + si) * S_LEN + k0 + KBLK + sdb;
            nk0 = *(const bf16x8_t*)gk;
            nx0 = *(const bf16x8_t*)gx;
        }
        f32x4_t s[2];
        s[0] = (f32x4_t)0.f; s[1] = (f32x4_t)0.f;
        __builtin_amdgcn_s_setprio(1);
        #pragma unroll
        for (int u = 0; u < 2; ++u)
            #pragma unroll
            for (int nn = 0; nn < 2; ++nn) {
                bf16x8_t kb = *(const bf16x8_t*)&Ks[cur][(nh * 2 + nn) * 16 + fr][u * 32 + fko];
                s[nn] = __builtin_amdgcn_mfma_f32_16x16x32_bf16(qf[u], kb, s[nn], 0, 0, 0);
            }
        __builtin_amdgcn_s_setprio(0);
        const bool boundary = (kt == kt0) || (kt == qt);
        float colf[2];
        #pragma unroll
        for (int nn = 0; nn < 2; ++nn)
            colf[nn] = colfL[k0 - i0 + (nh * 2 + nn) * 16 + c];
        #pragma unroll
        for (int j = 0; j < 4; ++j) {
            float pv[2];
            #pragma unroll
            for (int nn = 0; nn < 2; ++nn) {
                float w;
                if (boundary) {
                    int delta = rowt[j] - (k0 + (nh * 2 + nn) * 16 + c);
                    w = (delta >= 0 && delta < CTX_W) ? rowf[j] * colf[nn] : 0.f;
                } else {
                    w = rowf[j] * colf[nn];
                }
                wsum[j] += w;
                pv[nn] = w * s[nn][j];
            }
            // pi(col=n*16+c) = c*4+n; this wave's pair (n=2nh,2nh+1) is adjacent
            *(unsigned*)&Ps[wq * 16 + rg * 4 + j][c * 4 + nh * 2] = f2bf2(pv[0], pv[1]);
        }
        __syncthreads();   // P rows complete (both halves)
        __builtin_amdgcn_s_setprio(1);
        #pragma unroll
        for (int u = 0; u < 2; ++u) {
            bf16x8_t pa = *(const bf16x8_t*)&Ps[wq * 16 + fr][u * 32 + fko];
            #pragma unroll
            for (int nn = 0; nn < 2; ++nn) {
                bf16x8_t kb = *(const bf16x8_t*)&Xt[cur][(nh * 2 + nn) * 16 + fr][u * 32 + fko];
                accc[nn] = __builtin_amdgcn_mfma_f32_16x16x32_bf16(pa, kb, accc[nn], 0, 0, 0);
            }
        }
        __builtin_amdgcn_s_setprio(0);
        if (hn) {
            int nxt = cur ^ 1;
            *(bf16x8_t*)&Ks[nxt][si][sdb] = nk0;
            *(bf16x8_t*)&Xt[nxt][si][sdb] = nx0;
        }
        __syncthreads();
        cur ^= 1;
    }
    // persist = Q @ M_p^T (this wave's output quadrants)
    f32x4_t pacc[2];
    pacc[0] = (f32x4_t)0.f; pacc[1] = (f32x4_t)0.f;
    const float* mph = mp + hD * HD_DIM;
    #pragma unroll
    for (int u = 0; u < 2; ++u)
        #pragma unroll
        for (int nn = 0; nn < 2; ++nn) {
            const float* br = mph + (size_t)((nh * 2 + nn) * 16 + fr) * HD_DIM + u * 32 + fko;
            float4 a = *(const float4*)br;
            float4 bq = *(const float4*)(br + 4);
            bf16x8_t f;
            f[0]=f2bf(a.x); f[1]=f2bf(a.y); f[2]=f2bf(a.z); f[3]=f2bf(a.w);
            f[4]=f2bf(bq.x); f[5]=f2bf(bq.y); f[6]=f2bf(bq.z); f[7]=f2bf(bq.w);
            pacc[nn] = __builtin_amdgcn_mfma_f32_16x16x32_bf16(qf[u], f, pacc[nn], 0, 0, 0);
        }
    // lane-reduce wsum over this wave's 16 columns, then combine halves
    #pragma unroll
    for (int j = 0; j < 4; ++j) {
        wsum[j] += __shfl_xor(wsum[j], 1);
        wsum[j] += __shfl_xor(wsum[j], 2);
        wsum[j] += __shfl_xor(wsum[j], 4);
        wsum[j] += __shfl_xor(wsum[j], 8);
    }
    if (fr == 0) {
        #pragma unroll
        for (int j = 0; j < 4; ++j)
            redS[nh][wq * 16 + rg * 4 + j] = wsum[j];
    }
    __syncthreads();
    float wtot[4];
    #pragma unroll
    for (int j = 0; j < 4; ++j)
        wtot[j] = redS[0][wq * 16 + rg * 4 + j] + redS[1][wq * 16 + rg * 4 + j];
    float gate = 1.f / (1.f + __expf(-mg[0]));
    float keep = 1.f - gate;
    #pragma unroll
    for (int nn = 0; nn < 2; ++nn) {
        #pragma unroll
        for (int j = 0; j < 4; ++j) {
            float qn = keep * qold[nn][j] + gate * (pacc[nn][j] + accc[nn][j]) / (1.f + wtot[j]);
            Ps[wq * 16 + rg * 4 + j][(nh * 2 + nn) * 16 + c] = f2bf(qn * QSCALE);
        }
    }
    __syncthreads();   // q_new rows complete (both halves)
    bf16x8_t qf2[2];
    #pragma unroll
    for (int u = 0; u < 2; ++u)
        qf2[u] = *(const bf16x8_t*)&Ps[wq * 16 + fr][u * 32 + fko];

    // ---------------- attention phase ----------------
    f32x4_t acco[2];
    acco[0] = (f32x4_t)0.f; acco[1] = (f32x4_t)0.f;
    float l_run[4] = {0.f, 0.f, 0.f, 0.f};
    {
        const u16* gk = khp + (hS + si) * HD_DIM + sdb;
        const u16* gv = vhT + (hD + si) * S_LEN + sdb;
        *(bf16x8_t*)&Ks[0][si][sdb] = *(const bf16x8_t*)gk;
        *(bf16x8_t*)&Xt[0][si][sdb] = *(const bf16x8_t*)gv;
    }
    __syncthreads();
    cur = 0;
    for (int kt = 0; kt <= qt; ++kt) {
        const int k0 = kt * KBLK;
        const bool hn = (kt < qt);
        bf16x8_t nk0, nv0;
        if (hn) {
            const u16* gk = khp + (hS + k0 + KBLK + si) * HD_DIM + sdb;
            const u16* gv = vhT + (hD + si) * S_LEN + k0 + KBLK + sdb;
            nk0 = *(const bf16x8_t*)gk;
            nv0 = *(const bf16x8_t*)gv;
        }
        f32x4_t s[2];
        s[0] = (f32x4_t)0.f; s[1] = (f32x4_t)0.f;
        __builtin_amdgcn_s_setprio(1);
        #pragma unroll
        for (int u = 0; u < 2; ++u)
            #pragma unroll
            for (int nn = 0; nn < 2; ++nn) {
                bf16x8_t kb = *(const bf16x8_t*)&Ks[cur][(nh * 2 + nn) * 16 + fr][u * 32 + fko];
                s[nn] = __builtin_amdgcn_mfma_f32_16x16x32_bf16(qf2[u], kb, s[nn], 0, 0, 0);
            }
        __builtin_amdgcn_s_setprio(0);
        if (kt == qt) {   // causal mask only on diagonal tile
            #pragma unroll
            for (int nn = 0; nn < 2; ++nn) {
                int icol = k0 + (nh * 2 + nn) * 16 + c;
                #pragma unroll
                for (int j = 0; j < 4; ++j)
                    if (icol > rowt[j]) s[nn][j] = -1e30f;
            }
        }
        #pragma unroll
        for (int j = 0; j < 4; ++j) {
            float p0 = exp2f(s[0][j]);
            float p1 = exp2f(s[1][j]);
            l_run[j] += p0 + p1;
            *(unsigned*)&Ps[wq * 16 + rg * 4 + j][c * 4 + nh * 2] = f2bf2(p0, p1);
        }
        __syncthreads();   // P rows complete (both halves)
        __builtin_amdgcn_s_setprio(1);
        #pragma unroll
        for (int u = 0; u < 2; ++u) {
            bf16x8_t pa = *(const bf16x8_t*)&Ps[wq * 16 + fr][u * 32 + fko];
            #pragma unroll
            for (int nn = 0; nn < 2; ++nn) {
                bf16x8_t vb = *(const bf16x8_t*)&Xt[cur][(nh * 2 + nn) * 16 + fr][u * 32 + fko];
                acco[nn] = __builtin_amdgcn_mfma_f32_16x16x32_bf16(pa, vb, acco[nn], 0, 0, 0);
            }
        }
        __builtin_amdgcn_s_setprio(0);
        if (hn) {
            int nxt = cur ^ 1;
            *(bf16x8_t*)&Ks[nxt][si][sdb] = nk0;
            *(bf16x8_t*)&Xt[nxt][si][sdb] = nv0;
        }
        __syncthreads();
        cur ^= 1;
    }
    #pragma unroll
    for (int j = 0; j < 4; ++j) {
        l_run[j] += __shfl_xor(l_run[j], 1);
        l_run[j] += __shfl_xor(l_run[j], 2);
        l_run[j] += __shfl_xor(l_run[j], 4);
        l_run[j] += __shfl_xor(l_run[j], 8);
    }
    if (fr == 0) {
        #pragma unroll
        for (int j = 0; j < 4; ++j)
            redS[nh][wq * 16 + rg * 4 + j] = l_run[j];
    }
    __syncthreads();
    #pragma unroll
    for (int j = 0; j < 4; ++j)
        l_run[j] = redS[0][wq * 16 + rg * 4 + j] + redS[1][wq * 16 + rg * 4 + j];
    #pragma unroll
    for (int nn = 0; nn < 2; ++nn) {
        #pragma unroll
        for (int j = 0; j < 4; ++j) {
            float o = acco[nn][j] / l_run[j];
            ao[(size_t)rowt[j] * D_DIM + h * HD_DIM + (nh * 2 + nn) * 16 + c] = f2bf(o);
        }
    }
}

extern "C" void kernel_launch(void* const* d_in, const int* in_sizes, int n_in,
                              void* d_out, int out_size, void* d_ws, size_t ws_size,
                              hipStream_t stream) {
    const float* x         = (const float*)d_in[0];
    const float* norm1_w   = (const float*)d_in[1];
    const float* norm2_w   = (const float*)d_in[2];
    const float* w_qkv     = (const float*)d_in[3];
    const float* q_norm_w  = (const float*)d_in[4];
    const float* k_norm_w  = (const float*)d_in[5];
    const float* gamma_w1  = (const float*)d_in[6];
    const float* gamma_w2  = (const float*)d_in[7];
    const float* m_persist = (const float*)d_in[8];
    const float* mem_gate  = (const float*)d_in[9];
    const float* w_o       = (const float*)d_in[10];
    const float* ffn_w1    = (const float*)d_in[11];
    const float* ffn_w3    = (const float*)d_in[12];
    const float* ffn_w2    = (const float*)d_in[13];
    float* out = (float*)d_out;
    char* ws = (char*)d_ws;

    const size_t MB = 1024 * 1024;
    u16*   h_bf   = (u16*)(ws);                 // [0,4MB) h / h2
    u16*   wqT    = (u16*)(ws + 4 * MB);        // [4,10)
    u16*   woT    = (u16*)(ws + 10 * MB);       // [10,12)
    u16*   w13T   = (u16*)(ws + 12 * MB);       // [12,23) interleaved w1/w3
    u16*   w2T    = (u16*)(ws + 23 * MB);       // [23,28.5)
    u16*   qkv_bf = (u16*)(ws + 29884416);      // [28.5,40.5) dead after split
    u16*   ao_bf  = (u16*)(ws + 38273024);      // [36.5,40.5) (after qkv dead)
    float* qh     = (float*)(ws + 42467328);    // [40.5,48.5) fp32 q
    u16*   kh     = (u16*)(ws + 50855936);      // [48.5,52.5)
    u16*   khT_s  = (u16*)(ws + 50855936 + 4 * MB);   // [52.5,56.5)
    float* gammab = (float*)(ws + 59244544);    // [56.5,+8KB)
    u16*   vhT_s  = (u16*)(ws + 59244544 + 64 * 1024); // [56.5+64KB,+4MB)
    u16*   mid_bf = (u16*)(ws + 29884416);      // [28.5,40) post-attention

    // --- prep: weight transposes + rmsnorm1 + gamma, ONE launch --------------
    hipLaunchKernelGGL(prep_kernel, dim3(3136 + S_LEN), dim3(256), 0, stream,
                       w_qkv, w_o, ffn_w1, ffn_w3, ffn_w2, wqT, woT, w13T, w2T,
                       x, norm1_w, h_bf, gamma_w1, gamma_w2, gammab);

    // --- forward pass ---------------------------------------------------------
    hipLaunchKernelGGL((gemm_bb_kernel<64, 1>), dim3(24, 32), dim3(256), 0, stream,
                       h_bf, wqT, qkv_bf, S_LEN, 3 * D_DIM, D_DIM);
    hipLaunchKernelGGL(split_rope_tr_kernel, dim3(S_LEN / 64, H_NUM), dim3(256), 0, stream,
                       qkv_bf, q_norm_w, k_norm_w, qh, kh, khT_s, vhT_s);
    hipLaunchKernelGGL(fused_omega_attn_kernel, dim3(512), dim3(512), 0, stream,
                       qh, kh, khT_s, vhT_s, gammab, m_persist, mem_gate, ao_bf);
    hipLaunchKernelGGL(gemm64_kernel, dim3(16, 32), dim3(256), 0, stream,
                       ao_bf, woT, x, out, S_LEN, D_DIM, D_DIM);
    hipLaunchKernelGGL((rmsnorm_gamma_kernel<false>), dim3(S_LEN), dim3(256), 0, stream,
                       out, norm2_w, h_bf, (const float*)nullptr,
                       (const float*)nullptr, (float*)nullptr);
    // ffn13 GEMM (BM=128) with fused SwiGLU epilogue -> mid
    hipLaunchKernelGGL((gemm_bb_kernel<128, 2>), dim3(44, 16), dim3(256), 0, stream,
                       h_bf, w13T, mid_bf, S_LEN, 2 * FFNP, D_DIM);
    hipLaunchKernelGGL(gemm64_kernel, dim3(16, 32), dim3(256), 0, stream,
                       mid_bf, w2T, out, out, S_LEN, D_DIM, FFNP);
}

// Round 23
// 217.312 us; speedup vs baseline: 1.0600x; 1.0028x over previous
//
#include <hip/hip_runtime.h>
#include <hip/hip_bf16.h>

#define S_LEN 2048
#define D_DIM 1024
#define H_NUM 16
#define HD_DIM 64
#define GH_DIM 64
#define FFN_H 2730
#define FFNP  2816          // FFN_H padded to multiple of 128 (zero-filled)
#define CTX_W 512
#define L2LAM -0.00144341687f   // log2(0.999)
#define QBLK 64
#define KBLK 64
#define ALDK 76             // LDS row stride (152B): write-conflict-free, reads <=2-way
#define QSCALE 0.1803368801111731f  // 0.125 * log2(e): scores come out ready for exp2

typedef unsigned short u16;
typedef __attribute__((ext_vector_type(8))) short bf16x8_t;
typedef __attribute__((ext_vector_type(4))) float f32x4_t;

__device__ inline float wave_sum(float v) {
    for (int off = 32; off; off >>= 1) v += __shfl_xor(v, off);
    return v;
}
// f32 -> bf16 (RNE) via the HW pack instruction: 1 VALU op.
__device__ inline u16 f2bf(float f) {
    unsigned r;
    asm("v_cvt_pk_bf16_f32 %0, %1, %2" : "=v"(r) : "v"(f), "v"(f));
    return (u16)r;
}
// pack two f32 -> u32 of 2 bf16 (lo, hi): 1 VALU op.
__device__ inline unsigned f2bf2(float lo, float hi) {
    unsigned r;
    asm("v_cvt_pk_bf16_f32 %0, %1, %2" : "=v"(r) : "v"(lo), "v"(hi));
    return r;
}
__device__ inline float bf2f(u16 u) {
    return __uint_as_float(((unsigned int)u) << 16);
}
__device__ inline void gload16(const void* g, void* l) {
    __builtin_amdgcn_global_load_lds(
        (const __attribute__((address_space(1))) void*)g,
        (__attribute__((address_space(3))) void*)l, 16, 0, 0);
}

// ------- RMSNorm (fp32 in -> bf16 out) --------------------------------------
__global__ __launch_bounds__(256) void rmsnorm_kernel(
    const float* __restrict__ in, const float* __restrict__ w,
    u16* __restrict__ out)
{
    __shared__ float wsum[4];
    int row = blockIdx.x;
    int tid = threadIdx.x, lane = tid & 63, wv = tid >> 6;
    const float4* ir = reinterpret_cast<const float4*>(in + (size_t)row * D_DIM);
    float4 v = ir[tid];
    float ss = v.x*v.x + v.y*v.y + v.z*v.z + v.w*v.w;
    ss = wave_sum(ss);
    if (lane == 0) wsum[wv] = ss;
    __syncthreads();
    float tot = wsum[0] + wsum[1] + wsum[2] + wsum[3];
    float scale = rsqrtf(tot / (float)D_DIM + 1e-6f);
    const float4* wr = reinterpret_cast<const float4*>(w);
    float4 wv4 = wr[tid];
    uint2 o;
    o.x = f2bf2(v.x * scale * wv4.x, v.y * scale * wv4.y);
    o.y = f2bf2(v.z * scale * wv4.z, v.w * scale * wv4.w);
    *reinterpret_cast<uint2*>(out + (size_t)row * D_DIM + tid * 4) = o;
}

// --- prep: weight transposes (64x64 tiles, 128B writes) + rmsnorm1 ----------
// Segments: qkv 768 | wo 256 | w1 704 | w3 704 | w2 704 | gw1 16 = 3152 blocks;
// blocks [3152, 3152+2048) do rmsnorm1 for row = b-3152.
__global__ __launch_bounds__(256) void prep_kernel(
    const float* __restrict__ w_qkv, const float* __restrict__ w_o,
    const float* __restrict__ w1f, const float* __restrict__ w3f,
    const float* __restrict__ w2f, const float* __restrict__ gw1f,
    u16* __restrict__ wqT, u16* __restrict__ woT, u16* __restrict__ w13T,
    u16* __restrict__ w2T, u16* __restrict__ gw1T,
    const float* __restrict__ x, const float* __restrict__ norm1_w,
    u16* __restrict__ h_bf)
{
    __shared__ float tile[64][65];
    __shared__ float wsum[4];
    int b = blockIdx.x;
    int tid = threadIdx.x;
    if (b < 3152) {
        const float* src; u16* dst;
        int srcK, srcN, Kp, rowOff, rowMul, nbx;
        if (b < 768)       {           src = w_qkv; dst = wqT;  srcK = 1024; srcN = 3072; Kp = 1024; rowOff = 0; rowMul = 1; nbx = 48; }
        else if (b < 1024) { b -= 768;  src = w_o;  dst = woT;  srcK = 1024; srcN = 1024; Kp = 1024; rowOff = 0; rowMul = 1; nbx = 16; }
        else if (b < 1728) { b -= 1024; src = w1f;  dst = w13T; srcK = 1024; srcN = 2730; Kp = 1024; rowOff = 0; rowMul = 2; nbx = 44; }
        else if (b < 2432) { b -= 1728; src = w3f;  dst = w13T; srcK = 1024; srcN = 2730; Kp = 1024; rowOff = 1; rowMul = 2; nbx = 44; }
        else if (b < 3136) { b -= 2432; src = w2f;  dst = w2T;  srcK = 2730; srcN = 1024; Kp = 2816; rowOff = 0; rowMul = 1; nbx = 16; }
        else               { b -= 3136; src = gw1f; dst = gw1T; srcK = 1024; srcN = 64;   Kp = 1024; rowOff = 0; rowMul = 1; nbx = 1; }
        int n0 = (b % nbx) * 64, k0 = (b / nbx) * 64;
        int tx = tid & 15, ty = tid >> 4;       // read: 16 thr/row x float4
        bool interior = (k0 + 63 < srcK) && (n0 + 63 < srcN);
        #pragma unroll
        for (int p = 0; p < 4; ++p) {
            int kk = p * 16 + ty;
            int r = k0 + kk;
            int cb = n0 + tx * 4;
            float4 v;
            if (interior) {
                v = *(const float4*)(src + (size_t)r * srcN + cb);
            } else {
                v.x = (r < srcK && cb     < srcN) ? src[(size_t)r * srcN + cb]     : 0.f;
                v.y = (r < srcK && cb + 1 < srcN) ? src[(size_t)r * srcN + cb + 1] : 0.f;
                v.z = (r < srcK && cb + 2 < srcN) ? src[(size_t)r * srcN + cb + 2] : 0.f;
                v.w = (r < srcK && cb + 3 < srcN) ? src[(size_t)r * srcN + cb + 3] : 0.f;
            }
            tile[kk][tx*4+0] = v.x; tile[kk][tx*4+1] = v.y;
            tile[kk][tx*4+2] = v.z; tile[kk][tx*4+3] = v.w;
        }
        __syncthreads();
        int wx = tid & 7, wy = tid >> 3;        // write: 8 thr/row x uint4(8 u16)
        #pragma unroll
        for (int p = 0; p < 2; ++p) {
            int nn = p * 32 + wy;
            int ks = wx * 8;
            uint4 o;
            o.x = f2bf2(tile[ks+0][nn], tile[ks+1][nn]);
            o.y = f2bf2(tile[ks+2][nn], tile[ks+3][nn]);
            o.z = f2bf2(tile[ks+4][nn], tile[ks+5][nn]);
            o.w = f2bf2(tile[ks+6][nn], tile[ks+7][nn]);
            *(uint4*)(dst + (size_t)(rowOff + (size_t)(n0 + nn) * rowMul) * Kp + k0 + ks) = o;
        }
    } else {
        int row = b - 3152;
        int lane = tid & 63, wv = tid >> 6;
        const float4* ir = reinterpret_cast<const float4*>(x + (size_t)row * D_DIM);
        float4 v = ir[tid];
        float ss = v.x*v.x + v.y*v.y + v.z*v.z + v.w*v.w;
        ss = wave_sum(ss);
        if (lane == 0) wsum[wv] = ss;
        __syncthreads();
        float tot = wsum[0] + wsum[1] + wsum[2] + wsum[3];
        float scale = rsqrtf(tot / (float)D_DIM + 1e-6f);
        const float4* wr = reinterpret_cast<const float4*>(norm1_w);
        float4 wv4 = wr[tid];
        uint2 o;
        o.x = f2bf2(v.x * scale * wv4.x, v.y * scale * wv4.y);
        o.y = f2bf2(v.z * scale * wv4.z, v.w * scale * wv4.w);
        *reinterpret_cast<uint2*>(h_bf + (size_t)row * D_DIM + tid * 4) = o;
    }
}

// --- gamma gate as MFMA GEMM + fused finish ---------------------------------
// g1 = h(2048x1024) @ W1(1024x64) via 64x64 tiles (grid 32); each block holds
// its 64 tokens' FULL g1 rows in-register -> silu, x w2, row-reduce, sigmoid.
__global__ __launch_bounds__(256) void gamma_gemm_kernel(
    const u16* __restrict__ A, const u16* __restrict__ B,
    const float* __restrict__ w2, float* __restrict__ gamma, int K)
{
    __shared__ u16 As[64 * 64];
    __shared__ u16 Bs[64 * 64];
    __shared__ float red[2][64];
    int tid = threadIdx.x, lane = tid & 63, wid = tid >> 6;
    int wr = wid >> 1, wc = wid & 1;
    int row0 = blockIdx.x * 64;
    int l8 = lane >> 3, l7 = lane & 7;
    f32x4_t acc[2][2];
    #pragma unroll
    for (int i = 0; i < 2; ++i)
        #pragma unroll
        for (int j = 0; j < 2; ++j) acc[i][j] = (f32x4_t)0.f;
    int fr = lane & 15, fo = (lane >> 4) * 8;
    for (int k0 = 0; k0 < K; k0 += 64) {
        #pragma unroll
        for (int i = 0; i < 2; ++i) {
            int ch = wid * 2 + i;
            const u16* ga = A + (size_t)(row0 + ch * 8 + l8) * K + k0 + l7 * 8;
            gload16(ga, &As[ch * 512]);
            const u16* gb = B + (size_t)(ch * 8 + l8) * K + k0 + l7 * 8;
            gload16(gb, &Bs[ch * 512]);
        }
        __syncthreads();
        __builtin_amdgcn_s_setprio(1);
        #pragma unroll
        for (int khf = 0; khf < 2; ++khf) {
            bf16x8_t bfrag[2];
            #pragma unroll
            for (int ni = 0; ni < 2; ++ni)
                bfrag[ni] = *(const bf16x8_t*)&Bs[(wc * 32 + ni * 16 + fr) * 64 + khf * 32 + fo];
            #pragma unroll
            for (int mi = 0; mi < 2; ++mi) {
                bf16x8_t af = *(const bf16x8_t*)&As[(wr * 32 + mi * 16 + fr) * 64 + khf * 32 + fo];
                #pragma unroll
                for (int ni = 0; ni < 2; ++ni)
                    acc[mi][ni] = __builtin_amdgcn_mfma_f32_16x16x32_bf16(
                        af, bfrag[ni], acc[mi][ni], 0, 0, 0);
            }
        }
        __builtin_amdgcn_s_setprio(0);
        __syncthreads();
    }
    int dr = (lane >> 4) * 4, dc = lane & 15;
    float w2v0 = w2[wc * 32 + dc];
    float w2v1 = w2[wc * 32 + 16 + dc];
    #pragma unroll
    for (int mi = 0; mi < 2; ++mi) {
        #pragma unroll
        for (int j = 0; j < 4; ++j) {
            float v0 = acc[mi][0][j];
            float v1 = acc[mi][1][j];
            float t = v0 / (1.f + __expf(-v0)) * w2v0
                    + v1 / (1.f + __expf(-v1)) * w2v1;
            t += __shfl_xor(t, 1);
            t += __shfl_xor(t, 2);
            t += __shfl_xor(t, 4);
            t += __shfl_xor(t, 8);
            if (dc == 0) red[wc][wr * 32 + mi * 16 + dr + j] = t;
        }
    }
    __syncthreads();
    if (tid < 64) {
        float g = red[0][tid] + red[1][tid];
        gamma[row0 + tid] = 1.f / (1.f + __expf(-g));
    }
}

// ---- fused split qkv + qk rmsnorm + RoPE + KV transpose (one launch) -------
__global__ __launch_bounds__(256) void split_rope_tr_kernel(
    const u16* __restrict__ qkv, const float* __restrict__ qw,
    const float* __restrict__ kw, float* __restrict__ qhp,
    u16* __restrict__ khp, u16* __restrict__ khT, u16* __restrict__ vhT)
{
    __shared__ u16 tk[64][ALDK];
    __shared__ u16 tv[64][ALDK];
    int tid = threadIdx.x;
    int w = tid >> 6, d = tid & 63;
    int h = blockIdx.y;
    int s0 = blockIdx.x * 64;
    float qwv = qw[d], kwv = kw[d];
    int j = d & 31;
    float inv = expf(-(float)j * (9.2103403719761836f / 32.0f));
    float sgn = (d < 32) ? -1.f : 1.f;
    for (int i = 0; i < 16; ++i) {
        int sl = w * 16 + i;
        int s = s0 + sl;
        size_t base = (size_t)s * (3 * D_DIM) + h * HD_DIM + d;
        float qv = bf2f(qkv[base]);
        float kv = bf2f(qkv[base + D_DIM]);
        u16  vv = qkv[base + 2 * D_DIM];
        float sq = wave_sum(qv * qv);
        float qn = qv * rsqrtf(sq / (float)HD_DIM + 1e-6f) * qwv;
        float sk = wave_sum(kv * kv);
        float kn = kv * rsqrtf(sk / (float)HD_DIM + 1e-6f) * kwv;
        float ang = (float)s * inv;
        float cs = cosf(ang), sn = sinf(ang);
        float qp = __shfl_xor(qn, 32);
        float kp = __shfl_xor(kn, 32);
        float qo = qn * cs + sgn * qp * sn;
        float ko = kn * cs + sgn * kp * sn;
        size_t ob = ((size_t)h * S_LEN + s) * HD_DIM + d;
        u16 kb = f2bf(ko);
        qhp[ob] = qo;
        khp[ob] = kb;
        tk[sl][d] = kb;
        tv[sl][d] = vv;
    }
    __syncthreads();
    int r = tid >> 2, cc = (tid & 3) * 16;
    union { u16 u[16]; bf16x8_t v[2]; } ok, ov;
    #pragma unroll
    for (int e = 0; e < 16; ++e) {
        int ksrc = (e & 3) * 16 + (tid & 3) * 4 + (e >> 2);   // pi^-1 permute
        ok.u[e] = tk[ksrc][r]; ov.u[e] = tv[ksrc][r];
    }
    u16* kd = khT + ((size_t)h * HD_DIM + r) * S_LEN + s0 + cc;
    u16* vd = vhT + ((size_t)h * HD_DIM + r) * S_LEN + s0 + cc;
    *(bf16x8_t*)kd       = ok.v[0];
    *(bf16x8_t*)(kd + 8) = ok.v[1];
    *(bf16x8_t*)vd       = ov.v[0];
    *(bf16x8_t*)(vd + 8) = ov.v[1];
}

// ---------------- bf16 MFMA GEMM, 128-col tiles ------------------------------
// MODE 1: bf16 out.  MODE 2: paired silu-mul, bf16 out width N/2.
template<int BM, int MODE>
__global__ __launch_bounds__(256) void gemm_bb_kernel(
    const u16* __restrict__ A, const u16* __restrict__ B,
    u16* __restrict__ Cb, int M, int N, int K)
{
    constexpr int MREP = BM / 32;
    constexpr int ACH  = BM / 32;
    __shared__ u16 As[BM * 64];
    __shared__ u16 Bs[128 * 64];
    int tid = threadIdx.x, lane = tid & 63, wid = tid >> 6;
    int wr = wid >> 1, wc = wid & 1;
    int row0 = blockIdx.y * BM, col0 = blockIdx.x * 128;
    int l8 = lane >> 3, l7 = lane & 7;
    f32x4_t acc[MREP][4];
    #pragma unroll
    for (int i = 0; i < MREP; ++i)
        #pragma unroll
        for (int j = 0; j < 4; ++j) acc[i][j] = (f32x4_t)0.f;

    int fr = lane & 15, fo = (lane >> 4) * 8;
    for (int k0 = 0; k0 < K; k0 += 64) {
        #pragma unroll
        for (int i = 0; i < ACH; ++i) {
            int ch = wid * ACH + i;
            const u16* ga = A + (size_t)(row0 + ch * 8 + l8) * K + k0 + l7 * 8;
            gload16(ga, &As[ch * 512]);
        }
        #pragma unroll
        for (int i = 0; i < 4; ++i) {
            int ch = wid * 4 + i;
            const u16* gb = B + (size_t)(col0 + ch * 8 + l8) * K + k0 + l7 * 8;
            gload16(gb, &Bs[ch * 512]);
        }
        __syncthreads();
        __builtin_amdgcn_s_setprio(1);
        #pragma unroll
        for (int khf = 0; khf < 2; ++khf) {
            bf16x8_t bfrag[4];
            #pragma unroll
            for (int ni = 0; ni < 4; ++ni)
                bfrag[ni] = *(const bf16x8_t*)&Bs[(wc * 64 + ni * 16 + fr) * 64 + khf * 32 + fo];
            #pragma unroll
            for (int mi = 0; mi < MREP; ++mi) {
                bf16x8_t af = *(const bf16x8_t*)&As[(wr * (BM / 2) + mi * 16 + fr) * 64 + khf * 32 + fo];
                #pragma unroll
                for (int ni = 0; ni < 4; ++ni)
                    acc[mi][ni] = __builtin_amdgcn_mfma_f32_16x16x32_bf16(
                        af, bfrag[ni], acc[mi][ni], 0, 0, 0);
            }
        }
        __builtin_amdgcn_s_setprio(0);
        __syncthreads();
    }
    int dr = (lane >> 4) * 4, dc = lane & 15;
    #pragma unroll
    for (int mi = 0; mi < MREP; ++mi) {
        int gr = row0 + wr * (BM / 2) + mi * 16 + dr;
        #pragma unroll
        for (int ni = 0; ni < 4; ++ni) {
            int gc = col0 + wc * 64 + ni * 16 + dc;
            #pragma unroll
            for (int j = 0; j < 4; ++j) {
                float v = acc[mi][ni][j];
                if (MODE == 1) {
                    Cb[(size_t)(gr + j) * N + gc] = f2bf(v);
                } else {
                    float partner = __shfl_xor(v, 1);
                    float a1 = (dc & 1) ? partner : v;
                    float a3 = (dc & 1) ? v : partner;
                    float rr = a1 / (1.f + __expf(-a1)) * a3;
                    if (!(dc & 1))
                        Cb[(size_t)(gr + j) * (N >> 1) + (gc >> 1)] = f2bf(rr);
                }
            }
        }
    }
}

// ---------------- bf16 MFMA GEMM, 64x64 tiles, fp32 out + residual ----------
__global__ __launch_bounds__(256) void gemm64_kernel(
    const u16* __restrict__ A, const u16* __restrict__ B,
    const float* __restrict__ res, float* __restrict__ Cf,
    int M, int N, int K)
{
    __shared__ u16 As[64 * 64];
    __shared__ u16 Bs[64 * 64];
    int tid = threadIdx.x, lane = tid & 63, wid = tid >> 6;
    int wr = wid >> 1, wc = wid & 1;
    int row0 = blockIdx.y * 64, col0 = blockIdx.x * 64;
    int l8 = lane >> 3, l7 = lane & 7;
    f32x4_t acc[2][2];
    #pragma unroll
    for (int i = 0; i < 2; ++i)
        #pragma unroll
        for (int j = 0; j < 2; ++j) acc[i][j] = (f32x4_t)0.f;
    int fr = lane & 15, fo = (lane >> 4) * 8;
    for (int k0 = 0; k0 < K; k0 += 64) {
        #pragma unroll
        for (int i = 0; i < 2; ++i) {
            int ch = wid * 2 + i;
            const u16* ga = A + (size_t)(row0 + ch * 8 + l8) * K + k0 + l7 * 8;
            gload16(ga, &As[ch * 512]);
            const u16* gb = B + (size_t)(col0 + ch * 8 + l8) * K + k0 + l7 * 8;
            gload16(gb, &Bs[ch * 512]);
        }
        __syncthreads();
        __builtin_amdgcn_s_setprio(1);
        #pragma unroll
        for (int khf = 0; khf < 2; ++khf) {
            bf16x8_t bfrag[2];
            #pragma unroll
            for (int ni = 0; ni < 2; ++ni)
                bfrag[ni] = *(const bf16x8_t*)&Bs[(wc * 32 + ni * 16 + fr) * 64 + khf * 32 + fo];
            #pragma unroll
            for (int mi = 0; mi < 2; ++mi) {
                bf16x8_t af = *(const bf16x8_t*)&As[(wr * 32 + mi * 16 + fr) * 64 + khf * 32 + fo];
                #pragma unroll
                for (int ni = 0; ni < 2; ++ni)
                    acc[mi][ni] = __builtin_amdgcn_mfma_f32_16x16x32_bf16(
                        af, bfrag[ni], acc[mi][ni], 0, 0, 0);
            }
        }
        __builtin_amdgcn_s_setprio(0);
        __syncthreads();
    }
    int dr = (lane >> 4) * 4, dc = lane & 15;
    #pragma unroll
    for (int mi = 0; mi < 2; ++mi) {
        int gr = row0 + wr * 32 + mi * 16 + dr;
        #pragma unroll
        for (int ni = 0; ni < 2; ++ni) {
            int gc = col0 + wc * 32 + ni * 16 + dc;
            #pragma unroll
            for (int j = 0; j < 4; ++j) {
                size_t off = (size_t)(gr + j) * N + gc;
                Cf[off] = acc[mi][ni][j] + res[off];
            }
        }
    }
}

// ============ FUSED omega-rule + flash attention (8-wave col-split) =========
__global__ __launch_bounds__(512) void fused_omega_attn_kernel(
    const float* __restrict__ qhp, const u16* __restrict__ khp,
    const u16* __restrict__ khT, const u16* __restrict__ vhT,
    const float* __restrict__ gammab, const float* __restrict__ mp,
    const float* __restrict__ mg, u16* __restrict__ ao)
{
    __shared__ u16 Ks[2][KBLK][ALDK];
    __shared__ u16 Xt[2][KBLK][ALDK];
    __shared__ u16 Ps[QBLK][ALDK];
    __shared__ float colfL[CTX_W + KBLK];
    __shared__ float redS[2][QBLK];      // cross-half reduction (wsum / l)
    const int tid = threadIdx.x, lane = tid & 63, wid = tid >> 6;
    const int wq = wid & 3;              // row group (16 q-rows)
    const int nh = wid >> 2;             // column half (0/1)
    const int b = blockIdx.x;
    const int hi = (b >> 8) & 1;
    const int h = ((b & 7) << 1) + hi;
    const int s5 = (b >> 3) & 31;
    const int qt = hi ? (31 - s5) : s5;
    const int q0 = qt * QBLK;
    const int fr = lane & 15, g4 = lane >> 4;
    const int fko = g4 * 8;
    const int c = fr, rg = g4;
    const int si = tid >> 3, sdb = (tid & 7) * 8;   // staging: 512 thr x 16B
    const size_t hS = (size_t)h * S_LEN;
    const size_t hD = (size_t)h * HD_DIM;

    int rowt[4]; float rowf[4];
    #pragma unroll
    for (int j = 0; j < 4; ++j) {
        rowt[j] = q0 + wq * 16 + rg * 4 + j;
        rowf[j] = exp2f((float)(wq * 16 + rg * 4 + j) * L2LAM);
    }
    bf16x8_t qf[2];
    {
        const float* qrow = qhp + (hS + q0 + wq * 16 + fr) * HD_DIM;
        #pragma unroll
        for (int u = 0; u < 2; ++u) {
            float4 a = *(const float4*)(qrow + u * 32 + fko);
            float4 bq = *(const float4*)(qrow + u * 32 + fko + 4);
            bf16x8_t f;
            f[0]=f2bf(a.x); f[1]=f2bf(a.y); f[2]=f2bf(a.z); f[3]=f2bf(a.w);
            f[4]=f2bf(bq.x); f[5]=f2bf(bq.y); f[6]=f2bf(bq.z); f[7]=f2bf(bq.w);
            qf[u] = f;
        }
    }
    // preload q_old for this wave's column quadrants (n = 2*nh + nn)
    float qold[2][4];
    #pragma unroll
    for (int nn = 0; nn < 2; ++nn)
        #pragma unroll
        for (int j = 0; j < 4; ++j)
            qold[nn][j] = qhp[(hS + rowt[j]) * HD_DIM + (nh * 2 + nn) * 16 + c];

    // ---------------- omega phase ----------------
    f32x4_t accc[2];
    accc[0] = (f32x4_t)0.f; accc[1] = (f32x4_t)0.f;
    float wsum[4] = {0.f, 0.f, 0.f, 0.f};
    const int kt0 = (q0 > (CTX_W - 1)) ? (q0 - (CTX_W - 1)) / KBLK : 0;
    const int i0 = kt0 * KBLK;
    const int nwin = (qt + 1) * KBLK - i0;
    for (int idx = tid; idx < nwin; idx += 512) {
        int icol = i0 + idx;
        colfL[idx] = exp2f((float)(q0 - icol) * L2LAM) * gammab[icol];
    }
    {
        const u16* gk = khp + (hS + kt0 * KBLK + si) * HD_DIM + sdb;
        const u16* gx = khT + (hD + si) * S_LEN + kt0 * KBLK + sdb;
        *(bf16x8_t*)&Ks[0][si][sdb] = *(const bf16x8_t*)gk;
        *(bf16x8_t*)&Xt[0][si][sdb] = *(const bf16x8_t*)gx;
    }
    __syncthreads();
    int cur = 0;
    for (int kt = kt0; kt <= qt; ++kt) {
        const int k0 = kt * KBLK;
        const bool hn = (kt < qt);
        bf16x8_t nk0, nx0;
        if (hn) {
            const u16* gk = khp + (hS + k0 + KBLK + si) * HD_DIM + sdb;
            const u16* gx = khT + (hD + si) * S_LEN + k0 + KBLK + sdb;
            nk0 = *(const bf16x8_t*)gk;
            nx0 = *(const bf16x8_t*)gx;
        }
        f32x4_t s[2];
        s[0] = (f32x4_t)0.f; s[1] = (f32x4_t)0.f;
        __builtin_amdgcn_s_setprio(1);
        #pragma unroll
        for (int u = 0; u < 2; ++u)
            #pragma unroll
            for (int nn = 0; nn < 2; ++nn) {
                bf16x8_t kb = *(const bf16x8_t*)&Ks[cur][(nh * 2 + nn) * 16 + fr][u * 32 + fko];
                s[nn] = __builtin_amdgcn_mfma_f32_16x16x32_bf16(qf[u], kb, s[nn], 0, 0, 0);
            }
        __builtin_amdgcn_s_setprio(0);
        const bool boundary = (kt == kt0) || (kt == qt);
        float colf[2];
        #pragma unroll
        for (int nn = 0; nn < 2; ++nn)
            colf[nn] = colfL[k0 - i0 + (nh * 2 + nn) * 16 + c];
        #pragma unroll
        for (int j = 0; j < 4; ++j) {
            float pv[2];
            #pragma unroll
            for (int nn = 0; nn < 2; ++nn) {
                float w;
                if (boundary) {
                    int delta = rowt[j] - (k0 + (nh * 2 + nn) * 16 + c);
                    w = (delta >= 0 && delta < CTX_W) ? rowf[j] * colf[nn] : 0.f;
                } else {
                    w = rowf[j] * colf[nn];
                }
                wsum[j] += w;
                pv[nn] = w * s[nn][j];
            }
            *(unsigned*)&Ps[wq * 16 + rg * 4 + j][c * 4 + nh * 2] = f2bf2(pv[0], pv[1]);
        }
        __syncthreads();   // P rows complete (both halves)
        __builtin_amdgcn_s_setprio(1);
        #pragma unroll
        for (int u = 0; u < 2; ++u) {
            bf16x8_t pa = *(const bf16x8_t*)&Ps[wq * 16 + fr][u * 32 + fko];
            #pragma unroll
            for (int nn = 0; nn < 2; ++nn) {
                bf16x8_t kb = *(const bf16x8_t*)&Xt[cur][(nh * 2 + nn) * 16 + fr][u * 32 + fko];
                accc[nn] = __builtin_amdgcn_mfma_f32_16x16x32_bf16(pa, kb, accc[nn], 0, 0, 0);
            }
        }
        __builtin_amdgcn_s_setprio(0);
        if (hn) {
            int nxt = cur ^ 1;
            *(bf16x8_t*)&Ks[nxt][si][sdb] = nk0;
            *(bf16x8_t*)&Xt[nxt][si][sdb] = nx0;
        }
        __syncthreads();
        cur ^= 1;
    }
    // persist = Q @ M_p^T (this wave's output quadrants)
    f32x4_t pacc[2];
    pacc[0] = (f32x4_t)0.f; pacc[1] = (f32x4_t)0.f;
    const float* mph = mp + hD * HD_DIM;
    #pragma unroll
    for (int u = 0; u < 2; ++u)
        #pragma unroll
        for (int nn = 0; nn < 2; ++nn) {
            const float* br = mph + (size_t)((nh * 2 + nn) * 16 + fr) * HD_DIM + u * 32 + fko;
            float4 a = *(const float4*)br;
            float4 bq = *(const float4*)(br + 4);
            bf16x8_t f;
            f[0]=f2bf(a.x); f[1]=f2bf(a.y); f[2]=f2bf(a.z); f[3]=f2bf(a.w);
            f[4]=f2bf(bq.x); f[5]=f2bf(bq.y); f[6]=f2bf(bq.z); f[7]=f2bf(bq.w);
            pacc[nn] = __builtin_amdgcn_mfma_f32_16x16x32_bf16(qf[u], f, pacc[nn], 0, 0, 0);
        }
    #pragma unroll
    for (int j = 0; j < 4; ++j) {
        wsum[j] += __shfl_xor(wsum[j], 1);
        wsum[j] += __shfl_xor(wsum[j], 2);
        wsum[j] += __shfl_xor(wsum[j], 4);
        wsum[j] += __shfl_xor(wsum[j], 8);
    }
    if (fr == 0) {
        #pragma unroll
        for (int j = 0; j < 4; ++j)
            redS[nh][wq * 16 + rg * 4 + j] = wsum[j];
    }
    __syncthreads();
    float wtot[4];
    #pragma unroll
    for (int j = 0; j < 4; ++j)
        wtot[j] = redS[0][wq * 16 + rg * 4 + j] + redS[1][wq * 16 + rg * 4 + j];
    float gate = 1.f / (1.f + __expf(-mg[0]));
    float keep = 1.f - gate;
    #pragma unroll
    for (int nn = 0; nn < 2; ++nn) {
        #pragma unroll
        for (int j = 0; j < 4; ++j) {
            float qn = keep * qold[nn][j] + gate * (pacc[nn][j] + accc[nn][j]) / (1.f + wtot[j]);
            Ps[wq * 16 + rg * 4 + j][(nh * 2 + nn) * 16 + c] = f2bf(qn * QSCALE);
        }
    }
    __syncthreads();   // q_new rows complete (both halves)
    bf16x8_t qf2[2];
    #pragma unroll
    for (int u = 0; u < 2; ++u)
        qf2[u] = *(const bf16x8_t*)&Ps[wq * 16 + fr][u * 32 + fko];

    // ---------------- attention phase ----------------
    f32x4_t acco[2];
    acco[0] = (f32x4_t)0.f; acco[1] = (f32x4_t)0.f;
    float l_run[4] = {0.f, 0.f, 0.f, 0.f};
    {
        const u16* gk = khp + (hS + si) * HD_DIM + sdb;
        const u16* gv = vhT + (hD + si) * S_LEN + sdb;
        *(bf16x8_t*)&Ks[0][si][sdb] = *(const bf16x8_t*)gk;
        *(bf16x8_t*)&Xt[0][si][sdb] = *(const bf16x8_t*)gv;
    }
    __syncthreads();
    cur = 0;
    for (int kt = 0; kt <= qt; ++kt) {
        const int k0 = kt * KBLK;
        const bool hn = (kt < qt);
        bf16x8_t nk0, nv0;
        if (hn) {
            const u16* gk = khp + (hS + k0 + KBLK + si) * HD_DIM + sdb;
            const u16* gv = vhT + (hD + si) * S_LEN + k0 + KBLK + sdb;
            nk0 = *(const bf16x8_t*)gk;
            nv0 = *(const bf16x8_t*)gv;
        }
        f32x4_t s[2];
        s[0] = (f32x4_t)0.f; s[1] = (f32x4_t)0.f;
        __builtin_amdgcn_s_setprio(1);
        #pragma unroll
        for (int u = 0; u < 2; ++u)
            #pragma unroll
            for (int nn = 0; nn < 2; ++nn) {
                bf16x8_t kb = *(const bf16x8_t*)&Ks[cur][(nh * 2 + nn) * 16 + fr][u * 32 + fko];
                s[nn] = __builtin_amdgcn_mfma_f32_16x16x32_bf16(qf2[u], kb, s[nn], 0, 0, 0);
            }
        __builtin_amdgcn_s_setprio(0);
        if (kt == qt) {   // causal mask only on diagonal tile
            #pragma unroll
            for (int nn = 0; nn < 2; ++nn) {
                int icol = k0 + (nh * 2 + nn) * 16 + c;
                #pragma unroll
                for (int j = 0; j < 4; ++j)
                    if (icol > rowt[j]) s[nn][j] = -1e30f;
            }
        }
        #pragma unroll
        for (int j = 0; j < 4; ++j) {
            float p0 = exp2f(s[0][j]);
            float p1 = exp2f(s[1][j]);
            l_run[j] += p0 + p1;
            *(unsigned*)&Ps[wq * 16 + rg * 4 + j][c * 4 + nh * 2] = f2bf2(p0, p1);
        }
        __syncthreads();   // P rows complete (both halves)
        __builtin_amdgcn_s_setprio(1);
        #pragma unroll
        for (int u = 0; u < 2; ++u) {
            bf16x8_t pa = *(const bf16x8_t*)&Ps[wq * 16 + fr][u * 32 + fko];
            #pragma unroll
            for (int nn = 0; nn < 2; ++nn) {
                bf16x8_t vb = *(const bf16x8_t*)&Xt[cur][(nh * 2 + nn) * 16 + fr][u * 32 + fko];
                acco[nn] = __builtin_amdgcn_mfma_f32_16x16x32_bf16(pa, vb, acco[nn], 0, 0, 0);
            }
        }
        __builtin_amdgcn_s_setprio(0);
        if (hn) {
            int nxt = cur ^ 1;
            *(bf16x8_t*)&Ks[nxt][si][sdb] = nk0;
            *(bf16x8_t*)&Xt[nxt][si][sdb] = nv0;
        }
        __syncthreads();
        cur ^= 1;
    }
    #pragma unroll
    for (int j = 0; j < 4; ++j) {
        l_run[j] += __shfl_xor(l_run[j], 1);
        l_run[j] += __shfl_xor(l_run[j], 2);
        l_run[j] += __shfl_xor(l_run[j], 4);
        l_run[j] += __shfl_xor(l_run[j], 8);
    }
    if (fr == 0) {
        #pragma unroll
        for (int j = 0; j < 4; ++j)
            redS[nh][wq * 16 + rg * 4 + j] = l_run[j];
    }
    __syncthreads();
    #pragma unroll
    for (int j = 0; j < 4; ++j)
        l_run[j] = redS[0][wq * 16 + rg * 4 + j] + redS[1][wq * 16 + rg * 4 + j];
    #pragma unroll
    for (int nn = 0; nn < 2; ++nn) {
        #pragma unroll
        for (int j = 0; j < 4; ++j) {
            float o = acco[nn][j] / l_run[j];
            ao[(size_t)rowt[j] * D_DIM + h * HD_DIM + (nh * 2 + nn) * 16 + c] = f2bf(o);
        }
    }
}

extern "C" void kernel_launch(void* const* d_in, const int* in_sizes, int n_in,
                              void* d_out, int out_size, void* d_ws, size_t ws_size,
                              hipStream_t stream) {
    const float* x         = (const float*)d_in[0];
    const float* norm1_w   = (const float*)d_in[1];
    const float* norm2_w   = (const float*)d_in[2];
    const float* w_qkv     = (const float*)d_in[3];
    const float* q_norm_w  = (const float*)d_in[4];
    const float* k_norm_w  = (const float*)d_in[5];
    const float* gamma_w1  = (const float*)d_in[6];
    const float* gamma_w2  = (const float*)d_in[7];
    const float* m_persist = (const float*)d_in[8];
    const float* mem_gate  = (const float*)d_in[9];
    const float* w_o       = (const float*)d_in[10];
    const float* ffn_w1    = (const float*)d_in[11];
    const float* ffn_w3    = (const float*)d_in[12];
    const float* ffn_w2    = (const float*)d_in[13];
    float* out = (float*)d_out;
    char* ws = (char*)d_ws;

    const size_t MB = 1024 * 1024;
    u16*   h_bf   = (u16*)(ws);                 // [0,4MB) h / h2
    u16*   wqT    = (u16*)(ws + 4 * MB);        // [4,10)
    u16*   woT    = (u16*)(ws + 10 * MB);       // [10,12)
    u16*   w13T   = (u16*)(ws + 12 * MB);       // [12,23) interleaved w1/w3
    u16*   w2T    = (u16*)(ws + 23 * MB);       // [23,28.5)
    u16*   qkv_bf = (u16*)(ws + 29884416);      // [28.5,40.5) dead after split
    u16*   ao_bf  = (u16*)(ws + 38273024);      // [36.5,40.5) (after qkv dead)
    float* qh     = (float*)(ws + 42467328);    // [40.5,48.5) fp32 q
    u16*   kh     = (u16*)(ws + 50855936);      // [48.5,52.5)
    u16*   khT_s  = (u16*)(ws + 50855936 + 4 * MB);   // [52.5,56.5)
    float* gammab = (float*)(ws + 59244544);    // [56.5,+8KB)
    u16*   vhT_s  = (u16*)(ws + 59244544 + 65536);    // [56.56,+4MB)
    u16*   gw1T   = (u16*)(ws + 63504384);      // [60.56,+128KB) gamma W1^T bf16
    u16*   mid_bf = (u16*)(ws + 29884416);      // [28.5,40) post-attention

    // --- prep: weight transposes (incl. gw1) + rmsnorm1, ONE launch ----------
    hipLaunchKernelGGL(prep_kernel, dim3(3152 + S_LEN), dim3(256), 0, stream,
                       w_qkv, w_o, ffn_w1, ffn_w3, ffn_w2, gamma_w1,
                       wqT, woT, w13T, w2T, gw1T, x, norm1_w, h_bf);

    // --- forward pass ---------------------------------------------------------
    hipLaunchKernelGGL((gemm_bb_kernel<64, 1>), dim3(24, 32), dim3(256), 0, stream,
                       h_bf, wqT, qkv_bf, S_LEN, 3 * D_DIM, D_DIM);
    // gamma gate via MFMA GEMM + fused silu/w2/sigmoid finish (32 blocks)
    hipLaunchKernelGGL(gamma_gemm_kernel, dim3(32), dim3(256), 0, stream,
                       h_bf, gw1T, gamma_w2, gammab, D_DIM);
    hipLaunchKernelGGL(split_rope_tr_kernel, dim3(S_LEN / 64, H_NUM), dim3(256), 0, stream,
                       qkv_bf, q_norm_w, k_norm_w, qh, kh, khT_s, vhT_s);
    hipLaunchKernelGGL(fused_omega_attn_kernel, dim3(512), dim3(512), 0, stream,
                       qh, kh, khT_s, vhT_s, gammab, m_persist, mem_gate, ao_bf);
    hipLaunchKernelGGL(gemm64_kernel, dim3(16, 32), dim3(256), 0, stream,
                       ao_bf, woT, x, out, S_LEN, D_DIM, D_DIM);
    hipLaunchKernelGGL(rmsnorm_kernel, dim3(S_LEN), dim3(256), 0, stream,
                       out, norm2_w, h_bf);
    // ffn13 GEMM (BM=128) with fused SwiGLU epilogue -> mid
    hipLaunchKernelGGL((gemm_bb_kernel<128, 2>), dim3(44, 16), dim3(256), 0, stream,
                       h_bf, w13T, mid_bf, S_LEN, 2 * FFNP, D_DIM);
    hipLaunchKernelGGL(gemm64_kernel, dim3(16, 32), dim3(256), 0, stream,
                       mid_bf, w2T, out, out, S_LEN, D_DIM, FFNP);
}

// Round 24
// 207.659 us; speedup vs baseline: 1.1093x; 1.0465x over previous
//
#include <hip/hip_runtime.h>
#include <hip/hip_bf16.h>

#define S_LEN 2048
#define D_DIM 1024
#define H_NUM 16
#define HD_DIM 64
#define GH_DIM 64
#define FFN_H 2730
#define FFNP  2816          // FFN_H padded to multiple of 128 (zero-filled)
#define CTX_W 512
#define L2LAM -0.00144341687f   // log2(0.999)
#define QBLK 64
#define KBLK 64
#define ALDK 76             // LDS row stride (152B): write-conflict-free, reads <=2-way
#define QSCALE 0.1803368801111731f  // 0.125 * log2(e): scores come out ready for exp2

typedef unsigned short u16;
typedef __attribute__((ext_vector_type(8))) short bf16x8_t;
typedef __attribute__((ext_vector_type(4))) float f32x4_t;

__device__ inline float wave_sum(float v) {
    for (int off = 32; off; off >>= 1) v += __shfl_xor(v, off);
    return v;
}
// f32 -> bf16 (RNE) via the HW pack instruction: 1 VALU op.
__device__ inline u16 f2bf(float f) {
    unsigned r;
    asm("v_cvt_pk_bf16_f32 %0, %1, %2" : "=v"(r) : "v"(f), "v"(f));
    return (u16)r;
}
// pack two f32 -> u32 of 2 bf16 (lo, hi): 1 VALU op.
__device__ inline unsigned f2bf2(float lo, float hi) {
    unsigned r;
    asm("v_cvt_pk_bf16_f32 %0, %1, %2" : "=v"(r) : "v"(lo), "v"(hi));
    return r;
}
__device__ inline float bf2f(u16 u) {
    return __uint_as_float(((unsigned int)u) << 16);
}
__device__ inline void gload16(const void* g, void* l) {
    __builtin_amdgcn_global_load_lds(
        (const __attribute__((address_space(1))) void*)g,
        (__attribute__((address_space(3))) void*)l, 16, 0, 0);
}

// ------- RMSNorm (fp32 in -> bf16 out) --------------------------------------
__global__ __launch_bounds__(256) void rmsnorm_kernel(
    const float* __restrict__ in, const float* __restrict__ w,
    u16* __restrict__ out)
{
    __shared__ float wsum[4];
    int row = blockIdx.x;
    int tid = threadIdx.x, lane = tid & 63, wv = tid >> 6;
    const float4* ir = reinterpret_cast<const float4*>(in + (size_t)row * D_DIM);
    float4 v = ir[tid];
    float ss = v.x*v.x + v.y*v.y + v.z*v.z + v.w*v.w;
    ss = wave_sum(ss);
    if (lane == 0) wsum[wv] = ss;
    __syncthreads();
    float tot = wsum[0] + wsum[1] + wsum[2] + wsum[3];
    float scale = rsqrtf(tot / (float)D_DIM + 1e-6f);
    const float4* wr = reinterpret_cast<const float4*>(w);
    float4 wv4 = wr[tid];
    uint2 o;
    o.x = f2bf2(v.x * scale * wv4.x, v.y * scale * wv4.y);
    o.y = f2bf2(v.z * scale * wv4.z, v.w * scale * wv4.w);
    *reinterpret_cast<uint2*>(out + (size_t)row * D_DIM + tid * 4) = o;
}

// --- prep: wqT + gw1T transposes + rmsnorm1 (late transposes moved into the
// fused attention launch where they back-fill idle CUs).
// Segments: qkv 768 | gw1 16 = 784 blocks; [784, 784+2048) rmsnorm rows.
__global__ __launch_bounds__(256) void prep_kernel(
    const float* __restrict__ w_qkv, const float* __restrict__ gw1f,
    u16* __restrict__ wqT, u16* __restrict__ gw1T,
    const float* __restrict__ x, const float* __restrict__ norm1_w,
    u16* __restrict__ h_bf)
{
    __shared__ float tile[64][65];
    __shared__ float wsum[4];
    int b = blockIdx.x;
    int tid = threadIdx.x;
    if (b < 784) {
        const float* src; u16* dst;
        int srcK, srcN, Kp, nbx;
        if (b < 768) {           src = w_qkv; dst = wqT;  srcK = 1024; srcN = 3072; Kp = 1024; nbx = 48; }
        else         { b -= 768; src = gw1f;  dst = gw1T; srcK = 1024; srcN = 64;   Kp = 1024; nbx = 1; }
        int n0 = (b % nbx) * 64, k0 = (b / nbx) * 64;
        int tx = tid & 15, ty = tid >> 4;
        bool interior = (k0 + 63 < srcK) && (n0 + 63 < srcN);
        #pragma unroll
        for (int p = 0; p < 4; ++p) {
            int kk = p * 16 + ty;
            int r = k0 + kk;
            int cb = n0 + tx * 4;
            float4 v;
            if (interior) {
                v = *(const float4*)(src + (size_t)r * srcN + cb);
            } else {
                v.x = (r < srcK && cb     < srcN) ? src[(size_t)r * srcN + cb]     : 0.f;
                v.y = (r < srcK && cb + 1 < srcN) ? src[(size_t)r * srcN + cb + 1] : 0.f;
                v.z = (r < srcK && cb + 2 < srcN) ? src[(size_t)r * srcN + cb + 2] : 0.f;
                v.w = (r < srcK && cb + 3 < srcN) ? src[(size_t)r * srcN + cb + 3] : 0.f;
            }
            tile[kk][tx*4+0] = v.x; tile[kk][tx*4+1] = v.y;
            tile[kk][tx*4+2] = v.z; tile[kk][tx*4+3] = v.w;
        }
        __syncthreads();
        int wx = tid & 7, wy = tid >> 3;
        #pragma unroll
        for (int p = 0; p < 2; ++p) {
            int nn = p * 32 + wy;
            int ks = wx * 8;
            uint4 o;
            o.x = f2bf2(tile[ks+0][nn], tile[ks+1][nn]);
            o.y = f2bf2(tile[ks+2][nn], tile[ks+3][nn]);
            o.z = f2bf2(tile[ks+4][nn], tile[ks+5][nn]);
            o.w = f2bf2(tile[ks+6][nn], tile[ks+7][nn]);
            *(uint4*)(dst + (size_t)(n0 + nn) * Kp + k0 + ks) = o;
        }
    } else {
        int row = b - 784;
        int lane = tid & 63, wv = tid >> 6;
        const float4* ir = reinterpret_cast<const float4*>(x + (size_t)row * D_DIM);
        float4 v = ir[tid];
        float ss = v.x*v.x + v.y*v.y + v.z*v.z + v.w*v.w;
        ss = wave_sum(ss);
        if (lane == 0) wsum[wv] = ss;
        __syncthreads();
        float tot = wsum[0] + wsum[1] + wsum[2] + wsum[3];
        float scale = rsqrtf(tot / (float)D_DIM + 1e-6f);
        const float4* wr = reinterpret_cast<const float4*>(norm1_w);
        float4 wv4 = wr[tid];
        uint2 o;
        o.x = f2bf2(v.x * scale * wv4.x, v.y * scale * wv4.y);
        o.y = f2bf2(v.z * scale * wv4.z, v.w * scale * wv4.w);
        *reinterpret_cast<uint2*>(h_bf + (size_t)row * D_DIM + tid * 4) = o;
    }
}

// --- gamma gate as MFMA GEMM + fused finish ---------------------------------
__global__ __launch_bounds__(256) void gamma_gemm_kernel(
    const u16* __restrict__ A, const u16* __restrict__ B,
    const float* __restrict__ w2, float* __restrict__ gamma, int K)
{
    __shared__ u16 As[64 * 64];
    __shared__ u16 Bs[64 * 64];
    __shared__ float red[2][64];
    int tid = threadIdx.x, lane = tid & 63, wid = tid >> 6;
    int wr = wid >> 1, wc = wid & 1;
    int row0 = blockIdx.x * 64;
    int l8 = lane >> 3, l7 = lane & 7;
    f32x4_t acc[2][2];
    #pragma unroll
    for (int i = 0; i < 2; ++i)
        #pragma unroll
        for (int j = 0; j < 2; ++j) acc[i][j] = (f32x4_t)0.f;
    int fr = lane & 15, fo = (lane >> 4) * 8;
    for (int k0 = 0; k0 < K; k0 += 64) {
        #pragma unroll
        for (int i = 0; i < 2; ++i) {
            int ch = wid * 2 + i;
            const u16* ga = A + (size_t)(row0 + ch * 8 + l8) * K + k0 + l7 * 8;
            gload16(ga, &As[ch * 512]);
            const u16* gb = B + (size_t)(ch * 8 + l8) * K + k0 + l7 * 8;
            gload16(gb, &Bs[ch * 512]);
        }
        __syncthreads();
        __builtin_amdgcn_s_setprio(1);
        #pragma unroll
        for (int khf = 0; khf < 2; ++khf) {
            bf16x8_t bfrag[2];
            #pragma unroll
            for (int ni = 0; ni < 2; ++ni)
                bfrag[ni] = *(const bf16x8_t*)&Bs[(wc * 32 + ni * 16 + fr) * 64 + khf * 32 + fo];
            #pragma unroll
            for (int mi = 0; mi < 2; ++mi) {
                bf16x8_t af = *(const bf16x8_t*)&As[(wr * 32 + mi * 16 + fr) * 64 + khf * 32 + fo];
                #pragma unroll
                for (int ni = 0; ni < 2; ++ni)
                    acc[mi][ni] = __builtin_amdgcn_mfma_f32_16x16x32_bf16(
                        af, bfrag[ni], acc[mi][ni], 0, 0, 0);
            }
        }
        __builtin_amdgcn_s_setprio(0);
        __syncthreads();
    }
    int dr = (lane >> 4) * 4, dc = lane & 15;
    float w2v0 = w2[wc * 32 + dc];
    float w2v1 = w2[wc * 32 + 16 + dc];
    #pragma unroll
    for (int mi = 0; mi < 2; ++mi) {
        #pragma unroll
        for (int j = 0; j < 4; ++j) {
            float v0 = acc[mi][0][j];
            float v1 = acc[mi][1][j];
            float t = v0 / (1.f + __expf(-v0)) * w2v0
                    + v1 / (1.f + __expf(-v1)) * w2v1;
            t += __shfl_xor(t, 1);
            t += __shfl_xor(t, 2);
            t += __shfl_xor(t, 4);
            t += __shfl_xor(t, 8);
            if (dc == 0) red[wc][wr * 32 + mi * 16 + dr + j] = t;
        }
    }
    __syncthreads();
    if (tid < 64) {
        float g = red[0][tid] + red[1][tid];
        gamma[row0 + tid] = 1.f / (1.f + __expf(-g));
    }
}

// ---- fused split qkv + qk rmsnorm + RoPE + KV transpose (one launch) -------
__global__ __launch_bounds__(256) void split_rope_tr_kernel(
    const u16* __restrict__ qkv, const float* __restrict__ qw,
    const float* __restrict__ kw, float* __restrict__ qhp,
    u16* __restrict__ khp, u16* __restrict__ khT, u16* __restrict__ vhT)
{
    __shared__ u16 tk[64][ALDK];
    __shared__ u16 tv[64][ALDK];
    int tid = threadIdx.x;
    int w = tid >> 6, d = tid & 63;
    int h = blockIdx.y;
    int s0 = blockIdx.x * 64;
    float qwv = qw[d], kwv = kw[d];
    int j = d & 31;
    float inv = expf(-(float)j * (9.2103403719761836f / 32.0f));
    float sgn = (d < 32) ? -1.f : 1.f;
    for (int i = 0; i < 16; ++i) {
        int sl = w * 16 + i;
        int s = s0 + sl;
        size_t base = (size_t)s * (3 * D_DIM) + h * HD_DIM + d;
        float qv = bf2f(qkv[base]);
        float kv = bf2f(qkv[base + D_DIM]);
        u16  vv = qkv[base + 2 * D_DIM];
        float sq = wave_sum(qv * qv);
        float qn = qv * rsqrtf(sq / (float)HD_DIM + 1e-6f) * qwv;
        float sk = wave_sum(kv * kv);
        float kn = kv * rsqrtf(sk / (float)HD_DIM + 1e-6f) * kwv;
        float ang = (float)s * inv;
        float cs = cosf(ang), sn = sinf(ang);
        float qp = __shfl_xor(qn, 32);
        float kp = __shfl_xor(kn, 32);
        float qo = qn * cs + sgn * qp * sn;
        float ko = kn * cs + sgn * kp * sn;
        size_t ob = ((size_t)h * S_LEN + s) * HD_DIM + d;
        u16 kb = f2bf(ko);
        qhp[ob] = qo;
        khp[ob] = kb;
        tk[sl][d] = kb;
        tv[sl][d] = vv;
    }
    __syncthreads();
    int r = tid >> 2, cc = (tid & 3) * 16;
    union { u16 u[16]; bf16x8_t v[2]; } ok, ov;
    #pragma unroll
    for (int e = 0; e < 16; ++e) {
        int ksrc = (e & 3) * 16 + (tid & 3) * 4 + (e >> 2);   // pi^-1 permute
        ok.u[e] = tk[ksrc][r]; ov.u[e] = tv[ksrc][r];
    }
    u16* kd = khT + ((size_t)h * HD_DIM + r) * S_LEN + s0 + cc;
    u16* vd = vhT + ((size_t)h * HD_DIM + r) * S_LEN + s0 + cc;
    *(bf16x8_t*)kd       = ok.v[0];
    *(bf16x8_t*)(kd + 8) = ok.v[1];
    *(bf16x8_t*)vd       = ov.v[0];
    *(bf16x8_t*)(vd + 8) = ov.v[1];
}

// ---------------- bf16 MFMA GEMM, 128-col tiles ------------------------------
// MODE 1: bf16 out.  MODE 2: paired silu-mul, bf16 out width N/2.
template<int BM, int MODE>
__global__ __launch_bounds__(256) void gemm_bb_kernel(
    const u16* __restrict__ A, const u16* __restrict__ B,
    u16* __restrict__ Cb, int M, int N, int K)
{
    constexpr int MREP = BM / 32;
    constexpr int ACH  = BM / 32;
    __shared__ u16 As[BM * 64];
    __shared__ u16 Bs[128 * 64];
    int tid = threadIdx.x, lane = tid & 63, wid = tid >> 6;
    int wr = wid >> 1, wc = wid & 1;
    int row0 = blockIdx.y * BM, col0 = blockIdx.x * 128;
    int l8 = lane >> 3, l7 = lane & 7;
    f32x4_t acc[MREP][4];
    #pragma unroll
    for (int i = 0; i < MREP; ++i)
        #pragma unroll
        for (int j = 0; j < 4; ++j) acc[i][j] = (f32x4_t)0.f;

    int fr = lane & 15, fo = (lane >> 4) * 8;
    for (int k0 = 0; k0 < K; k0 += 64) {
        #pragma unroll
        for (int i = 0; i < ACH; ++i) {
            int ch = wid * ACH + i;
            const u16* ga = A + (size_t)(row0 + ch * 8 + l8) * K + k0 + l7 * 8;
            gload16(ga, &As[ch * 512]);
        }
        #pragma unroll
        for (int i = 0; i < 4; ++i) {
            int ch = wid * 4 + i;
            const u16* gb = B + (size_t)(col0 + ch * 8 + l8) * K + k0 + l7 * 8;
            gload16(gb, &Bs[ch * 512]);
        }
        __syncthreads();
        __builtin_amdgcn_s_setprio(1);
        #pragma unroll
        for (int khf = 0; khf < 2; ++khf) {
            bf16x8_t bfrag[4];
            #pragma unroll
            for (int ni = 0; ni < 4; ++ni)
                bfrag[ni] = *(const bf16x8_t*)&Bs[(wc * 64 + ni * 16 + fr) * 64 + khf * 32 + fo];
            #pragma unroll
            for (int mi = 0; mi < MREP; ++mi) {
                bf16x8_t af = *(const bf16x8_t*)&As[(wr * (BM / 2) + mi * 16 + fr) * 64 + khf * 32 + fo];
                #pragma unroll
                for (int ni = 0; ni < 4; ++ni)
                    acc[mi][ni] = __builtin_amdgcn_mfma_f32_16x16x32_bf16(
                        af, bfrag[ni], acc[mi][ni], 0, 0, 0);
            }
        }
        __builtin_amdgcn_s_setprio(0);
        __syncthreads();
    }
    int dr = (lane >> 4) * 4, dc = lane & 15;
    #pragma unroll
    for (int mi = 0; mi < MREP; ++mi) {
        int gr = row0 + wr * (BM / 2) + mi * 16 + dr;
        #pragma unroll
        for (int ni = 0; ni < 4; ++ni) {
            int gc = col0 + wc * 64 + ni * 16 + dc;
            #pragma unroll
            for (int j = 0; j < 4; ++j) {
                float v = acc[mi][ni][j];
                if (MODE == 1) {
                    Cb[(size_t)(gr + j) * N + gc] = f2bf(v);
                } else {
                    float partner = __shfl_xor(v, 1);
                    float a1 = (dc & 1) ? partner : v;
                    float a3 = (dc & 1) ? v : partner;
                    float rr = a1 / (1.f + __expf(-a1)) * a3;
                    if (!(dc & 1))
                        Cb[(size_t)(gr + j) * (N >> 1) + (gc >> 1)] = f2bf(rr);
                }
            }
        }
    }
}

// ---------------- bf16 MFMA GEMM, 64x64 tiles, fp32 out + residual ----------
__global__ __launch_bounds__(256) void gemm64_kernel(
    const u16* __restrict__ A, const u16* __restrict__ B,
    const float* __restrict__ res, float* __restrict__ Cf,
    int M, int N, int K)
{
    __shared__ u16 As[64 * 64];
    __shared__ u16 Bs[64 * 64];
    int tid = threadIdx.x, lane = tid & 63, wid = tid >> 6;
    int wr = wid >> 1, wc = wid & 1;
    int row0 = blockIdx.y * 64, col0 = blockIdx.x * 64;
    int l8 = lane >> 3, l7 = lane & 7;
    f32x4_t acc[2][2];
    #pragma unroll
    for (int i = 0; i < 2; ++i)
        #pragma unroll
        for (int j = 0; j < 2; ++j) acc[i][j] = (f32x4_t)0.f;
    int fr = lane & 15, fo = (lane >> 4) * 8;
    for (int k0 = 0; k0 < K; k0 += 64) {
        #pragma unroll
        for (int i = 0; i < 2; ++i) {
            int ch = wid * 2 + i;
            const u16* ga = A + (size_t)(row0 + ch * 8 + l8) * K + k0 + l7 * 8;
            gload16(ga, &As[ch * 512]);
            const u16* gb = B + (size_t)(col0 + ch * 8 + l8) * K + k0 + l7 * 8;
            gload16(gb, &Bs[ch * 512]);
        }
        __syncthreads();
        __builtin_amdgcn_s_setprio(1);
        #pragma unroll
        for (int khf = 0; khf < 2; ++khf) {
            bf16x8_t bfrag[2];
            #pragma unroll
            for (int ni = 0; ni < 2; ++ni)
                bfrag[ni] = *(const bf16x8_t*)&Bs[(wc * 32 + ni * 16 + fr) * 64 + khf * 32 + fo];
            #pragma unroll
            for (int mi = 0; mi < 2; ++mi) {
                bf16x8_t af = *(const bf16x8_t*)&As[(wr * 32 + mi * 16 + fr) * 64 + khf * 32 + fo];
                #pragma unroll
                for (int ni = 0; ni < 2; ++ni)
                    acc[mi][ni] = __builtin_amdgcn_mfma_f32_16x16x32_bf16(
                        af, bfrag[ni], acc[mi][ni], 0, 0, 0);
            }
        }
        __builtin_amdgcn_s_setprio(0);
        __syncthreads();
    }
    int dr = (lane >> 4) * 4, dc = lane & 15;
    #pragma unroll
    for (int mi = 0; mi < 2; ++mi) {
        int gr = row0 + wr * 32 + mi * 16 + dr;
        #pragma unroll
        for (int ni = 0; ni < 2; ++ni) {
            int gc = col0 + wc * 32 + ni * 16 + dc;
            #pragma unroll
            for (int j = 0; j < 4; ++j) {
                size_t off = (size_t)(gr + j) * N + gc;
                Cf[off] = acc[mi][ni][j] + res[off];
            }
        }
    }
}

// ============ FUSED omega-rule + flash attention (8-wave col-split) =========
// Blocks [0,512): attention. Blocks [512, 512+2368): weight transposes for
// wo/w1/w3/w2 that back-fill idle CUs while attention blocks retire (their
// outputs are first consumed by kernels AFTER this launch).
__global__ __launch_bounds__(512) void fused_omega_attn_kernel(
    const float* __restrict__ qhp, const u16* __restrict__ khp,
    const u16* __restrict__ khT, const u16* __restrict__ vhT,
    const float* __restrict__ gammab, const float* __restrict__ mp,
    const float* __restrict__ mg, u16* __restrict__ ao,
    const float* __restrict__ w_o, const float* __restrict__ w1f,
    const float* __restrict__ w3f, const float* __restrict__ w2f,
    u16* __restrict__ woT, u16* __restrict__ w13T, u16* __restrict__ w2T)
{
    __shared__ u16 Ks[2][KBLK][ALDK];
    __shared__ u16 Xt[2][KBLK][ALDK];
    __shared__ u16 Ps[QBLK][ALDK];
    __shared__ float colfL[CTX_W + KBLK];
    __shared__ float redS[2][QBLK];      // cross-half reduction (wsum / l)
    const int tid = threadIdx.x, lane = tid & 63, wid = tid >> 6;
    const int b = blockIdx.x;

    if (b >= 512) {
        // ---- transpose back-fill path (512 threads per 64x64 tile) ----
        int b2 = b - 512;
        const float* src; u16* dst;
        int srcK, srcN, Kp, rowOff, rowMul, nbx;
        if (b2 < 256)       {             src = w_o; dst = woT;  srcK = 1024; srcN = 1024; Kp = 1024; rowOff = 0; rowMul = 1; nbx = 16; }
        else if (b2 < 960)  { b2 -= 256;  src = w1f; dst = w13T; srcK = 1024; srcN = 2730; Kp = 1024; rowOff = 0; rowMul = 2; nbx = 44; }
        else if (b2 < 1664) { b2 -= 960;  src = w3f; dst = w13T; srcK = 1024; srcN = 2730; Kp = 1024; rowOff = 1; rowMul = 2; nbx = 44; }
        else                { b2 -= 1664; src = w2f; dst = w2T;  srcK = 2730; srcN = 1024; Kp = 2816; rowOff = 0; rowMul = 1; nbx = 16; }
        int n0 = (b2 % nbx) * 64, k0 = (b2 / nbx) * 64;
        float* tile = (float*)&Ks[0][0][0];    // 16.6KB alias inside Ks (19.4KB)
        int tx = tid & 15, ty = tid >> 4;      // ty 0..31
        bool interior = (k0 + 63 < srcK) && (n0 + 63 < srcN);
        #pragma unroll
        for (int p = 0; p < 2; ++p) {
            int kk = p * 32 + ty;
            int r = k0 + kk;
            int cb = n0 + tx * 4;
            float4 v;
            if (interior) {
                v = *(const float4*)(src + (size_t)r * srcN + cb);
            } else {
                v.x = (r < srcK && cb     < srcN) ? src[(size_t)r * srcN + cb]     : 0.f;
                v.y = (r < srcK && cb + 1 < srcN) ? src[(size_t)r * srcN + cb + 1] : 0.f;
                v.z = (r < srcK && cb + 2 < srcN) ? src[(size_t)r * srcN + cb + 2] : 0.f;
                v.w = (r < srcK && cb + 3 < srcN) ? src[(size_t)r * srcN + cb + 3] : 0.f;
            }
            tile[kk * 65 + tx*4+0] = v.x; tile[kk * 65 + tx*4+1] = v.y;
            tile[kk * 65 + tx*4+2] = v.z; tile[kk * 65 + tx*4+3] = v.w;
        }
        __syncthreads();
        int wx = tid & 7, wy = tid >> 3;       // wy 0..63
        int nn = wy, ks = wx * 8;
        uint4 o;
        o.x = f2bf2(tile[(ks+0) * 65 + nn], tile[(ks+1) * 65 + nn]);
        o.y = f2bf2(tile[(ks+2) * 65 + nn], tile[(ks+3) * 65 + nn]);
        o.z = f2bf2(tile[(ks+4) * 65 + nn], tile[(ks+5) * 65 + nn]);
        o.w = f2bf2(tile[(ks+6) * 65 + nn], tile[(ks+7) * 65 + nn]);
        *(uint4*)(dst + (size_t)(rowOff + (size_t)(n0 + nn) * rowMul) * Kp + k0 + ks) = o;
        return;
    }

    const int wq = wid & 3;              // row group (16 q-rows)
    const int nh = wid >> 2;             // column half (0/1)
    const int hi = (b >> 8) & 1;
    const int h = ((b & 7) << 1) + hi;
    const int s5 = (b >> 3) & 31;
    const int qt = hi ? (31 - s5) : s5;
    const int q0 = qt * QBLK;
    const int fr = lane & 15, g4 = lane >> 4;
    const int fko = g4 * 8;
    const int c = fr, rg = g4;
    const int si = tid >> 3, sdb = (tid & 7) * 8;   // staging: 512 thr x 16B
    const size_t hS = (size_t)h * S_LEN;
    const size_t hD = (size_t)h * HD_DIM;

    int rowt[4]; float rowf[4];
    #pragma unroll
    for (int j = 0; j < 4; ++j) {
        rowt[j] = q0 + wq * 16 + rg * 4 + j;
        rowf[j] = exp2f((float)(wq * 16 + rg * 4 + j) * L2LAM);
    }
    bf16x8_t qf[2];
    {
        const float* qrow = qhp + (hS + q0 + wq * 16 + fr) * HD_DIM;
        #pragma unroll
        for (int u = 0; u < 2; ++u) {
            float4 a = *(const float4*)(qrow + u * 32 + fko);
            float4 bq = *(const float4*)(qrow + u * 32 + fko + 4);
            bf16x8_t f;
            f[0]=f2bf(a.x); f[1]=f2bf(a.y); f[2]=f2bf(a.z); f[3]=f2bf(a.w);
            f[4]=f2bf(bq.x); f[5]=f2bf(bq.y); f[6]=f2bf(bq.z); f[7]=f2bf(bq.w);
            qf[u] = f;
        }
    }
    // preload q_old for this wave's column quadrants (n = 2*nh + nn)
    float qold[2][4];
    #pragma unroll
    for (int nn = 0; nn < 2; ++nn)
        #pragma unroll
        for (int j = 0; j < 4; ++j)
            qold[nn][j] = qhp[(hS + rowt[j]) * HD_DIM + (nh * 2 + nn) * 16 + c];

    // ---------------- omega phase ----------------
    f32x4_t accc[2];
    accc[0] = (f32x4_t)0.f; accc[1] = (f32x4_t)0.f;
    float wsum[4] = {0.f, 0.f, 0.f, 0.f};
    const int kt0 = (q0 > (CTX_W - 1)) ? (q0 - (CTX_W - 1)) / KBLK : 0;
    const int i0 = kt0 * KBLK;
    const int nwin = (qt + 1) * KBLK - i0;
    for (int idx = tid; idx < nwin; idx += 512) {
        int icol = i0 + idx;
        colfL[idx] = exp2f((float)(q0 - icol) * L2LAM) * gammab[icol];
    }
    {
        const u16* gk = khp + (hS + kt0 * KBLK + si) * HD_DIM + sdb;
        const u16* gx = khT + (hD + si) * S_LEN + kt0 * KBLK + sdb;
        *(bf16x8_t*)&Ks[0][si][sdb] = *(const bf16x8_t*)gk;
        *(bf16x8_t*)&Xt[0][si][sdb] = *(const bf16x8_t*)gx;
    }
    __syncthreads();
    int cur = 0;
    for (int kt = kt0; kt <= qt; ++kt) {
        const int k0 = kt * KBLK;
        const bool hn = (kt < qt);
        bf16x8_t nk0, nx0;
        if (hn) {
            const u16* gk = khp + (hS + k0 + KBLK + si) * HD_DIM + sdb;
            const u16* gx = khT + (hD + si) * S_LEN + k0 + KBLK + sdb;
            nk0 = *(const bf16x8_t*)gk;
            nx0 = *(const bf16x8_t*)gx;
        }
        f32x4_t s[2];
        s[0] = (f32x4_t)0.f; s[1] = (f32x4_t)0.f;
        __builtin_amdgcn_s_setprio(1);
        #pragma unroll
        for (int u = 0; u < 2; ++u)
            #pragma unroll
            for (int nn = 0; nn < 2; ++nn) {
                bf16x8_t kb = *(const bf16x8_t*)&Ks[cur][(nh * 2 + nn) * 16 + fr][u * 32 + fko];
                s[nn] = __builtin_amdgcn_mfma_f32_16x16x32_bf16(qf[u], kb, s[nn], 0, 0, 0);
            }
        __builtin_amdgcn_s_setprio(0);
        const bool boundary = (kt == kt0) || (kt == qt);
        float colf[2];
        #pragma unroll
        for (int nn = 0; nn < 2; ++nn)
            colf[nn] = colfL[k0 - i0 + (nh * 2 + nn) * 16 + c];
        #pragma unroll
        for (int j = 0; j < 4; ++j) {
            float pv[2];
            #pragma unroll
            for (int nn = 0; nn < 2; ++nn) {
                float w;
                if (boundary) {
                    int delta = rowt[j] - (k0 + (nh * 2 + nn) * 16 + c);
                    w = (delta >= 0 && delta < CTX_W) ? rowf[j] * colf[nn] : 0.f;
                } else {
                    w = rowf[j] * colf[nn];
                }
                wsum[j] += w;
                pv[nn] = w * s[nn][j];
            }
            *(unsigned*)&Ps[wq * 16 + rg * 4 + j][c * 4 + nh * 2] = f2bf2(pv[0], pv[1]);
        }
        __syncthreads();   // P rows complete (both halves)
        __builtin_amdgcn_s_setprio(1);
        #pragma unroll
        for (int u = 0; u < 2; ++u) {
            bf16x8_t pa = *(const bf16x8_t*)&Ps[wq * 16 + fr][u * 32 + fko];
            #pragma unroll
            for (int nn = 0; nn < 2; ++nn) {
                bf16x8_t kb = *(const bf16x8_t*)&Xt[cur][(nh * 2 + nn) * 16 + fr][u * 32 + fko];
                accc[nn] = __builtin_amdgcn_mfma_f32_16x16x32_bf16(pa, kb, accc[nn], 0, 0, 0);
            }
        }
        __builtin_amdgcn_s_setprio(0);
        if (hn) {
            int nxt = cur ^ 1;
            *(bf16x8_t*)&Ks[nxt][si][sdb] = nk0;
            *(bf16x8_t*)&Xt[nxt][si][sdb] = nx0;
        }
        __syncthreads();
        cur ^= 1;
    }
    // persist = Q @ M_p^T (this wave's output quadrants)
    f32x4_t pacc[2];
    pacc[0] = (f32x4_t)0.f; pacc[1] = (f32x4_t)0.f;
    const float* mph = mp + hD * HD_DIM;
    #pragma unroll
    for (int u = 0; u < 2; ++u)
        #pragma unroll
        for (int nn = 0; nn < 2; ++nn) {
            const float* br = mph + (size_t)((nh * 2 + nn) * 16 + fr) * HD_DIM + u * 32 + fko;
            float4 a = *(const float4*)br;
            float4 bq = *(const float4*)(br + 4);
            bf16x8_t f;
            f[0]=f2bf(a.x); f[1]=f2bf(a.y); f[2]=f2bf(a.z); f[3]=f2bf(a.w);
            f[4]=f2bf(bq.x); f[5]=f2bf(bq.y); f[6]=f2bf(bq.z); f[7]=f2bf(bq.w);
            pacc[nn] = __builtin_amdgcn_mfma_f32_16x16x32_bf16(qf[u], f, pacc[nn], 0, 0, 0);
        }
    #pragma unroll
    for (int j = 0; j < 4; ++j) {
        wsum[j] += __shfl_xor(wsum[j], 1);
        wsum[j] += __shfl_xor(wsum[j], 2);
        wsum[j] += __shfl_xor(wsum[j], 4);
        wsum[j] += __shfl_xor(wsum[j], 8);
    }
    if (fr == 0) {
        #pragma unroll
        for (int j = 0; j < 4; ++j)
            redS[nh][wq * 16 + rg * 4 + j] = wsum[j];
    }
    __syncthreads();
    float wtot[4];
    #pragma unroll
    for (int j = 0; j < 4; ++j)
        wtot[j] = redS[0][wq * 16 + rg * 4 + j] + redS[1][wq * 16 + rg * 4 + j];
    float gate = 1.f / (1.f + __expf(-mg[0]));
    float keep = 1.f - gate;
    #pragma unroll
    for (int nn = 0; nn < 2; ++nn) {
        #pragma unroll
        for (int j = 0; j < 4; ++j) {
            float qn = keep * qold[nn][j] + gate * (pacc[nn][j] + accc[nn][j]) / (1.f + wtot[j]);
            Ps[wq * 16 + rg * 4 + j][(nh * 2 + nn) * 16 + c] = f2bf(qn * QSCALE);
        }
    }
    __syncthreads();   // q_new rows complete (both halves)
    bf16x8_t qf2[2];
    #pragma unroll
    for (int u = 0; u < 2; ++u)
        qf2[u] = *(const bf16x8_t*)&Ps[wq * 16 + fr][u * 32 + fko];

    // ---------------- attention phase ----------------
    f32x4_t acco[2];
    acco[0] = (f32x4_t)0.f; acco[1] = (f32x4_t)0.f;
    float l_run[4] = {0.f, 0.f, 0.f, 0.f};
    {
        const u16* gk = khp + (hS + si) * HD_DIM + sdb;
        const u16* gv = vhT + (hD + si) * S_LEN + sdb;
        *(bf16x8_t*)&Ks[0][si][sdb] = *(const bf16x8_t*)gk;
        *(bf16x8_t*)&Xt[0][si][sdb] = *(const bf16x8_t*)gv;
    }
    __syncthreads();
    cur = 0;
    for (int kt = 0; kt <= qt; ++kt) {
        const int k0 = kt * KBLK;
        const bool hn = (kt < qt);
        bf16x8_t nk0, nv0;
        if (hn) {
            const u16* gk = khp + (hS + k0 + KBLK + si) * HD_DIM + sdb;
            const u16* gv = vhT + (hD + si) * S_LEN + k0 + KBLK + sdb;
            nk0 = *(const bf16x8_t*)gk;
            nv0 = *(const bf16x8_t*)gv;
        }
        f32x4_t s[2];
        s[0] = (f32x4_t)0.f; s[1] = (f32x4_t)0.f;
        __builtin_amdgcn_s_setprio(1);
        #pragma unroll
        for (int u = 0; u < 2; ++u)
            #pragma unroll
            for (int nn = 0; nn < 2; ++nn) {
                bf16x8_t kb = *(const bf16x8_t*)&Ks[cur][(nh * 2 + nn) * 16 + fr][u * 32 + fko];
                s[nn] = __builtin_amdgcn_mfma_f32_16x16x32_bf16(qf2[u], kb, s[nn], 0, 0, 0);
            }
        __builtin_amdgcn_s_setprio(0);
        if (kt == qt) {   // causal mask only on diagonal tile
            #pragma unroll
            for (int nn = 0; nn < 2; ++nn) {
                int icol = k0 + (nh * 2 + nn) * 16 + c;
                #pragma unroll
                for (int j = 0; j < 4; ++j)
                    if (icol > rowt[j]) s[nn][j] = -1e30f;
            }
        }
        #pragma unroll
        for (int j = 0; j < 4; ++j) {
            float p0 = exp2f(s[0][j]);
            float p1 = exp2f(s[1][j]);
            l_run[j] += p0 + p1;
            *(unsigned*)&Ps[wq * 16 + rg * 4 + j][c * 4 + nh * 2] = f2bf2(p0, p1);
        }
        __syncthreads();   // P rows complete (both halves)
        __builtin_amdgcn_s_setprio(1);
        #pragma unroll
        for (int u = 0; u < 2; ++u) {
            bf16x8_t pa = *(const bf16x8_t*)&Ps[wq * 16 + fr][u * 32 + fko];
            #pragma unroll
            for (int nn = 0; nn < 2; ++nn) {
                bf16x8_t vb = *(const bf16x8_t*)&Xt[cur][(nh * 2 + nn) * 16 + fr][u * 32 + fko];
                acco[nn] = __builtin_amdgcn_mfma_f32_16x16x32_bf16(pa, vb, acco[nn], 0, 0, 0);
            }
        }
        __builtin_amdgcn_s_setprio(0);
        if (hn) {
            int nxt = cur ^ 1;
            *(bf16x8_t*)&Ks[nxt][si][sdb] = nk0;
            *(bf16x8_t*)&Xt[nxt][si][sdb] = nv0;
        }
        __syncthreads();
        cur ^= 1;
    }
    #pragma unroll
    for (int j = 0; j < 4; ++j) {
        l_run[j] += __shfl_xor(l_run[j], 1);
        l_run[j] += __shfl_xor(l_run[j], 2);
        l_run[j] += __shfl_xor(l_run[j], 4);
        l_run[j] += __shfl_xor(l_run[j], 8);
    }
    if (fr == 0) {
        #pragma unroll
        for (int j = 0; j < 4; ++j)
            redS[nh][wq * 16 + rg * 4 + j] = l_run[j];
    }
    __syncthreads();
    #pragma unroll
    for (int j = 0; j < 4; ++j)
        l_run[j] = redS[0][wq * 16 + rg * 4 + j] + redS[1][wq * 16 + rg * 4 + j];
    #pragma unroll
    for (int nn = 0; nn < 2; ++nn) {
        #pragma unroll
        for (int j = 0; j < 4; ++j) {
            float o = acco[nn][j] / l_run[j];
            ao[(size_t)rowt[j] * D_DIM + h * HD_DIM + (nh * 2 + nn) * 16 + c] = f2bf(o);
        }
    }
}

extern "C" void kernel_launch(void* const* d_in, const int* in_sizes, int n_in,
                              void* d_out, int out_size, void* d_ws, size_t ws_size,
                              hipStream_t stream) {
    const float* x         = (const float*)d_in[0];
    const float* norm1_w   = (const float*)d_in[1];
    const float* norm2_w   = (const float*)d_in[2];
    const float* w_qkv     = (const float*)d_in[3];
    const float* q_norm_w  = (const float*)d_in[4];
    const float* k_norm_w  = (const float*)d_in[5];
    const float* gamma_w1  = (const float*)d_in[6];
    const float* gamma_w2  = (const float*)d_in[7];
    const float* m_persist = (const float*)d_in[8];
    const float* mem_gate  = (const float*)d_in[9];
    const float* w_o       = (const float*)d_in[10];
    const float* ffn_w1    = (const float*)d_in[11];
    const float* ffn_w3    = (const float*)d_in[12];
    const float* ffn_w2    = (const float*)d_in[13];
    float* out = (float*)d_out;
    char* ws = (char*)d_ws;

    const size_t MB = 1024 * 1024;
    u16*   h_bf   = (u16*)(ws);                 // [0,4MB) h / h2
    u16*   wqT    = (u16*)(ws + 4 * MB);        // [4,10)
    u16*   woT    = (u16*)(ws + 10 * MB);       // [10,12)
    u16*   w13T   = (u16*)(ws + 12 * MB);       // [12,23) interleaved w1/w3
    u16*   w2T    = (u16*)(ws + 23 * MB);       // [23,28.5)
    u16*   qkv_bf = (u16*)(ws + 29884416);      // [28.5,40.5) dead after split
    u16*   ao_bf  = (u16*)(ws + 38273024);      // [36.5,40.5) (after qkv dead)
    float* qh     = (float*)(ws + 42467328);    // [40.5,48.5) fp32 q
    u16*   kh     = (u16*)(ws + 50855936);      // [48.5,52.5)
    u16*   khT_s  = (u16*)(ws + 50855936 + 4 * MB);   // [52.5,56.5)
    float* gammab = (float*)(ws + 59244544);    // [56.5,+8KB)
    u16*   vhT_s  = (u16*)(ws + 59244544 + 65536);    // [56.56,+4MB)
    u16*   gw1T   = (u16*)(ws + 63504384);      // [60.56,+128KB) gamma W1^T bf16
    u16*   mid_bf = (u16*)(ws + 29884416);      // [28.5,40) post-attention

    // --- prep: wqT + gw1T transposes + rmsnorm1, ONE launch ------------------
    hipLaunchKernelGGL(prep_kernel, dim3(784 + S_LEN), dim3(256), 0, stream,
                       w_qkv, gamma_w1, wqT, gw1T, x, norm1_w, h_bf);

    // --- forward pass ---------------------------------------------------------
    hipLaunchKernelGGL((gemm_bb_kernel<64, 1>), dim3(24, 32), dim3(256), 0, stream,
                       h_bf, wqT, qkv_bf, S_LEN, 3 * D_DIM, D_DIM);
    // gamma gate via MFMA GEMM + fused silu/w2/sigmoid finish (32 blocks)
    hipLaunchKernelGGL(gamma_gemm_kernel, dim3(32), dim3(256), 0, stream,
                       h_bf, gw1T, gamma_w2, gammab, D_DIM);
    hipLaunchKernelGGL(split_rope_tr_kernel, dim3(S_LEN / 64, H_NUM), dim3(256), 0, stream,
                       qkv_bf, q_norm_w, k_norm_w, qh, kh, khT_s, vhT_s);
    // fused attention (512 blocks) + late weight transposes back-fill (2368)
    hipLaunchKernelGGL(fused_omega_attn_kernel, dim3(512 + 2368), dim3(512), 0, stream,
                       qh, kh, khT_s, vhT_s, gammab, m_persist, mem_gate, ao_bf,
                       w_o, ffn_w1, ffn_w3, ffn_w2, woT, w13T, w2T);
    hipLaunchKernelGGL(gemm64_kernel, dim3(16, 32), dim3(256), 0, stream,
                       ao_bf, woT, x, out, S_LEN, D_DIM, D_DIM);
    hipLaunchKernelGGL(rmsnorm_kernel, dim3(S_LEN), dim3(256), 0, stream,
                       out, norm2_w, h_bf);
    // ffn13 GEMM (BM=128) with fused SwiGLU epilogue -> mid
    hipLaunchKernelGGL((gemm_bb_kernel<128, 2>), dim3(44, 16), dim3(256), 0, stream,
                       h_bf, w13T, mid_bf, S_LEN, 2 * FFNP, D_DIM);
    hipLaunchKernelGGL(gemm64_kernel, dim3(16, 32), dim3(256), 0, stream,
                       mid_bf, w2T, out, out, S_LEN, D_DIM, FFNP);
}

// Round 25
// 195.753 us; speedup vs baseline: 1.1767x; 1.0608x over previous
//
#include <hip/hip_runtime.h>
#include <hip/hip_bf16.h>

#define S_LEN 2048
#define D_DIM 1024
#define H_NUM 16
#define HD_DIM 64
#define GH_DIM 64
#define FFN_H 2730
#define FFNP  2816          // FFN_H padded to multiple of 128 (zero-filled)
#define CTX_W 512
#define L2LAM -0.00144341687f   // log2(0.999)
#define QBLK 64
#define KBLK 64
#define ALDK 76             // LDS row stride (152B): write-conflict-free, reads <=2-way
#define QSCALE 0.1803368801111731f  // 0.125 * log2(e): scores come out ready for exp2

typedef unsigned short u16;
typedef __attribute__((ext_vector_type(8))) short bf16x8_t;
typedef __attribute__((ext_vector_type(4))) float f32x4_t;

__device__ inline float wave_sum(float v) {
    for (int off = 32; off; off >>= 1) v += __shfl_xor(v, off);
    return v;
}
// f32 -> bf16 (RNE) via the HW pack instruction: 1 VALU op.
__device__ inline u16 f2bf(float f) {
    unsigned r;
    asm("v_cvt_pk_bf16_f32 %0, %1, %2" : "=v"(r) : "v"(f), "v"(f));
    return (u16)r;
}
// pack two f32 -> u32 of 2 bf16 (lo, hi): 1 VALU op.
__device__ inline unsigned f2bf2(float lo, float hi) {
    unsigned r;
    asm("v_cvt_pk_bf16_f32 %0, %1, %2" : "=v"(r) : "v"(lo), "v"(hi));
    return r;
}
__device__ inline float bf2f(u16 u) {
    return __uint_as_float(((unsigned int)u) << 16);
}
__device__ inline void gload16(const void* g, void* l) {
    __builtin_amdgcn_global_load_lds(
        (const __attribute__((address_space(1))) void*)g,
        (__attribute__((address_space(3))) void*)l, 16, 0, 0);
}

// ------- RMSNorm (fp32 in -> bf16 out) --------------------------------------
__global__ __launch_bounds__(256) void rmsnorm_kernel(
    const float* __restrict__ in, const float* __restrict__ w,
    u16* __restrict__ out)
{
    __shared__ float wsum[4];
    int row = blockIdx.x;
    int tid = threadIdx.x, lane = tid & 63, wv = tid >> 6;
    const float4* ir = reinterpret_cast<const float4*>(in + (size_t)row * D_DIM);
    float4 v = ir[tid];
    float ss = v.x*v.x + v.y*v.y + v.z*v.z + v.w*v.w;
    ss = wave_sum(ss);
    if (lane == 0) wsum[wv] = ss;
    __syncthreads();
    float tot = wsum[0] + wsum[1] + wsum[2] + wsum[3];
    float scale = rsqrtf(tot / (float)D_DIM + 1e-6f);
    const float4* wr = reinterpret_cast<const float4*>(w);
    float4 wv4 = wr[tid];
    uint2 o;
    o.x = f2bf2(v.x * scale * wv4.x, v.y * scale * wv4.y);
    o.y = f2bf2(v.z * scale * wv4.z, v.w * scale * wv4.w);
    *reinterpret_cast<uint2*>(out + (size_t)row * D_DIM + tid * 4) = o;
}

// --- prep: wqT + gw1T transposes + rmsnorm1 ---------------------------------
__global__ __launch_bounds__(256) void prep_kernel(
    const float* __restrict__ w_qkv, const float* __restrict__ gw1f,
    u16* __restrict__ wqT, u16* __restrict__ gw1T,
    const float* __restrict__ x, const float* __restrict__ norm1_w,
    u16* __restrict__ h_bf)
{
    __shared__ float tile[64][65];
    __shared__ float wsum[4];
    int b = blockIdx.x;
    int tid = threadIdx.x;
    if (b < 784) {
        const float* src; u16* dst;
        int srcK, srcN, Kp, nbx;
        if (b < 768) {           src = w_qkv; dst = wqT;  srcK = 1024; srcN = 3072; Kp = 1024; nbx = 48; }
        else         { b -= 768; src = gw1f;  dst = gw1T; srcK = 1024; srcN = 64;   Kp = 1024; nbx = 1; }
        int n0 = (b % nbx) * 64, k0 = (b / nbx) * 64;
        int tx = tid & 15, ty = tid >> 4;
        bool interior = (k0 + 63 < srcK) && (n0 + 63 < srcN);
        #pragma unroll
        for (int p = 0; p < 4; ++p) {
            int kk = p * 16 + ty;
            int r = k0 + kk;
            int cb = n0 + tx * 4;
            float4 v;
            if (interior) {
                v = *(const float4*)(src + (size_t)r * srcN + cb);
            } else {
                v.x = (r < srcK && cb     < srcN) ? src[(size_t)r * srcN + cb]     : 0.f;
                v.y = (r < srcK && cb + 1 < srcN) ? src[(size_t)r * srcN + cb + 1] : 0.f;
                v.z = (r < srcK && cb + 2 < srcN) ? src[(size_t)r * srcN + cb + 2] : 0.f;
                v.w = (r < srcK && cb + 3 < srcN) ? src[(size_t)r * srcN + cb + 3] : 0.f;
            }
            tile[kk][tx*4+0] = v.x; tile[kk][tx*4+1] = v.y;
            tile[kk][tx*4+2] = v.z; tile[kk][tx*4+3] = v.w;
        }
        __syncthreads();
        int wx = tid & 7, wy = tid >> 3;
        #pragma unroll
        for (int p = 0; p < 2; ++p) {
            int nn = p * 32 + wy;
            int ks = wx * 8;
            uint4 o;
            o.x = f2bf2(tile[ks+0][nn], tile[ks+1][nn]);
            o.y = f2bf2(tile[ks+2][nn], tile[ks+3][nn]);
            o.z = f2bf2(tile[ks+4][nn], tile[ks+5][nn]);
            o.w = f2bf2(tile[ks+6][nn], tile[ks+7][nn]);
            *(uint4*)(dst + (size_t)(n0 + nn) * Kp + k0 + ks) = o;
        }
    } else {
        int row = b - 784;
        int lane = tid & 63, wv = tid >> 6;
        const float4* ir = reinterpret_cast<const float4*>(x + (size_t)row * D_DIM);
        float4 v = ir[tid];
        float ss = v.x*v.x + v.y*v.y + v.z*v.z + v.w*v.w;
        ss = wave_sum(ss);
        if (lane == 0) wsum[wv] = ss;
        __syncthreads();
        float tot = wsum[0] + wsum[1] + wsum[2] + wsum[3];
        float scale = rsqrtf(tot / (float)D_DIM + 1e-6f);
        const float4* wr = reinterpret_cast<const float4*>(norm1_w);
        float4 wv4 = wr[tid];
        uint2 o;
        o.x = f2bf2(v.x * scale * wv4.x, v.y * scale * wv4.y);
        o.y = f2bf2(v.z * scale * wv4.z, v.w * scale * wv4.w);
        *reinterpret_cast<uint2*>(h_bf + (size_t)row * D_DIM + tid * 4) = o;
    }
}

// ---- split qkv + qk rmsnorm + RoPE + KV transpose, PLUS gamma gate ---------
// Blocks [0,512): split (s0=(b&31)*64, h=b>>5). Blocks [512,544): gamma GEMM
// (row0=(b-512)*64). Both depend only on earlier launches; LDS is a manual
// union (split: 19.5KB tk/tv; gamma: 16.9KB As/Bs/red).
__global__ __launch_bounds__(256) void split_gamma_kernel(
    const u16* __restrict__ qkv, const float* __restrict__ qw,
    const float* __restrict__ kw, float* __restrict__ qhp,
    u16* __restrict__ khp, u16* __restrict__ khT, u16* __restrict__ vhT,
    const u16* __restrict__ h_bf, const u16* __restrict__ gw1T,
    const float* __restrict__ w2, float* __restrict__ gamma)
{
    __shared__ char smem[2 * 64 * ALDK * 2];   // 19456B, carved below
    int tid = threadIdx.x;
    int b = blockIdx.x;
    if (b < 512) {
        u16 (*tk)[ALDK] = (u16(*)[ALDK])smem;
        u16 (*tv)[ALDK] = (u16(*)[ALDK])(smem + 64 * ALDK * 2);
        int w = tid >> 6, d = tid & 63;
        int h = b >> 5;
        int s0 = (b & 31) * 64;
        float qwv = qw[d], kwv = kw[d];
        int j = d & 31;
        float inv = expf(-(float)j * (9.2103403719761836f / 32.0f));
        float sgn = (d < 32) ? -1.f : 1.f;
        for (int i = 0; i < 16; ++i) {
            int sl = w * 16 + i;
            int s = s0 + sl;
            size_t base = (size_t)s * (3 * D_DIM) + h * HD_DIM + d;
            float qv = bf2f(qkv[base]);
            float kv = bf2f(qkv[base + D_DIM]);
            u16  vv = qkv[base + 2 * D_DIM];
            float sq = wave_sum(qv * qv);
            float qn = qv * rsqrtf(sq / (float)HD_DIM + 1e-6f) * qwv;
            float sk = wave_sum(kv * kv);
            float kn = kv * rsqrtf(sk / (float)HD_DIM + 1e-6f) * kwv;
            float ang = (float)s * inv;
            float cs = cosf(ang), sn = sinf(ang);
            float qp = __shfl_xor(qn, 32);
            float kp = __shfl_xor(kn, 32);
            float qo = qn * cs + sgn * qp * sn;
            float ko = kn * cs + sgn * kp * sn;
            size_t ob = ((size_t)h * S_LEN + s) * HD_DIM + d;
            u16 kb = f2bf(ko);
            qhp[ob] = qo;
            khp[ob] = kb;
            tk[sl][d] = kb;
            tv[sl][d] = vv;
        }
        __syncthreads();
        int r = tid >> 2, cc = (tid & 3) * 16;
        union { u16 u[16]; bf16x8_t v[2]; } ok, ov;
        #pragma unroll
        for (int e = 0; e < 16; ++e) {
            int ksrc = (e & 3) * 16 + (tid & 3) * 4 + (e >> 2);   // pi^-1 permute
            ok.u[e] = tk[ksrc][r]; ov.u[e] = tv[ksrc][r];
        }
        u16* kd = khT + ((size_t)h * HD_DIM + r) * S_LEN + s0 + cc;
        u16* vd = vhT + ((size_t)h * HD_DIM + r) * S_LEN + s0 + cc;
        *(bf16x8_t*)kd       = ok.v[0];
        *(bf16x8_t*)(kd + 8) = ok.v[1];
        *(bf16x8_t*)vd       = ov.v[0];
        *(bf16x8_t*)(vd + 8) = ov.v[1];
    } else {
        // ---- gamma gate GEMM path ----
        u16* As = (u16*)smem;                       // 8KB
        u16* Bs = (u16*)(smem + 8192);              // 8KB
        float (*red)[64] = (float(*)[64])(smem + 16384);  // 512B
        int lane = tid & 63, wid = tid >> 6;
        int wr = wid >> 1, wc = wid & 1;
        int row0 = (b - 512) * 64;
        int l8 = lane >> 3, l7 = lane & 7;
        f32x4_t acc[2][2];
        #pragma unroll
        for (int i = 0; i < 2; ++i)
            #pragma unroll
            for (int j2 = 0; j2 < 2; ++j2) acc[i][j2] = (f32x4_t)0.f;
        int fr = lane & 15, fo = (lane >> 4) * 8;
        for (int k0 = 0; k0 < D_DIM; k0 += 64) {
            #pragma unroll
            for (int i = 0; i < 2; ++i) {
                int ch = wid * 2 + i;
                const u16* ga = h_bf + (size_t)(row0 + ch * 8 + l8) * D_DIM + k0 + l7 * 8;
                gload16(ga, &As[ch * 512]);
                const u16* gb = gw1T + (size_t)(ch * 8 + l8) * D_DIM + k0 + l7 * 8;
                gload16(gb, &Bs[ch * 512]);
            }
            __syncthreads();
            __builtin_amdgcn_s_setprio(1);
            #pragma unroll
            for (int khf = 0; khf < 2; ++khf) {
                bf16x8_t bfrag[2];
                #pragma unroll
                for (int ni = 0; ni < 2; ++ni)
                    bfrag[ni] = *(const bf16x8_t*)&Bs[(wc * 32 + ni * 16 + fr) * 64 + khf * 32 + fo];
                #pragma unroll
                for (int mi = 0; mi < 2; ++mi) {
                    bf16x8_t af = *(const bf16x8_t*)&As[(wr * 32 + mi * 16 + fr) * 64 + khf * 32 + fo];
                    #pragma unroll
                    for (int ni = 0; ni < 2; ++ni)
                        acc[mi][ni] = __builtin_amdgcn_mfma_f32_16x16x32_bf16(
                            af, bfrag[ni], acc[mi][ni], 0, 0, 0);
                }
            }
            __builtin_amdgcn_s_setprio(0);
            __syncthreads();
        }
        int dr = (lane >> 4) * 4, dc = lane & 15;
        float w2v0 = w2[wc * 32 + dc];
        float w2v1 = w2[wc * 32 + 16 + dc];
        #pragma unroll
        for (int mi = 0; mi < 2; ++mi) {
            #pragma unroll
            for (int j2 = 0; j2 < 4; ++j2) {
                float v0 = acc[mi][0][j2];
                float v1 = acc[mi][1][j2];
                float t = v0 / (1.f + __expf(-v0)) * w2v0
                        + v1 / (1.f + __expf(-v1)) * w2v1;
                t += __shfl_xor(t, 1);
                t += __shfl_xor(t, 2);
                t += __shfl_xor(t, 4);
                t += __shfl_xor(t, 8);
                if (dc == 0) red[wc][wr * 32 + mi * 16 + dr + j2] = t;
            }
        }
        __syncthreads();
        if (tid < 64) {
            float g = red[0][tid] + red[1][tid];
            gamma[row0 + tid] = 1.f / (1.f + __expf(-g));
        }
    }
}

// ---------------- bf16 MFMA GEMM, 128-col tiles ------------------------------
// MODE 1: bf16 out.  MODE 2: paired silu-mul, bf16 out width N/2.
template<int BM, int MODE>
__global__ __launch_bounds__(256) void gemm_bb_kernel(
    const u16* __restrict__ A, const u16* __restrict__ B,
    u16* __restrict__ Cb, int M, int N, int K)
{
    constexpr int MREP = BM / 32;
    constexpr int ACH  = BM / 32;
    __shared__ u16 As[BM * 64];
    __shared__ u16 Bs[128 * 64];
    int tid = threadIdx.x, lane = tid & 63, wid = tid >> 6;
    int wr = wid >> 1, wc = wid & 1;
    int row0 = blockIdx.y * BM, col0 = blockIdx.x * 128;
    int l8 = lane >> 3, l7 = lane & 7;
    f32x4_t acc[MREP][4];
    #pragma unroll
    for (int i = 0; i < MREP; ++i)
        #pragma unroll
        for (int j = 0; j < 4; ++j) acc[i][j] = (f32x4_t)0.f;

    int fr = lane & 15, fo = (lane >> 4) * 8;
    for (int k0 = 0; k0 < K; k0 += 64) {
        #pragma unroll
        for (int i = 0; i < ACH; ++i) {
            int ch = wid * ACH + i;
            const u16* ga = A + (size_t)(row0 + ch * 8 + l8) * K + k0 + l7 * 8;
            gload16(ga, &As[ch * 512]);
        }
        #pragma unroll
        for (int i = 0; i < 4; ++i) {
            int ch = wid * 4 + i;
            const u16* gb = B + (size_t)(col0 + ch * 8 + l8) * K + k0 + l7 * 8;
            gload16(gb, &Bs[ch * 512]);
        }
        __syncthreads();
        __builtin_amdgcn_s_setprio(1);
        #pragma unroll
        for (int khf = 0; khf < 2; ++khf) {
            bf16x8_t bfrag[4];
            #pragma unroll
            for (int ni = 0; ni < 4; ++ni)
                bfrag[ni] = *(const bf16x8_t*)&Bs[(wc * 64 + ni * 16 + fr) * 64 + khf * 32 + fo];
            #pragma unroll
            for (int mi = 0; mi < MREP; ++mi) {
                bf16x8_t af = *(const bf16x8_t*)&As[(wr * (BM / 2) + mi * 16 + fr) * 64 + khf * 32 + fo];
                #pragma unroll
                for (int ni = 0; ni < 4; ++ni)
                    acc[mi][ni] = __builtin_amdgcn_mfma_f32_16x16x32_bf16(
                        af, bfrag[ni], acc[mi][ni], 0, 0, 0);
            }
        }
        __builtin_amdgcn_s_setprio(0);
        __syncthreads();
    }
    int dr = (lane >> 4) * 4, dc = lane & 15;
    #pragma unroll
    for (int mi = 0; mi < MREP; ++mi) {
        int gr = row0 + wr * (BM / 2) + mi * 16 + dr;
        #pragma unroll
        for (int ni = 0; ni < 4; ++ni) {
            int gc = col0 + wc * 64 + ni * 16 + dc;
            #pragma unroll
            for (int j = 0; j < 4; ++j) {
                float v = acc[mi][ni][j];
                if (MODE == 1) {
                    Cb[(size_t)(gr + j) * N + gc] = f2bf(v);
                } else {
                    float partner = __shfl_xor(v, 1);
                    float a1 = (dc & 1) ? partner : v;
                    float a3 = (dc & 1) ? v : partner;
                    float rr = a1 / (1.f + __expf(-a1)) * a3;
                    if (!(dc & 1))
                        Cb[(size_t)(gr + j) * (N >> 1) + (gc >> 1)] = f2bf(rr);
                }
            }
        }
    }
}

// ---------------- bf16 MFMA GEMM, 64x64 tiles, fp32 out + residual ----------
__global__ __launch_bounds__(256) void gemm64_kernel(
    const u16* __restrict__ A, const u16* __restrict__ B,
    const float* __restrict__ res, float* __restrict__ Cf,
    int M, int N, int K)
{
    __shared__ u16 As[64 * 64];
    __shared__ u16 Bs[64 * 64];
    int tid = threadIdx.x, lane = tid & 63, wid = tid >> 6;
    int wr = wid >> 1, wc = wid & 1;
    int row0 = blockIdx.y * 64, col0 = blockIdx.x * 64;
    int l8 = lane >> 3, l7 = lane & 7;
    f32x4_t acc[2][2];
    #pragma unroll
    for (int i = 0; i < 2; ++i)
        #pragma unroll
        for (int j = 0; j < 2; ++j) acc[i][j] = (f32x4_t)0.f;
    int fr = lane & 15, fo = (lane >> 4) * 8;
    for (int k0 = 0; k0 < K; k0 += 64) {
        #pragma unroll
        for (int i = 0; i < 2; ++i) {
            int ch = wid * 2 + i;
            const u16* ga = A + (size_t)(row0 + ch * 8 + l8) * K + k0 + l7 * 8;
            gload16(ga, &As[ch * 512]);
            const u16* gb = B + (size_t)(col0 + ch * 8 + l8) * K + k0 + l7 * 8;
            gload16(gb, &Bs[ch * 512]);
        }
        __syncthreads();
        __builtin_amdgcn_s_setprio(1);
        #pragma unroll
        for (int khf = 0; khf < 2; ++khf) {
            bf16x8_t bfrag[2];
            #pragma unroll
            for (int ni = 0; ni < 2; ++ni)
                bfrag[ni] = *(const bf16x8_t*)&Bs[(wc * 32 + ni * 16 + fr) * 64 + khf * 32 + fo];
            #pragma unroll
            for (int mi = 0; mi < 2; ++mi) {
                bf16x8_t af = *(const bf16x8_t*)&As[(wr * 32 + mi * 16 + fr) * 64 + khf * 32 + fo];
                #pragma unroll
                for (int ni = 0; ni < 2; ++ni)
                    acc[mi][ni] = __builtin_amdgcn_mfma_f32_16x16x32_bf16(
                        af, bfrag[ni], acc[mi][ni], 0, 0, 0);
            }
        }
        __builtin_amdgcn_s_setprio(0);
        __syncthreads();
    }
    int dr = (lane >> 4) * 4, dc = lane & 15;
    #pragma unroll
    for (int mi = 0; mi < 2; ++mi) {
        int gr = row0 + wr * 32 + mi * 16 + dr;
        #pragma unroll
        for (int ni = 0; ni < 2; ++ni) {
            int gc = col0 + wc * 32 + ni * 16 + dc;
            #pragma unroll
            for (int j = 0; j < 4; ++j) {
                size_t off = (size_t)(gr + j) * N + gc;
                Cf[off] = acc[mi][ni][j] + res[off];
            }
        }
    }
}

// ============ FUSED omega-rule + flash attention (8-wave col-split) =========
// Blocks [0,512): attention. Blocks [512, 512+2368): weight transposes for
// wo/w1/w3/w2 that back-fill idle CUs while attention blocks retire.
__global__ __launch_bounds__(512) void fused_omega_attn_kernel(
    const float* __restrict__ qhp, const u16* __restrict__ khp,
    const u16* __restrict__ khT, const u16* __restrict__ vhT,
    const float* __restrict__ gammab, const float* __restrict__ mp,
    const float* __restrict__ mg, u16* __restrict__ ao,
    const float* __restrict__ w_o, const float* __restrict__ w1f,
    const float* __restrict__ w3f, const float* __restrict__ w2f,
    u16* __restrict__ woT, u16* __restrict__ w13T, u16* __restrict__ w2T)
{
    __shared__ u16 Ks[2][KBLK][ALDK];
    __shared__ u16 Xt[2][KBLK][ALDK];
    __shared__ u16 Ps[QBLK][ALDK];
    __shared__ float colfL[CTX_W + KBLK];
    __shared__ float redS[2][QBLK];      // cross-half reduction (wsum / l)
    const int tid = threadIdx.x, lane = tid & 63, wid = tid >> 6;
    const int b = blockIdx.x;

    if (b >= 512) {
        // ---- transpose back-fill path (512 threads per 64x64 tile) ----
        int b2 = b - 512;
        const float* src; u16* dst;
        int srcK, srcN, Kp, rowOff, rowMul, nbx;
        if (b2 < 256)       {             src = w_o; dst = woT;  srcK = 1024; srcN = 1024; Kp = 1024; rowOff = 0; rowMul = 1; nbx = 16; }
        else if (b2 < 960)  { b2 -= 256;  src = w1f; dst = w13T; srcK = 1024; srcN = 2730; Kp = 1024; rowOff = 0; rowMul = 2; nbx = 44; }
        else if (b2 < 1664) { b2 -= 960;  src = w3f; dst = w13T; srcK = 1024; srcN = 2730; Kp = 1024; rowOff = 1; rowMul = 2; nbx = 44; }
        else                { b2 -= 1664; src = w2f; dst = w2T;  srcK = 2730; srcN = 1024; Kp = 2816; rowOff = 0; rowMul = 1; nbx = 16; }
        int n0 = (b2 % nbx) * 64, k0 = (b2 / nbx) * 64;
        float* tile = (float*)&Ks[0][0][0];    // 16.6KB alias inside Ks+Xt
        int tx = tid & 15, ty = tid >> 4;      // ty 0..31
        bool interior = (k0 + 63 < srcK) && (n0 + 63 < srcN);
        #pragma unroll
        for (int p = 0; p < 2; ++p) {
            int kk = p * 32 + ty;
            int r = k0 + kk;
            int cb = n0 + tx * 4;
            float4 v;
            if (interior) {
                v = *(const float4*)(src + (size_t)r * srcN + cb);
            } else {
                v.x = (r < srcK && cb     < srcN) ? src[(size_t)r * srcN + cb]     : 0.f;
                v.y = (r < srcK && cb + 1 < srcN) ? src[(size_t)r * srcN + cb + 1] : 0.f;
                v.z = (r < srcK && cb + 2 < srcN) ? src[(size_t)r * srcN + cb + 2] : 0.f;
                v.w = (r < srcK && cb + 3 < srcN) ? src[(size_t)r * srcN + cb + 3] : 0.f;
            }
            tile[kk * 65 + tx*4+0] = v.x; tile[kk * 65 + tx*4+1] = v.y;
            tile[kk * 65 + tx*4+2] = v.z; tile[kk * 65 + tx*4+3] = v.w;
        }
        __syncthreads();
        int wx = tid & 7, wy = tid >> 3;       // wy 0..63
        int nn = wy, ks = wx * 8;
        uint4 o;
        o.x = f2bf2(tile[(ks+0) * 65 + nn], tile[(ks+1) * 65 + nn]);
        o.y = f2bf2(tile[(ks+2) * 65 + nn], tile[(ks+3) * 65 + nn]);
        o.z = f2bf2(tile[(ks+4) * 65 + nn], tile[(ks+5) * 65 + nn]);
        o.w = f2bf2(tile[(ks+6) * 65 + nn], tile[(ks+7) * 65 + nn]);
        *(uint4*)(dst + (size_t)(rowOff + (size_t)(n0 + nn) * rowMul) * Kp + k0 + ks) = o;
        return;
    }

    const int wq = wid & 3;              // row group (16 q-rows)
    const int nh = wid >> 2;             // column half (0/1)
    const int hi = (b >> 8) & 1;
    const int h = ((b & 7) << 1) + hi;
    const int s5 = (b >> 3) & 31;
    const int qt = hi ? (31 - s5) : s5;
    const int q0 = qt * QBLK;
    const int fr = lane & 15, g4 = lane >> 4;
    const int fko = g4 * 8;
    const int c = fr, rg = g4;
    const int si = tid >> 3, sdb = (tid & 7) * 8;   // staging: 512 thr x 16B
    const size_t hS = (size_t)h * S_LEN;
    const size_t hD = (size_t)h * HD_DIM;

    int rowt[4]; float rowf[4];
    #pragma unroll
    for (int j = 0; j < 4; ++j) {
        rowt[j] = q0 + wq * 16 + rg * 4 + j;
        rowf[j] = exp2f((float)(wq * 16 + rg * 4 + j) * L2LAM);
    }
    bf16x8_t qf[2];
    {
        const float* qrow = qhp + (hS + q0 + wq * 16 + fr) * HD_DIM;
        #pragma unroll
        for (int u = 0; u < 2; ++u) {
            float4 a = *(const float4*)(qrow + u * 32 + fko);
            float4 bq = *(const float4*)(qrow + u * 32 + fko + 4);
            bf16x8_t f;
            f[0]=f2bf(a.x); f[1]=f2bf(a.y); f[2]=f2bf(a.z); f[3]=f2bf(a.w);
            f[4]=f2bf(bq.x); f[5]=f2bf(bq.y); f[6]=f2bf(bq.z); f[7]=f2bf(bq.w);
            qf[u] = f;
        }
    }
    // preload q_old for this wave's column quadrants (n = 2*nh + nn)
    float qold[2][4];
    #pragma unroll
    for (int nn = 0; nn < 2; ++nn)
        #pragma unroll
        for (int j = 0; j < 4; ++j)
            qold[nn][j] = qhp[(hS + rowt[j]) * HD_DIM + (nh * 2 + nn) * 16 + c];

    // ---------------- omega phase ----------------
    f32x4_t accc[2];
    accc[0] = (f32x4_t)0.f; accc[1] = (f32x4_t)0.f;
    float wsum[4] = {0.f, 0.f, 0.f, 0.f};
    const int kt0 = (q0 > (CTX_W - 1)) ? (q0 - (CTX_W - 1)) / KBLK : 0;
    const int i0 = kt0 * KBLK;
    const int nwin = (qt + 1) * KBLK - i0;
    for (int idx = tid; idx < nwin; idx += 512) {
        int icol = i0 + idx;
        colfL[idx] = exp2f((float)(q0 - icol) * L2LAM) * gammab[icol];
    }
    {
        const u16* gk = khp + (hS + kt0 * KBLK + si) * HD_DIM + sdb;
        const u16* gx = khT + (hD + si) * S_LEN + kt0 * KBLK + sdb;
        *(bf16x8_t*)&Ks[0][si][sdb] = *(const bf16x8_t*)gk;
        *(bf16x8_t*)&Xt[0][si][sdb] = *(const bf16x8_t*)gx;
    }
    __syncthreads();
    int cur = 0;
    for (int kt = kt0; kt <= qt; ++kt) {
        const int k0 = kt * KBLK;
        const bool hn = (kt < qt);
        bf16x8_t nk0, nx0;
        if (hn) {
            const u16* gk = khp + (hS + k0 + KBLK + si) * HD_DIM + sdb;
            const u16* gx = khT + (hD + si) * S_LEN + k0 + KBLK + sdb;
            nk0 = *(const bf16x8_t*)gk;
            nx0 = *(const bf16x8_t*)gx;
        }
        f32x4_t s[2];
        s[0] = (f32x4_t)0.f; s[1] = (f32x4_t)0.f;
        __builtin_amdgcn_s_setprio(1);
        #pragma unroll
        for (int u = 0; u < 2; ++u)
            #pragma unroll
            for (int nn = 0; nn < 2; ++nn) {
                bf16x8_t kb = *(const bf16x8_t*)&Ks[cur][(nh * 2 + nn) * 16 + fr][u * 32 + fko];
                s[nn] = __builtin_amdgcn_mfma_f32_16x16x32_bf16(qf[u], kb, s[nn], 0, 0, 0);
            }
        __builtin_amdgcn_s_setprio(0);
        const bool boundary = (kt == kt0) || (kt == qt);
        float colf[2];
        #pragma unroll
        for (int nn = 0; nn < 2; ++nn)
            colf[nn] = colfL[k0 - i0 + (nh * 2 + nn) * 16 + c];
        #pragma unroll
        for (int j = 0; j < 4; ++j) {
            float pv[2];
            #pragma unroll
            for (int nn = 0; nn < 2; ++nn) {
                float w;
                if (boundary) {
                    int delta = rowt[j] - (k0 + (nh * 2 + nn) * 16 + c);
                    w = (delta >= 0 && delta < CTX_W) ? rowf[j] * colf[nn] : 0.f;
                } else {
                    w = rowf[j] * colf[nn];
                }
                wsum[j] += w;
                pv[nn] = w * s[nn][j];
            }
            *(unsigned*)&Ps[wq * 16 + rg * 4 + j][c * 4 + nh * 2] = f2bf2(pv[0], pv[1]);
        }
        __syncthreads();   // P rows complete (both halves)
        __builtin_amdgcn_s_setprio(1);
        #pragma unroll
        for (int u = 0; u < 2; ++u) {
            bf16x8_t pa = *(const bf16x8_t*)&Ps[wq * 16 + fr][u * 32 + fko];
            #pragma unroll
            for (int nn = 0; nn < 2; ++nn) {
                bf16x8_t kb = *(const bf16x8_t*)&Xt[cur][(nh * 2 + nn) * 16 + fr][u * 32 + fko];
                accc[nn] = __builtin_amdgcn_mfma_f32_16x16x32_bf16(pa, kb, accc[nn], 0, 0, 0);
            }
        }
        __builtin_amdgcn_s_setprio(0);
        if (hn) {
            int nxt = cur ^ 1;
            *(bf16x8_t*)&Ks[nxt][si][sdb] = nk0;
            *(bf16x8_t*)&Xt[nxt][si][sdb] = nx0;
        }
        __syncthreads();
        cur ^= 1;
    }
    // persist = Q @ M_p^T (this wave's output quadrants)
    f32x4_t pacc[2];
    pacc[0] = (f32x4_t)0.f; pacc[1] = (f32x4_t)0.f;
    const float* mph = mp + hD * HD_DIM;
    #pragma unroll
    for (int u = 0; u < 2; ++u)
        #pragma unroll
        for (int nn = 0; nn < 2; ++nn) {
            const float* br = mph + (size_t)((nh * 2 + nn) * 16 + fr) * HD_DIM + u * 32 + fko;
            float4 a = *(const float4*)br;
            float4 bq = *(const float4*)(br + 4);
            bf16x8_t f;
            f[0]=f2bf(a.x); f[1]=f2bf(a.y); f[2]=f2bf(a.z); f[3]=f2bf(a.w);
            f[4]=f2bf(bq.x); f[5]=f2bf(bq.y); f[6]=f2bf(bq.z); f[7]=f2bf(bq.w);
            pacc[nn] = __builtin_amdgcn_mfma_f32_16x16x32_bf16(qf[u], f, pacc[nn], 0, 0, 0);
        }
    #pragma unroll
    for (int j = 0; j < 4; ++j) {
        wsum[j] += __shfl_xor(wsum[j], 1);
        wsum[j] += __shfl_xor(wsum[j], 2);
        wsum[j] += __shfl_xor(wsum[j], 4);
        wsum[j] += __shfl_xor(wsum[j], 8);
    }
    if (fr == 0) {
        #pragma unroll
        for (int j = 0; j < 4; ++j)
            redS[nh][wq * 16 + rg * 4 + j] = wsum[j];
    }
    __syncthreads();
    float wtot[4];
    #pragma unroll
    for (int j = 0; j < 4; ++j)
        wtot[j] = redS[0][wq * 16 + rg * 4 + j] + redS[1][wq * 16 + rg * 4 + j];
    float gate = 1.f / (1.f + __expf(-mg[0]));
    float keep = 1.f - gate;
    #pragma unroll
    for (int nn = 0; nn < 2; ++nn) {
        #pragma unroll
        for (int j = 0; j < 4; ++j) {
            float qn = keep * qold[nn][j] + gate * (pacc[nn][j] + accc[nn][j]) / (1.f + wtot[j]);
            Ps[wq * 16 + rg * 4 + j][(nh * 2 + nn) * 16 + c] = f2bf(qn * QSCALE);
        }
    }
    __syncthreads();   // q_new rows complete (both halves)
    bf16x8_t qf2[2];
    #pragma unroll
    for (int u = 0; u < 2; ++u)
        qf2[u] = *(const bf16x8_t*)&Ps[wq * 16 + fr][u * 32 + fko];

    // ---------------- attention phase ----------------
    f32x4_t acco[2];
    acco[0] = (f32x4_t)0.f; acco[1] = (f32x4_t)0.f;
    float l_run[4] = {0.f, 0.f, 0.f, 0.f};
    {
        const u16* gk = khp + (hS + si) * HD_DIM + sdb;
        const u16* gv = vhT + (hD + si) * S_LEN + sdb;
        *(bf16x8_t*)&Ks[0][si][sdb] = *(const bf16x8_t*)gk;
        *(bf16x8_t*)&Xt[0][si][sdb] = *(const bf16x8_t*)gv;
    }
    __syncthreads();
    cur = 0;
    for (int kt = 0; kt <= qt; ++kt) {
        const int k0 = kt * KBLK;
        const bool hn = (kt < qt);
        bf16x8_t nk0, nv0;
        if (hn) {
            const u16* gk = khp + (hS + k0 + KBLK + si) * HD_DIM + sdb;
            const u16* gv = vhT + (hD + si) * S_LEN + k0 + KBLK + sdb;
            nk0 = *(const bf16x8_t*)gk;
            nv0 = *(const bf16x8_t*)gv;
        }
        f32x4_t s[2];
        s[0] = (f32x4_t)0.f; s[1] = (f32x4_t)0.f;
        __builtin_amdgcn_s_setprio(1);
        #pragma unroll
        for (int u = 0; u < 2; ++u)
            #pragma unroll
            for (int nn = 0; nn < 2; ++nn) {
                bf16x8_t kb = *(const bf16x8_t*)&Ks[cur][(nh * 2 + nn) * 16 + fr][u * 32 + fko];
                s[nn] = __builtin_amdgcn_mfma_f32_16x16x32_bf16(qf2[u], kb, s[nn], 0, 0, 0);
            }
        __builtin_amdgcn_s_setprio(0);
        if (kt == qt) {   // causal mask only on diagonal tile
            #pragma unroll
            for (int nn = 0; nn < 2; ++nn) {
                int icol = k0 + (nh * 2 + nn) * 16 + c;
                #pragma unroll
                for (int j = 0; j < 4; ++j)
                    if (icol > rowt[j]) s[nn][j] = -1e30f;
            }
        }
        #pragma unroll
        for (int j = 0; j < 4; ++j) {
            float p0 = exp2f(s[0][j]);
            float p1 = exp2f(s[1][j]);
            l_run[j] += p0 + p1;
            *(unsigned*)&Ps[wq * 16 + rg * 4 + j][c * 4 + nh * 2] = f2bf2(p0, p1);
        }
        __syncthreads();   // P rows complete (both halves)
        __builtin_amdgcn_s_setprio(1);
        #pragma unroll
        for (int u = 0; u < 2; ++u) {
            bf16x8_t pa = *(const bf16x8_t*)&Ps[wq * 16 + fr][u * 32 + fko];
            #pragma unroll
            for (int nn = 0; nn < 2; ++nn) {
                bf16x8_t vb = *(const bf16x8_t*)&Xt[cur][(nh * 2 + nn) * 16 + fr][u * 32 + fko];
                acco[nn] = __builtin_amdgcn_mfma_f32_16x16x32_bf16(pa, vb, acco[nn], 0, 0, 0);
            }
        }
        __builtin_amdgcn_s_setprio(0);
        if (hn) {
            int nxt = cur ^ 1;
            *(bf16x8_t*)&Ks[nxt][si][sdb] = nk0;
            *(bf16x8_t*)&Xt[nxt][si][sdb] = nv0;
        }
        __syncthreads();
        cur ^= 1;
    }
    #pragma unroll
    for (int j = 0; j < 4; ++j) {
        l_run[j] += __shfl_xor(l_run[j], 1);
        l_run[j] += __shfl_xor(l_run[j], 2);
        l_run[j] += __shfl_xor(l_run[j], 4);
        l_run[j] += __shfl_xor(l_run[j], 8);
    }
    if (fr == 0) {
        #pragma unroll
        for (int j = 0; j < 4; ++j)
            redS[nh][wq * 16 + rg * 4 + j] = l_run[j];
    }
    __syncthreads();
    #pragma unroll
    for (int j = 0; j < 4; ++j)
        l_run[j] = redS[0][wq * 16 + rg * 4 + j] + redS[1][wq * 16 + rg * 4 + j];
    #pragma unroll
    for (int nn = 0; nn < 2; ++nn) {
        #pragma unroll
        for (int j = 0; j < 4; ++j) {
            float o = acco[nn][j] / l_run[j];
            ao[(size_t)rowt[j] * D_DIM + h * HD_DIM + (nh * 2 + nn) * 16 + c] = f2bf(o);
        }
    }
}

extern "C" void kernel_launch(void* const* d_in, const int* in_sizes, int n_in,
                              void* d_out, int out_size, void* d_ws, size_t ws_size,
                              hipStream_t stream) {
    const float* x         = (const float*)d_in[0];
    const float* norm1_w   = (const float*)d_in[1];
    const float* norm2_w   = (const float*)d_in[2];
    const float* w_qkv     = (const float*)d_in[3];
    const float* q_norm_w  = (const float*)d_in[4];
    const float* k_norm_w  = (const float*)d_in[5];
    const float* gamma_w1  = (const float*)d_in[6];
    const float* gamma_w2  = (const float*)d_in[7];
    const float* m_persist = (const float*)d_in[8];
    const float* mem_gate  = (const float*)d_in[9];
    const float* w_o       = (const float*)d_in[10];
    const float* ffn_w1    = (const float*)d_in[11];
    const float* ffn_w3    = (const float*)d_in[12];
    const float* ffn_w2    = (const float*)d_in[13];
    float* out = (float*)d_out;
    char* ws = (char*)d_ws;

    const size_t MB = 1024 * 1024;
    u16*   h_bf   = (u16*)(ws);                 // [0,4MB) h / h2
    u16*   wqT    = (u16*)(ws + 4 * MB);        // [4,10)
    u16*   woT    = (u16*)(ws + 10 * MB);       // [10,12)
    u16*   w13T   = (u16*)(ws + 12 * MB);       // [12,23) interleaved w1/w3
    u16*   w2T    = (u16*)(ws + 23 * MB);       // [23,28.5)
    u16*   qkv_bf = (u16*)(ws + 29884416);      // [28.5,40.5) dead after split
    u16*   ao_bf  = (u16*)(ws + 38273024);      // [36.5,40.5) (after qkv dead)
    float* qh     = (float*)(ws + 42467328);    // [40.5,48.5) fp32 q
    u16*   kh     = (u16*)(ws + 50855936);      // [48.5,52.5)
    u16*   khT_s  = (u16*)(ws + 50855936 + 4 * MB);   // [52.5,56.5)
    float* gammab = (float*)(ws + 59244544);    // [56.5,+8KB)
    u16*   vhT_s  = (u16*)(ws + 59244544 + 65536);    // [56.56,+4MB)
    u16*   gw1T   = (u16*)(ws + 63504384);      // [60.56,+128KB) gamma W1^T bf16
    u16*   mid_bf = (u16*)(ws + 29884416);      // [28.5,40) post-attention

    // --- prep: wqT + gw1T transposes + rmsnorm1, ONE launch ------------------
    hipLaunchKernelGGL(prep_kernel, dim3(784 + S_LEN), dim3(256), 0, stream,
                       w_qkv, gamma_w1, wqT, gw1T, x, norm1_w, h_bf);

    // --- forward pass ---------------------------------------------------------
    hipLaunchKernelGGL((gemm_bb_kernel<64, 1>), dim3(24, 32), dim3(256), 0, stream,
                       h_bf, wqT, qkv_bf, S_LEN, 3 * D_DIM, D_DIM);
    // split+rope+transpose (512 blocks) + gamma gate GEMM (32 blocks), merged
    hipLaunchKernelGGL(split_gamma_kernel, dim3(512 + 32), dim3(256), 0, stream,
                       qkv_bf, q_norm_w, k_norm_w, qh, kh, khT_s, vhT_s,
                       h_bf, gw1T, gamma_w2, gammab);
    // fused attention (512 blocks) + late weight transposes back-fill (2368)
    hipLaunchKernelGGL(fused_omega_attn_kernel, dim3(512 + 2368), dim3(512), 0, stream,
                       qh, kh, khT_s, vhT_s, gammab, m_persist, mem_gate, ao_bf,
                       w_o, ffn_w1, ffn_w3, ffn_w2, woT, w13T, w2T);
    hipLaunchKernelGGL(gemm64_kernel, dim3(16, 32), dim3(256), 0, stream,
                       ao_bf, woT, x, out, S_LEN, D_DIM, D_DIM);
    hipLaunchKernelGGL(rmsnorm_kernel, dim3(S_LEN), dim3(256), 0, stream,
                       out, norm2_w, h_bf);
    // ffn13 GEMM (BM=128) with fused SwiGLU epilogue -> mid
    hipLaunchKernelGGL((gemm_bb_kernel<128, 2>), dim3(44, 16), dim3(256), 0, stream,
                       h_bf, w13T, mid_bf, S_LEN, 2 * FFNP, D_DIM);
    hipLaunchKernelGGL(gemm64_kernel, dim3(16, 32), dim3(256), 0, stream,
                       mid_bf, w2T, out, out, S_LEN, D_DIM, FFNP);
}

// Round 26
// 194.568 us; speedup vs baseline: 1.1839x; 1.0061x over previous
//
#include <hip/hip_runtime.h>
#include <hip/hip_bf16.h>

#define S_LEN 2048
#define D_DIM 1024
#define H_NUM 16
#define HD_DIM 64
#define GH_DIM 64
#define FFN_H 2730
#define FFNP  2816          // FFN_H padded to multiple of 128 (zero-filled)
#define CTX_W 512
#define L2LAM -0.00144341687f   // log2(0.999)
#define QBLK 64
#define KBLK 64
#define ALDK 76             // LDS row stride (152B): write-conflict-free, reads <=2-way
#define QSCALE 0.1803368801111731f  // 0.125 * log2(e): scores come out ready for exp2

typedef unsigned short u16;
typedef __attribute__((ext_vector_type(8))) short bf16x8_t;
typedef __attribute__((ext_vector_type(4))) float f32x4_t;

__device__ inline float wave_sum(float v) {
    for (int off = 32; off; off >>= 1) v += __shfl_xor(v, off);
    return v;
}
// f32 -> bf16 (RNE) via the HW pack instruction: 1 VALU op.
__device__ inline u16 f2bf(float f) {
    unsigned r;
    asm("v_cvt_pk_bf16_f32 %0, %1, %2" : "=v"(r) : "v"(f), "v"(f));
    return (u16)r;
}
// pack two f32 -> u32 of 2 bf16 (lo, hi): 1 VALU op.
__device__ inline unsigned f2bf2(float lo, float hi) {
    unsigned r;
    asm("v_cvt_pk_bf16_f32 %0, %1, %2" : "=v"(r) : "v"(lo), "v"(hi));
    return r;
}
__device__ inline float bf2f(u16 u) {
    return __uint_as_float(((unsigned int)u) << 16);
}
__device__ inline void gload16(const void* g, void* l) {
    __builtin_amdgcn_global_load_lds(
        (const __attribute__((address_space(1))) void*)g,
        (__attribute__((address_space(3))) void*)l, 16, 0, 0);
}

// ------- RMSNorm (fp32 in -> bf16 out) --------------------------------------
__global__ __launch_bounds__(256) void rmsnorm_kernel(
    const float* __restrict__ in, const float* __restrict__ w,
    u16* __restrict__ out)
{
    __shared__ float wsum[4];
    int row = blockIdx.x;
    int tid = threadIdx.x, lane = tid & 63, wv = tid >> 6;
    const float4* ir = reinterpret_cast<const float4*>(in + (size_t)row * D_DIM);
    float4 v = ir[tid];
    float ss = v.x*v.x + v.y*v.y + v.z*v.z + v.w*v.w;
    ss = wave_sum(ss);
    if (lane == 0) wsum[wv] = ss;
    __syncthreads();
    float tot = wsum[0] + wsum[1] + wsum[2] + wsum[3];
    float scale = rsqrtf(tot / (float)D_DIM + 1e-6f);
    const float4* wr = reinterpret_cast<const float4*>(w);
    float4 wv4 = wr[tid];
    uint2 o;
    o.x = f2bf2(v.x * scale * wv4.x, v.y * scale * wv4.y);
    o.y = f2bf2(v.z * scale * wv4.z, v.w * scale * wv4.w);
    *reinterpret_cast<uint2*>(out + (size_t)row * D_DIM + tid * 4) = o;
}

// --- prep: wqT + gw1T transposes + rmsnorm1 ---------------------------------
__global__ __launch_bounds__(256) void prep_kernel(
    const float* __restrict__ w_qkv, const float* __restrict__ gw1f,
    u16* __restrict__ wqT, u16* __restrict__ gw1T,
    const float* __restrict__ x, const float* __restrict__ norm1_w,
    u16* __restrict__ h_bf)
{
    __shared__ float tile[64][65];
    __shared__ float wsum[4];
    int b = blockIdx.x;
    int tid = threadIdx.x;
    if (b < 784) {
        const float* src; u16* dst;
        int srcK, srcN, Kp, nbx;
        if (b < 768) {           src = w_qkv; dst = wqT;  srcK = 1024; srcN = 3072; Kp = 1024; nbx = 48; }
        else         { b -= 768; src = gw1f;  dst = gw1T; srcK = 1024; srcN = 64;   Kp = 1024; nbx = 1; }
        int n0 = (b % nbx) * 64, k0 = (b / nbx) * 64;
        int tx = tid & 15, ty = tid >> 4;
        bool interior = (k0 + 63 < srcK) && (n0 + 63 < srcN);
        #pragma unroll
        for (int p = 0; p < 4; ++p) {
            int kk = p * 16 + ty;
            int r = k0 + kk;
            int cb = n0 + tx * 4;
            float4 v;
            if (interior) {
                v = *(const float4*)(src + (size_t)r * srcN + cb);
            } else {
                v.x = (r < srcK && cb     < srcN) ? src[(size_t)r * srcN + cb]     : 0.f;
                v.y = (r < srcK && cb + 1 < srcN) ? src[(size_t)r * srcN + cb + 1] : 0.f;
                v.z = (r < srcK && cb + 2 < srcN) ? src[(size_t)r * srcN + cb + 2] : 0.f;
                v.w = (r < srcK && cb + 3 < srcN) ? src[(size_t)r * srcN + cb + 3] : 0.f;
            }
            tile[kk][tx*4+0] = v.x; tile[kk][tx*4+1] = v.y;
            tile[kk][tx*4+2] = v.z; tile[kk][tx*4+3] = v.w;
        }
        __syncthreads();
        int wx = tid & 7, wy = tid >> 3;
        #pragma unroll
        for (int p = 0; p < 2; ++p) {
            int nn = p * 32 + wy;
            int ks = wx * 8;
            uint4 o;
            o.x = f2bf2(tile[ks+0][nn], tile[ks+1][nn]);
            o.y = f2bf2(tile[ks+2][nn], tile[ks+3][nn]);
            o.z = f2bf2(tile[ks+4][nn], tile[ks+5][nn]);
            o.w = f2bf2(tile[ks+6][nn], tile[ks+7][nn]);
            *(uint4*)(dst + (size_t)(n0 + nn) * Kp + k0 + ks) = o;
        }
    } else {
        int row = b - 784;
        int lane = tid & 63, wv = tid >> 6;
        const float4* ir = reinterpret_cast<const float4*>(x + (size_t)row * D_DIM);
        float4 v = ir[tid];
        float ss = v.x*v.x + v.y*v.y + v.z*v.z + v.w*v.w;
        ss = wave_sum(ss);
        if (lane == 0) wsum[wv] = ss;
        __syncthreads();
        float tot = wsum[0] + wsum[1] + wsum[2] + wsum[3];
        float scale = rsqrtf(tot / (float)D_DIM + 1e-6f);
        const float4* wr = reinterpret_cast<const float4*>(norm1_w);
        float4 wv4 = wr[tid];
        uint2 o;
        o.x = f2bf2(v.x * scale * wv4.x, v.y * scale * wv4.y);
        o.y = f2bf2(v.z * scale * wv4.z, v.w * scale * wv4.w);
        *reinterpret_cast<uint2*>(h_bf + (size_t)row * D_DIM + tid * 4) = o;
    }
}

// ---- split qkv + qk rmsnorm + RoPE + KV transpose, PLUS gamma gate ---------
// Blocks [0,512): split (s0=(b&31)*64, h=b>>5). Blocks [512,544): gamma GEMM
// (row0=(b-512)*64). Both depend only on earlier launches; LDS is a manual
// union (split: 19.5KB tk/tv; gamma: 16.9KB As/Bs/red).
__global__ __launch_bounds__(256) void split_gamma_kernel(
    const u16* __restrict__ qkv, const float* __restrict__ qw,
    const float* __restrict__ kw, float* __restrict__ qhp,
    u16* __restrict__ khp, u16* __restrict__ khT, u16* __restrict__ vhT,
    const u16* __restrict__ h_bf, const u16* __restrict__ gw1T,
    const float* __restrict__ w2, float* __restrict__ gamma)
{
    __shared__ char smem[2 * 64 * ALDK * 2];   // 19456B, carved below
    int tid = threadIdx.x;
    int b = blockIdx.x;
    if (b < 512) {
        u16 (*tk)[ALDK] = (u16(*)[ALDK])smem;
        u16 (*tv)[ALDK] = (u16(*)[ALDK])(smem + 64 * ALDK * 2);
        int w = tid >> 6, d = tid & 63;
        int h = b >> 5;
        int s0 = (b & 31) * 64;
        float qwv = qw[d], kwv = kw[d];
        int j = d & 31;
        float inv = expf(-(float)j * (9.2103403719761836f / 32.0f));
        float sgn = (d < 32) ? -1.f : 1.f;
        for (int i = 0; i < 16; ++i) {
            int sl = w * 16 + i;
            int s = s0 + sl;
            size_t base = (size_t)s * (3 * D_DIM) + h * HD_DIM + d;
            float qv = bf2f(qkv[base]);
            float kv = bf2f(qkv[base + D_DIM]);
            u16  vv = qkv[base + 2 * D_DIM];
            float sq = wave_sum(qv * qv);
            float qn = qv * rsqrtf(sq / (float)HD_DIM + 1e-6f) * qwv;
            float sk = wave_sum(kv * kv);
            float kn = kv * rsqrtf(sk / (float)HD_DIM + 1e-6f) * kwv;
            float ang = (float)s * inv;
            float cs = cosf(ang), sn = sinf(ang);
            float qp = __shfl_xor(qn, 32);
            float kp = __shfl_xor(kn, 32);
            float qo = qn * cs + sgn * qp * sn;
            float ko = kn * cs + sgn * kp * sn;
            size_t ob = ((size_t)h * S_LEN + s) * HD_DIM + d;
            u16 kb = f2bf(ko);
            qhp[ob] = qo;
            khp[ob] = kb;
            tk[sl][d] = kb;
            tv[sl][d] = vv;
        }
        __syncthreads();
        int r = tid >> 2, cc = (tid & 3) * 16;
        union { u16 u[16]; bf16x8_t v[2]; } ok, ov;
        #pragma unroll
        for (int e = 0; e < 16; ++e) {
            int ksrc = (e & 3) * 16 + (tid & 3) * 4 + (e >> 2);   // pi^-1 permute
            ok.u[e] = tk[ksrc][r]; ov.u[e] = tv[ksrc][r];
        }
        u16* kd = khT + ((size_t)h * HD_DIM + r) * S_LEN + s0 + cc;
        u16* vd = vhT + ((size_t)h * HD_DIM + r) * S_LEN + s0 + cc;
        *(bf16x8_t*)kd       = ok.v[0];
        *(bf16x8_t*)(kd + 8) = ok.v[1];
        *(bf16x8_t*)vd       = ov.v[0];
        *(bf16x8_t*)(vd + 8) = ov.v[1];
    } else {
        // ---- gamma gate GEMM path ----
        u16* As = (u16*)smem;                       // 8KB
        u16* Bs = (u16*)(smem + 8192);              // 8KB
        float (*red)[64] = (float(*)[64])(smem + 16384);  // 512B
        int lane = tid & 63, wid = tid >> 6;
        int wr = wid >> 1, wc = wid & 1;
        int row0 = (b - 512) * 64;
        int l8 = lane >> 3, l7 = lane & 7;
        f32x4_t acc[2][2];
        #pragma unroll
        for (int i = 0; i < 2; ++i)
            #pragma unroll
            for (int j2 = 0; j2 < 2; ++j2) acc[i][j2] = (f32x4_t)0.f;
        int fr = lane & 15, fo = (lane >> 4) * 8;
        for (int k0 = 0; k0 < D_DIM; k0 += 64) {
            #pragma unroll
            for (int i = 0; i < 2; ++i) {
                int ch = wid * 2 + i;
                const u16* ga = h_bf + (size_t)(row0 + ch * 8 + l8) * D_DIM + k0 + l7 * 8;
                gload16(ga, &As[ch * 512]);
                const u16* gb = gw1T + (size_t)(ch * 8 + l8) * D_DIM + k0 + l7 * 8;
                gload16(gb, &Bs[ch * 512]);
            }
            __syncthreads();
            __builtin_amdgcn_s_setprio(1);
            #pragma unroll
            for (int khf = 0; khf < 2; ++khf) {
                bf16x8_t bfrag[2];
                #pragma unroll
                for (int ni = 0; ni < 2; ++ni)
                    bfrag[ni] = *(const bf16x8_t*)&Bs[(wc * 32 + ni * 16 + fr) * 64 + khf * 32 + fo];
                #pragma unroll
                for (int mi = 0; mi < 2; ++mi) {
                    bf16x8_t af = *(const bf16x8_t*)&As[(wr * 32 + mi * 16 + fr) * 64 + khf * 32 + fo];
                    #pragma unroll
                    for (int ni = 0; ni < 2; ++ni)
                        acc[mi][ni] = __builtin_amdgcn_mfma_f32_16x16x32_bf16(
                            af, bfrag[ni], acc[mi][ni], 0, 0, 0);
                }
            }
            __builtin_amdgcn_s_setprio(0);
            __syncthreads();
        }
        int dr = (lane >> 4) * 4, dc = lane & 15;
        float w2v0 = w2[wc * 32 + dc];
        float w2v1 = w2[wc * 32 + 16 + dc];
        #pragma unroll
        for (int mi = 0; mi < 2; ++mi) {
            #pragma unroll
            for (int j2 = 0; j2 < 4; ++j2) {
                float v0 = acc[mi][0][j2];
                float v1 = acc[mi][1][j2];
                float t = v0 / (1.f + __expf(-v0)) * w2v0
                        + v1 / (1.f + __expf(-v1)) * w2v1;
                t += __shfl_xor(t, 1);
                t += __shfl_xor(t, 2);
                t += __shfl_xor(t, 4);
                t += __shfl_xor(t, 8);
                if (dc == 0) red[wc][wr * 32 + mi * 16 + dr + j2] = t;
            }
        }
        __syncthreads();
        if (tid < 64) {
            float g = red[0][tid] + red[1][tid];
            gamma[row0 + tid] = 1.f / (1.f + __expf(-g));
        }
    }
}

// ---------------- bf16 MFMA GEMM, 128-col tiles ------------------------------
// MODE 1: bf16 out.  MODE 2: paired silu-mul, bf16 out width N/2.
template<int BM, int MODE>
__global__ __launch_bounds__(256) void gemm_bb_kernel(
    const u16* __restrict__ A, const u16* __restrict__ B,
    u16* __restrict__ Cb, int M, int N, int K)
{
    constexpr int MREP = BM / 32;
    constexpr int ACH  = BM / 32;
    __shared__ u16 As[BM * 64];
    __shared__ u16 Bs[128 * 64];
    int tid = threadIdx.x, lane = tid & 63, wid = tid >> 6;
    int wr = wid >> 1, wc = wid & 1;
    int row0 = blockIdx.y * BM, col0 = blockIdx.x * 128;
    int l8 = lane >> 3, l7 = lane & 7;
    f32x4_t acc[MREP][4];
    #pragma unroll
    for (int i = 0; i < MREP; ++i)
        #pragma unroll
        for (int j = 0; j < 4; ++j) acc[i][j] = (f32x4_t)0.f;

    int fr = lane & 15, fo = (lane >> 4) * 8;
    for (int k0 = 0; k0 < K; k0 += 64) {
        #pragma unroll
        for (int i = 0; i < ACH; ++i) {
            int ch = wid * ACH + i;
            const u16* ga = A + (size_t)(row0 + ch * 8 + l8) * K + k0 + l7 * 8;
            gload16(ga, &As[ch * 512]);
        }
        #pragma unroll
        for (int i = 0; i < 4; ++i) {
            int ch = wid * 4 + i;
            const u16* gb = B + (size_t)(col0 + ch * 8 + l8) * K + k0 + l7 * 8;
            gload16(gb, &Bs[ch * 512]);
        }
        __syncthreads();
        __builtin_amdgcn_s_setprio(1);
        #pragma unroll
        for (int khf = 0; khf < 2; ++khf) {
            bf16x8_t bfrag[4];
            #pragma unroll
            for (int ni = 0; ni < 4; ++ni)
                bfrag[ni] = *(const bf16x8_t*)&Bs[(wc * 64 + ni * 16 + fr) * 64 + khf * 32 + fo];
            #pragma unroll
            for (int mi = 0; mi < MREP; ++mi) {
                bf16x8_t af = *(const bf16x8_t*)&As[(wr * (BM / 2) + mi * 16 + fr) * 64 + khf * 32 + fo];
                #pragma unroll
                for (int ni = 0; ni < 4; ++ni)
                    acc[mi][ni] = __builtin_amdgcn_mfma_f32_16x16x32_bf16(
                        af, bfrag[ni], acc[mi][ni], 0, 0, 0);
            }
        }
        __builtin_amdgcn_s_setprio(0);
        __syncthreads();
    }
    int dr = (lane >> 4) * 4, dc = lane & 15;
    #pragma unroll
    for (int mi = 0; mi < MREP; ++mi) {
        int gr = row0 + wr * (BM / 2) + mi * 16 + dr;
        #pragma unroll
        for (int ni = 0; ni < 4; ++ni) {
            int gc = col0 + wc * 64 + ni * 16 + dc;
            #pragma unroll
            for (int j = 0; j < 4; ++j) {
                float v = acc[mi][ni][j];
                if (MODE == 1) {
                    Cb[(size_t)(gr + j) * N + gc] = f2bf(v);
                } else {
                    float partner = __shfl_xor(v, 1);
                    float a1 = (dc & 1) ? partner : v;
                    float a3 = (dc & 1) ? v : partner;
                    float rr = a1 / (1.f + __expf(-a1)) * a3;
                    if (!(dc & 1))
                        Cb[(size_t)(gr + j) * (N >> 1) + (gc >> 1)] = f2bf(rr);
                }
            }
        }
    }
}

// ---------------- bf16 MFMA GEMM, 64x64 tiles, fp32 out + residual ----------
__global__ __launch_bounds__(256) void gemm64_kernel(
    const u16* __restrict__ A, const u16* __restrict__ B,
    const float* __restrict__ res, float* __restrict__ Cf,
    int M, int N, int K)
{
    __shared__ u16 As[64 * 64];
    __shared__ u16 Bs[64 * 64];
    int tid = threadIdx.x, lane = tid & 63, wid = tid >> 6;
    int wr = wid >> 1, wc = wid & 1;
    int row0 = blockIdx.y * 64, col0 = blockIdx.x * 64;
    int l8 = lane >> 3, l7 = lane & 7;
    f32x4_t acc[2][2];
    #pragma unroll
    for (int i = 0; i < 2; ++i)
        #pragma unroll
        for (int j = 0; j < 2; ++j) acc[i][j] = (f32x4_t)0.f;
    int fr = lane & 15, fo = (lane >> 4) * 8;
    for (int k0 = 0; k0 < K; k0 += 64) {
        #pragma unroll
        for (int i = 0; i < 2; ++i) {
            int ch = wid * 2 + i;
            const u16* ga = A + (size_t)(row0 + ch * 8 + l8) * K + k0 + l7 * 8;
            gload16(ga, &As[ch * 512]);
            const u16* gb = B + (size_t)(col0 + ch * 8 + l8) * K + k0 + l7 * 8;
            gload16(gb, &Bs[ch * 512]);
        }
        __syncthreads();
        __builtin_amdgcn_s_setprio(1);
        #pragma unroll
        for (int khf = 0; khf < 2; ++khf) {
            bf16x8_t bfrag[2];
            #pragma unroll
            for (int ni = 0; ni < 2; ++ni)
                bfrag[ni] = *(const bf16x8_t*)&Bs[(wc * 32 + ni * 16 + fr) * 64 + khf * 32 + fo];
            #pragma unroll
            for (int mi = 0; mi < 2; ++mi) {
                bf16x8_t af = *(const bf16x8_t*)&As[(wr * 32 + mi * 16 + fr) * 64 + khf * 32 + fo];
                #pragma unroll
                for (int ni = 0; ni < 2; ++ni)
                    acc[mi][ni] = __builtin_amdgcn_mfma_f32_16x16x32_bf16(
                        af, bfrag[ni], acc[mi][ni], 0, 0, 0);
            }
        }
        __builtin_amdgcn_s_setprio(0);
        __syncthreads();
    }
    int dr = (lane >> 4) * 4, dc = lane & 15;
    #pragma unroll
    for (int mi = 0; mi < 2; ++mi) {
        int gr = row0 + wr * 32 + mi * 16 + dr;
        #pragma unroll
        for (int ni = 0; ni < 2; ++ni) {
            int gc = col0 + wc * 32 + ni * 16 + dc;
            #pragma unroll
            for (int j = 0; j < 4; ++j) {
                size_t off = (size_t)(gr + j) * N + gc;
                Cf[off] = acc[mi][ni][j] + res[off];
            }
        }
    }
}

// ============ FUSED omega-rule + flash attention (8-wave col-split) =========
// Blocks [0,512): attention. Blocks [512, 512+2368): weight transposes for
// wo/w1/w3/w2 that back-fill idle CUs while attention blocks retire.
// Attention loops use 3-buffer K/X rotation + double-buffered Ps + depth-2
// register prefetch -> ONE barrier per K-tile (iteration kt writes buffer
// (kt+2)%3 post-barrier; first read of that buffer is QK of kt+2, separated
// by barrier of kt+1). LDS 80640B/block: 2 blocks/CU still fit (161280<163840).
__global__ __launch_bounds__(512) void fused_omega_attn_kernel(
    const float* __restrict__ qhp, const u16* __restrict__ khp,
    const u16* __restrict__ khT, const u16* __restrict__ vhT,
    const float* __restrict__ gammab, const float* __restrict__ mp,
    const float* __restrict__ mg, u16* __restrict__ ao,
    const float* __restrict__ w_o, const float* __restrict__ w1f,
    const float* __restrict__ w3f, const float* __restrict__ w2f,
    u16* __restrict__ woT, u16* __restrict__ w13T, u16* __restrict__ w2T)
{
    __shared__ u16 Ks[3][KBLK][ALDK];
    __shared__ u16 Xt[3][KBLK][ALDK];
    __shared__ u16 Ps[2][QBLK][ALDK];
    __shared__ float colfL[CTX_W + KBLK];
    __shared__ float redS[2][QBLK];      // cross-half reduction (wsum / l)
    const int tid = threadIdx.x, lane = tid & 63, wid = tid >> 6;
    const int b = blockIdx.x;

    if (b >= 512) {
        // ---- transpose back-fill path (512 threads per 64x64 tile) ----
        int b2 = b - 512;
        const float* src; u16* dst;
        int srcK, srcN, Kp, rowOff, rowMul, nbx;
        if (b2 < 256)       {             src = w_o; dst = woT;  srcK = 1024; srcN = 1024; Kp = 1024; rowOff = 0; rowMul = 1; nbx = 16; }
        else if (b2 < 960)  { b2 -= 256;  src = w1f; dst = w13T; srcK = 1024; srcN = 2730; Kp = 1024; rowOff = 0; rowMul = 2; nbx = 44; }
        else if (b2 < 1664) { b2 -= 960;  src = w3f; dst = w13T; srcK = 1024; srcN = 2730; Kp = 1024; rowOff = 1; rowMul = 2; nbx = 44; }
        else                { b2 -= 1664; src = w2f; dst = w2T;  srcK = 2730; srcN = 1024; Kp = 2816; rowOff = 0; rowMul = 1; nbx = 16; }
        int n0 = (b2 % nbx) * 64, k0 = (b2 / nbx) * 64;
        float* tile = (float*)&Ks[0][0][0];    // 16.6KB alias inside Ks
        int tx = tid & 15, ty = tid >> 4;      // ty 0..31
        bool interior = (k0 + 63 < srcK) && (n0 + 63 < srcN);
        #pragma unroll
        for (int p = 0; p < 2; ++p) {
            int kk = p * 32 + ty;
            int r = k0 + kk;
            int cb = n0 + tx * 4;
            float4 v;
            if (interior) {
                v = *(const float4*)(src + (size_t)r * srcN + cb);
            } else {
                v.x = (r < srcK && cb     < srcN) ? src[(size_t)r * srcN + cb]     : 0.f;
                v.y = (r < srcK && cb + 1 < srcN) ? src[(size_t)r * srcN + cb + 1] : 0.f;
                v.z = (r < srcK && cb + 2 < srcN) ? src[(size_t)r * srcN + cb + 2] : 0.f;
                v.w = (r < srcK && cb + 3 < srcN) ? src[(size_t)r * srcN + cb + 3] : 0.f;
            }
            tile[kk * 65 + tx*4+0] = v.x; tile[kk * 65 + tx*4+1] = v.y;
            tile[kk * 65 + tx*4+2] = v.z; tile[kk * 65 + tx*4+3] = v.w;
        }
        __syncthreads();
        int wx = tid & 7, wy = tid >> 3;       // wy 0..63
        int nn = wy, ks = wx * 8;
        uint4 o;
        o.x = f2bf2(tile[(ks+0) * 65 + nn], tile[(ks+1) * 65 + nn]);
        o.y = f2bf2(tile[(ks+2) * 65 + nn], tile[(ks+3) * 65 + nn]);
        o.z = f2bf2(tile[(ks+4) * 65 + nn], tile[(ks+5) * 65 + nn]);
        o.w = f2bf2(tile[(ks+6) * 65 + nn], tile[(ks+7) * 65 + nn]);
        *(uint4*)(dst + (size_t)(rowOff + (size_t)(n0 + nn) * rowMul) * Kp + k0 + ks) = o;
        return;
    }

    const int wq = wid & 3;              // row group (16 q-rows)
    const int nh = wid >> 2;             // column half (0/1)
    const int hi = (b >> 8) & 1;
    const int h = ((b & 7) << 1) + hi;
    const int s5 = (b >> 3) & 31;
    const int qt = hi ? (31 - s5) : s5;
    const int q0 = qt * QBLK;
    const int fr = lane & 15, g4 = lane >> 4;
    const int fko = g4 * 8;
    const int c = fr, rg = g4;
    const int si = tid >> 3, sdb = (tid & 7) * 8;   // staging: 512 thr x 16B
    const size_t hS = (size_t)h * S_LEN;
    const size_t hD = (size_t)h * HD_DIM;

    int rowt[4]; float rowf[4];
    #pragma unroll
    for (int j = 0; j < 4; ++j) {
        rowt[j] = q0 + wq * 16 + rg * 4 + j;
        rowf[j] = exp2f((float)(wq * 16 + rg * 4 + j) * L2LAM);
    }
    bf16x8_t qf[2];
    {
        const float* qrow = qhp + (hS + q0 + wq * 16 + fr) * HD_DIM;
        #pragma unroll
        for (int u = 0; u < 2; ++u) {
            float4 a = *(const float4*)(qrow + u * 32 + fko);
            float4 bq = *(const float4*)(qrow + u * 32 + fko + 4);
            bf16x8_t f;
            f[0]=f2bf(a.x); f[1]=f2bf(a.y); f[2]=f2bf(a.z); f[3]=f2bf(a.w);
            f[4]=f2bf(bq.x); f[5]=f2bf(bq.y); f[6]=f2bf(bq.z); f[7]=f2bf(bq.w);
            qf[u] = f;
        }
    }
    // preload q_old for this wave's column quadrants (n = 2*nh + nn)
    float qold[2][4];
    #pragma unroll
    for (int nn = 0; nn < 2; ++nn)
        #pragma unroll
        for (int j = 0; j < 4; ++j)
            qold[nn][j] = qhp[(hS + rowt[j]) * HD_DIM + (nh * 2 + nn) * 16 + c];

    // ---------------- omega phase (3-buf, 1 barrier/tile) ----------------
    f32x4_t accc[2];
    accc[0] = (f32x4_t)0.f; accc[1] = (f32x4_t)0.f;
    float wsum[4] = {0.f, 0.f, 0.f, 0.f};
    const int kt0 = (q0 > (CTX_W - 1)) ? (q0 - (CTX_W - 1)) / KBLK : 0;
    const int i0 = kt0 * KBLK;
    const int nwin = (qt + 1) * KBLK - i0;
    for (int idx = tid; idx < nwin; idx += 512) {
        int icol = i0 + idx;
        colfL[idx] = exp2f((float)(q0 - icol) * L2LAM) * gammab[icol];
    }
    {
        const u16* gk = khp + (hS + kt0 * KBLK + si) * HD_DIM + sdb;
        const u16* gx = khT + (hD + si) * S_LEN + kt0 * KBLK + sdb;
        *(bf16x8_t*)&Ks[0][si][sdb] = *(const bf16x8_t*)gk;
        *(bf16x8_t*)&Xt[0][si][sdb] = *(const bf16x8_t*)gx;
        if (kt0 < qt) {
            *(bf16x8_t*)&Ks[1][si][sdb] = *(const bf16x8_t*)(gk + (size_t)KBLK * HD_DIM);
            *(bf16x8_t*)&Xt[1][si][sdb] = *(const bf16x8_t*)(gx + KBLK);
        }
    }
    __syncthreads();
    int cur = 0;
    for (int kt = kt0; kt <= qt; ++kt) {
        const int k0 = kt * KBLK;
        const bool pf = (kt + 2 <= qt);
        bf16x8_t nk0, nx0;
        if (pf) {
            const u16* gk = khp + (hS + k0 + 2 * KBLK + si) * HD_DIM + sdb;
            const u16* gx = khT + (hD + si) * S_LEN + k0 + 2 * KBLK + sdb;
            nk0 = *(const bf16x8_t*)gk;
            nx0 = *(const bf16x8_t*)gx;
        }
        f32x4_t s[2];
        s[0] = (f32x4_t)0.f; s[1] = (f32x4_t)0.f;
        __builtin_amdgcn_s_setprio(1);
        #pragma unroll
        for (int u = 0; u < 2; ++u)
            #pragma unroll
            for (int nn = 0; nn < 2; ++nn) {
                bf16x8_t kb = *(const bf16x8_t*)&Ks[cur][(nh * 2 + nn) * 16 + fr][u * 32 + fko];
                s[nn] = __builtin_amdgcn_mfma_f32_16x16x32_bf16(qf[u], kb, s[nn], 0, 0, 0);
            }
        __builtin_amdgcn_s_setprio(0);
        const bool boundary = (kt == kt0) || (kt == qt);
        float colf[2];
        #pragma unroll
        for (int nn = 0; nn < 2; ++nn)
            colf[nn] = colfL[k0 - i0 + (nh * 2 + nn) * 16 + c];
        #pragma unroll
        for (int j = 0; j < 4; ++j) {
            float pv[2];
            #pragma unroll
            for (int nn = 0; nn < 2; ++nn) {
                float w;
                if (boundary) {
                    int delta = rowt[j] - (k0 + (nh * 2 + nn) * 16 + c);
                    w = (delta >= 0 && delta < CTX_W) ? rowf[j] * colf[nn] : 0.f;
                } else {
                    w = rowf[j] * colf[nn];
                }
                wsum[j] += w;
                pv[nn] = w * s[nn][j];
            }
            *(unsigned*)&Ps[kt & 1][wq * 16 + rg * 4 + j][c * 4 + nh * 2] = f2bf2(pv[0], pv[1]);
        }
        __syncthreads();   // P rows complete (both halves); prior-tile buffers free
        __builtin_amdgcn_s_setprio(1);
        #pragma unroll
        for (int u = 0; u < 2; ++u) {
            bf16x8_t pa = *(const bf16x8_t*)&Ps[kt & 1][wq * 16 + fr][u * 32 + fko];
            #pragma unroll
            for (int nn = 0; nn < 2; ++nn) {
                bf16x8_t kb = *(const bf16x8_t*)&Xt[cur][(nh * 2 + nn) * 16 + fr][u * 32 + fko];
                accc[nn] = __builtin_amdgcn_mfma_f32_16x16x32_bf16(pa, kb, accc[nn], 0, 0, 0);
            }
        }
        __builtin_amdgcn_s_setprio(0);
        if (pf) {
            int w = cur - 1; if (w < 0) w += 3;   // (cur+2)%3
            *(bf16x8_t*)&Ks[w][si][sdb] = nk0;
            *(bf16x8_t*)&Xt[w][si][sdb] = nx0;
        }
        cur = (cur == 2) ? 0 : cur + 1;
    }
    // persist = Q @ M_p^T (this wave's output quadrants)
    f32x4_t pacc[2];
    pacc[0] = (f32x4_t)0.f; pacc[1] = (f32x4_t)0.f;
    const float* mph = mp + hD * HD_DIM;
    #pragma unroll
    for (int u = 0; u < 2; ++u)
        #pragma unroll
        for (int nn = 0; nn < 2; ++nn) {
            const float* br = mph + (size_t)((nh * 2 + nn) * 16 + fr) * HD_DIM + u * 32 + fko;
            float4 a = *(const float4*)br;
            float4 bq = *(const float4*)(br + 4);
            bf16x8_t f;
            f[0]=f2bf(a.x); f[1]=f2bf(a.y); f[2]=f2bf(a.z); f[3]=f2bf(a.w);
            f[4]=f2bf(bq.x); f[5]=f2bf(bq.y); f[6]=f2bf(bq.z); f[7]=f2bf(bq.w);
            pacc[nn] = __builtin_amdgcn_mfma_f32_16x16x32_bf16(qf[u], f, pacc[nn], 0, 0, 0);
        }
    #pragma unroll
    for (int j = 0; j < 4; ++j) {
        wsum[j] += __shfl_xor(wsum[j], 1);
        wsum[j] += __shfl_xor(wsum[j], 2);
        wsum[j] += __shfl_xor(wsum[j], 4);
        wsum[j] += __shfl_xor(wsum[j], 8);
    }
    if (fr == 0) {
        #pragma unroll
        for (int j = 0; j < 4; ++j)
            redS[nh][wq * 16 + rg * 4 + j] = wsum[j];
    }
    __syncthreads();
    float wtot[4];
    #pragma unroll
    for (int j = 0; j < 4; ++j)
        wtot[j] = redS[0][wq * 16 + rg * 4 + j] + redS[1][wq * 16 + rg * 4 + j];
    float gate = 1.f / (1.f + __expf(-mg[0]));
    float keep = 1.f - gate;
    #pragma unroll
    for (int nn = 0; nn < 2; ++nn) {
        #pragma unroll
        for (int j = 0; j < 4; ++j) {
            float qn = keep * qold[nn][j] + gate * (pacc[nn][j] + accc[nn][j]) / (1.f + wtot[j]);
            Ps[0][wq * 16 + rg * 4 + j][(nh * 2 + nn) * 16 + c] = f2bf(qn * QSCALE);
        }
    }
    __syncthreads();   // q_new rows complete (both halves)
    bf16x8_t qf2[2];
    #pragma unroll
    for (int u = 0; u < 2; ++u)
        qf2[u] = *(const bf16x8_t*)&Ps[0][wq * 16 + fr][u * 32 + fko];

    // ---------------- attention phase (3-buf, 1 barrier/tile) ---------------
    f32x4_t acco[2];
    acco[0] = (f32x4_t)0.f; acco[1] = (f32x4_t)0.f;
    float l_run[4] = {0.f, 0.f, 0.f, 0.f};
    {
        const u16* gk = khp + (hS + si) * HD_DIM + sdb;
        const u16* gv = vhT + (hD + si) * S_LEN + sdb;
        *(bf16x8_t*)&Ks[0][si][sdb] = *(const bf16x8_t*)gk;
        *(bf16x8_t*)&Xt[0][si][sdb] = *(const bf16x8_t*)gv;
        if (qt > 0) {
            *(bf16x8_t*)&Ks[1][si][sdb] = *(const bf16x8_t*)(gk + (size_t)KBLK * HD_DIM);
            *(bf16x8_t*)&Xt[1][si][sdb] = *(const bf16x8_t*)(gv + KBLK);
        }
    }
    __syncthreads();
    cur = 0;
    for (int kt = 0; kt <= qt; ++kt) {
        const int k0 = kt * KBLK;
        const bool pf = (kt + 2 <= qt);
        bf16x8_t nk0, nv0;
        if (pf) {
            const u16* gk = khp + (hS + k0 + 2 * KBLK + si) * HD_DIM + sdb;
            const u16* gv = vhT + (hD + si) * S_LEN + k0 + 2 * KBLK + sdb;
            nk0 = *(const bf16x8_t*)gk;
            nv0 = *(const bf16x8_t*)gv;
        }
        f32x4_t s[2];
        s[0] = (f32x4_t)0.f; s[1] = (f32x4_t)0.f;
        __builtin_amdgcn_s_setprio(1);
        #pragma unroll
        for (int u = 0; u < 2; ++u)
            #pragma unroll
            for (int nn = 0; nn < 2; ++nn) {
                bf16x8_t kb = *(const bf16x8_t*)&Ks[cur][(nh * 2 + nn) * 16 + fr][u * 32 + fko];
                s[nn] = __builtin_amdgcn_mfma_f32_16x16x32_bf16(qf2[u], kb, s[nn], 0, 0, 0);
            }
        __builtin_amdgcn_s_setprio(0);
        if (kt == qt) {   // causal mask only on diagonal tile
            #pragma unroll
            for (int nn = 0; nn < 2; ++nn) {
                int icol = k0 + (nh * 2 + nn) * 16 + c;
                #pragma unroll
                for (int j = 0; j < 4; ++j)
                    if (icol > rowt[j]) s[nn][j] = -1e30f;
            }
        }
        #pragma unroll
        for (int j = 0; j < 4; ++j) {
            float p0 = exp2f(s[0][j]);
            float p1 = exp2f(s[1][j]);
            l_run[j] += p0 + p1;
            *(unsigned*)&Ps[kt & 1][wq * 16 + rg * 4 + j][c * 4 + nh * 2] = f2bf2(p0, p1);
        }
        __syncthreads();   // P rows complete (both halves)
        __builtin_amdgcn_s_setprio(1);
        #pragma unroll
        for (int u = 0; u < 2; ++u) {
            bf16x8_t pa = *(const bf16x8_t*)&Ps[kt & 1][wq * 16 + fr][u * 32 + fko];
            #pragma unroll
            for (int nn = 0; nn < 2; ++nn) {
                bf16x8_t vb = *(const bf16x8_t*)&Xt[cur][(nh * 2 + nn) * 16 + fr][u * 32 + fko];
                acco[nn] = __builtin_amdgcn_mfma_f32_16x16x32_bf16(pa, vb, acco[nn], 0, 0, 0);
            }
        }
        __builtin_amdgcn_s_setprio(0);
        if (pf) {
            int w = cur - 1; if (w < 0) w += 3;   // (cur+2)%3
            *(bf16x8_t*)&Ks[w][si][sdb] = nk0;
            *(bf16x8_t*)&Xt[w][si][sdb] = nv0;
        }
        cur = (cur == 2) ? 0 : cur + 1;
    }
    #pragma unroll
    for (int j = 0; j < 4; ++j) {
        l_run[j] += __shfl_xor(l_run[j], 1);
        l_run[j] += __shfl_xor(l_run[j], 2);
        l_run[j] += __shfl_xor(l_run[j], 4);
        l_run[j] += __shfl_xor(l_run[j], 8);
    }
    if (fr == 0) {
        #pragma unroll
        for (int j = 0; j < 4; ++j)
            redS[nh][wq * 16 + rg * 4 + j] = l_run[j];
    }
    __syncthreads();
    #pragma unroll
    for (int j = 0; j < 4; ++j)
        l_run[j] = redS[0][wq * 16 + rg * 4 + j] + redS[1][wq * 16 + rg * 4 + j];
    #pragma unroll
    for (int nn = 0; nn < 2; ++nn) {
        #pragma unroll
        for (int j = 0; j < 4; ++j) {
            float o = acco[nn][j] / l_run[j];
            ao[(size_t)rowt[j] * D_DIM + h * HD_DIM + (nh * 2 + nn) * 16 + c] = f2bf(o);
        }
    }
}

extern "C" void kernel_launch(void* const* d_in, const int* in_sizes, int n_in,
                              void* d_out, int out_size, void* d_ws, size_t ws_size,
                              hipStream_t stream) {
    const float* x         = (const float*)d_in[0];
    const float* norm1_w   = (const float*)d_in[1];
    const float* norm2_w   = (const float*)d_in[2];
    const float* w_qkv     = (const float*)d_in[3];
    const float* q_norm_w  = (const float*)d_in[4];
    const float* k_norm_w  = (const float*)d_in[5];
    const float* gamma_w1  = (const float*)d_in[6];
    const float* gamma_w2  = (const float*)d_in[7];
    const float* m_persist = (const float*)d_in[8];
    const float* mem_gate  = (const float*)d_in[9];
    const float* w_o       = (const float*)d_in[10];
    const float* ffn_w1    = (const float*)d_in[11];
    const float* ffn_w3    = (const float*)d_in[12];
    const float* ffn_w2    = (const float*)d_in[13];
    float* out = (float*)d_out;
    char* ws = (char*)d_ws;

    const size_t MB = 1024 * 1024;
    u16*   h_bf   = (u16*)(ws);                 // [0,4MB) h / h2
    u16*   wqT    = (u16*)(ws + 4 * MB);        // [4,10)
    u16*   woT    = (u16*)(ws + 10 * MB);       // [10,12)
    u16*   w13T   = (u16*)(ws + 12 * MB);       // [12,23) interleaved w1/w3
    u16*   w2T    = (u16*)(ws + 23 * MB);       // [23,28.5)
    u16*   qkv_bf = (u16*)(ws + 29884416);      // [28.5,40.5) dead after split
    u16*   ao_bf  = (u16*)(ws + 38273024);      // [36.5,40.5) (after qkv dead)
    float* qh     = (float*)(ws + 42467328);    // [40.5,48.5) fp32 q
    u16*   kh     = (u16*)(ws + 50855936);      // [48.5,52.5)
    u16*   khT_s  = (u16*)(ws + 50855936 + 4 * MB);   // [52.5,56.5)
    float* gammab = (float*)(ws + 59244544);    // [56.5,+8KB)
    u16*   vhT_s  = (u16*)(ws + 59244544 + 65536);    // [56.56,+4MB)
    u16*   gw1T   = (u16*)(ws + 63504384);      // [60.56,+128KB) gamma W1^T bf16
    u16*   mid_bf = (u16*)(ws + 29884416);      // [28.5,40) post-attention

    // --- prep: wqT + gw1T transposes + rmsnorm1, ONE launch ------------------
    hipLaunchKernelGGL(prep_kernel, dim3(784 + S_LEN), dim3(256), 0, stream,
                       w_qkv, gamma_w1, wqT, gw1T, x, norm1_w, h_bf);

    // --- forward pass ---------------------------------------------------------
    hipLaunchKernelGGL((gemm_bb_kernel<64, 1>), dim3(24, 32), dim3(256), 0, stream,
                       h_bf, wqT, qkv_bf, S_LEN, 3 * D_DIM, D_DIM);
    // split+rope+transpose (512 blocks) + gamma gate GEMM (32 blocks), merged
    hipLaunchKernelGGL(split_gamma_kernel, dim3(512 + 32), dim3(256), 0, stream,
                       qkv_bf, q_norm_w, k_norm_w, qh, kh, khT_s, vhT_s,
                       h_bf, gw1T, gamma_w2, gammab);
    // fused attention (512 blocks) + late weight transposes back-fill (2368)
    hipLaunchKernelGGL(fused_omega_attn_kernel, dim3(512 + 2368), dim3(512), 0, stream,
                       qh, kh, khT_s, vhT_s, gammab, m_persist, mem_gate, ao_bf,
                       w_o, ffn_w1, ffn_w3, ffn_w2, woT, w13T, w2T);
    hipLaunchKernelGGL(gemm64_kernel, dim3(16, 32), dim3(256), 0, stream,
                       ao_bf, woT, x, out, S_LEN, D_DIM, D_DIM);
    hipLaunchKernelGGL(rmsnorm_kernel, dim3(S_LEN), dim3(256), 0, stream,
                       out, norm2_w, h_bf);
    // ffn13 GEMM (BM=128) with fused SwiGLU epilogue -> mid
    hipLaunchKernelGGL((gemm_bb_kernel<128, 2>), dim3(44, 16), dim3(256), 0, stream,
                       h_bf, w13T, mid_bf, S_LEN, 2 * FFNP, D_DIM);
    hipLaunchKernelGGL(gemm64_kernel, dim3(16, 32), dim3(256), 0, stream,
                       mid_bf, w2T, out, out, S_LEN, D_DIM, FFNP);
}